// Round 1
// baseline (272.354 us; speedup 1.0000x reference)
//
#include <hip/hip_runtime.h>
#include <cstdint>
#include <cstddef>

typedef unsigned short u16;
typedef __attribute__((ext_vector_type(8))) __bf16 bf16x8;   // MFMA A/B operand
typedef __attribute__((ext_vector_type(4))) float floatx4;   // MFMA C/D operand

// dims
#define T_DIM   512
#define B_SZ    8
#define ROWS    4096      // T*B
#define OBS_D   256
#define D_IN    2048
#define NHEAD   16
#define NSTATE  64
#define PDIM    128
#define NUNITS  256
#define NACT    64
#define NSEG    4
#define SEGT    128       // T_DIM / NSEG
#define SLOT    (B_SZ * NHEAD * PDIM * NSTATE)   // 1048576 elems per seg-state slot
// r18: BCm now holds only B(1024) | C(1024). dtraw moved to dedicated dtdecay
// kernel so the projection GEMM is N=2048 -> grid 32x16 = 512 blocks = exactly
// 2 blocks/CU (was 544 = 2.125/CU -> 32 CUs ran 3 blocks, ~1/3 of the dispatch
// was a 5%-occupancy tail; OccupancyPercent 17.5% matched that model).
#define BCSTR   2048

__host__ __device__ __forceinline__ float bf2f(u16 u) {
    union { uint32_t i; float f; } v; v.i = ((uint32_t)u) << 16; return v.f;
}
__host__ __device__ __forceinline__ u16 f2bf(float f) {
    union { float f; uint32_t i; } v; v.f = f;
    uint32_t r = v.i + 0x7FFFu + ((v.i >> 16) & 1u);
    return (u16)(r >> 16);
}

// async 16B/lane global->LDS (m97 pattern). lds ptr must be wave-uniform.
__device__ __forceinline__ void glds16(const u16* g, u16* l) {
    __builtin_amdgcn_global_load_lds(
        (__attribute__((address_space(1))) void*)g,
        (__attribute__((address_space(3))) void*)l, 16, 0, 0);
}

// ---------------- harness-required symbol (zero-work launch keeps it referenced) ----------------
__global__ __launch_bounds__(256) void ActorAgent_27625229647898_kernel(
        float* __restrict__ out, int n, float v) {
    for (int i = blockIdx.x * 256 + threadIdx.x; i < n; i += gridDim.x * 256)
        out[i] = v;
}

// ---------------- prep: all weight converts + transposes in ONE launch ----------------
// flat section: obs cvt, W_dt^T scatter into WdtT (16 x 2048).
__global__ __launch_bounds__(256) void prep(const float* __restrict__ obs,
                                            const float* __restrict__ W_dt,
                                            const float* __restrict__ W_in,
                                            const float* __restrict__ W_B,
                                            const float* __restrict__ W_C,
                                            const float* __restrict__ W_yo,
                                            const float* __restrict__ W_head,
                                            u16* __restrict__ obsb,
                                            u16* __restrict__ WinT, u16* __restrict__ WBCT,
                                            u16* __restrict__ WdtT,
                                            u16* __restrict__ WyoT, u16* __restrict__ WheadT) {
    int bid = blockIdx.x;
    if (bid < 160) {
        const int NOBS = ROWS * OBS_D;             // 1048576
        const int NDT  = D_IN * NHEAD;             // 32768
        for (int i = bid * 256 + threadIdx.x; i < NOBS + NDT; i += 160 * 256) {
            if (i < NOBS) obsb[i] = f2bf(obs[i]);
            else {
                int j = i - NOBS;                  // j = k*16 + n
                int k = j >> 4, n = j & 15;
                WdtT[n * D_IN + k] = f2bf(W_dt[j]);
            }
        }
        return;
    }
    bid -= 160;
    const float* src; u16* dst; int R, C, bx, by;
    if (bid < 512)       { src = W_in;   dst = WinT;   R = 256;  C = 2048; bx = bid & 63; by = bid >> 6; }
    else if (bid < 2560) { int i = bid - 512;  src = W_B;  dst = WBCT; R = 2048; C = 1024; bx = i & 31; by = i >> 5; }
    else if (bid < 4608) { int i = bid - 2560; src = W_C;  dst = WBCT + (size_t)1024 * 2048; R = 2048; C = 1024; bx = i & 31; by = i >> 5; }
    else if (bid < 5120) { int i = bid - 4608; src = W_yo; dst = WyoT; R = 2048; C = 256;  bx = i & 7;  by = i >> 3; }
    else                 { int i = bid - 5120; src = W_head; dst = WheadT; R = 256; C = 64; bx = i & 1; by = i >> 1; }
    __shared__ float t[32][33];
    int c0 = bx * 32, r0 = by * 32;
    int tx = threadIdx.x & 31, ty = threadIdx.x >> 5;
#pragma unroll
    for (int i = 0; i < 32; i += 8)
        t[ty + i][tx] = src[(size_t)(r0 + ty + i) * C + c0 + tx];
    __syncthreads();
#pragma unroll
    for (int i = 0; i < 32; i += 8)
        dst[(size_t)(c0 + ty + i) * R + r0 + tx] = f2bf(t[tx][ty + i]);
}

// ---------------- bt128: 128x128 bf16 MFMA GEMM, B^T (N,K), BK=32 glds staging ----------------
// Proven round-13 structure: unpadded [row][32] LDS, 4 glds16/thread-group/iter,
// 16 MFMA per wave-iter, 2 barriers/iter. Best measured variant.
// NOTE (r14/r15/r17 post-mortems): BK=64 (bank conflicts 3x), 128x64 tile
// (MFMA/barrier halved), and XCD swizzle (A thrashes per-XCD L2) all regress.
template <int ACT, int OUT_BF16, int HAS_BIAS>
__global__ __launch_bounds__(256) void gemm_bt128(const u16* __restrict__ A,
                                                  const u16* __restrict__ BT,
                                                  const float* __restrict__ bias,
                                                  void* __restrict__ Cout,
                                                  int M, int N, int K) {
    __shared__ __align__(16) u16 sA[128 * 32];
    __shared__ __align__(16) u16 sB[128 * 32];
    const int tid  = threadIdx.x;
    const int wave = tid >> 6, lane = tid & 63;
    const int quad = lane >> 4, lr = lane & 15;
    const int wm = wave & 1, wn = wave >> 1;
    const int m0 = blockIdx.x * 128, n0 = blockIdx.y * 128;
    const int r0 = wave * 32 + (lane >> 2);   // staged row per lane
    const int kel = (lane & 3) * 8;           // k offset (u16) per lane

    floatx4 acc[4][4];
#pragma unroll
    for (int i = 0; i < 4; i++)
#pragma unroll
        for (int j = 0; j < 4; j++)
#pragma unroll
            for (int r = 0; r < 4; r++) acc[i][j][r] = 0.f;

    const u16* apg = A + (size_t)(m0 + r0) * K + kel;
    const u16* bpg = BT + (size_t)(n0 + r0) * K + kel;
    u16* lA0 = &sA[(wave * 32) * 32];
    u16* lA1 = &sA[(wave * 32 + 16) * 32];
    u16* lB0 = &sB[(wave * 32) * 32];
    u16* lB1 = &sB[(wave * 32 + 16) * 32];

    for (int k0 = 0; k0 < K; k0 += 32) {
        __syncthreads();   // previous iteration's LDS readers done
        glds16(apg + k0, lA0);
        glds16(apg + (size_t)16 * K + k0, lA1);
        glds16(bpg + k0, lB0);
        glds16(bpg + (size_t)16 * K + k0, lB1);
        __syncthreads();   // drain vmcnt -> LDS visible
        bf16x8 af[4], bfr[4];
#pragma unroll
        for (int i = 0; i < 4; i++)
            af[i] = *(const bf16x8*)&sA[(wm * 64 + i * 16 + lr) * 32 + quad * 8];
#pragma unroll
        for (int j = 0; j < 4; j++)
            bfr[j] = *(const bf16x8*)&sB[(wn * 64 + j * 16 + lr) * 32 + quad * 8];
#pragma unroll
        for (int i = 0; i < 4; i++)
#pragma unroll
            for (int j = 0; j < 4; j++)
                acc[i][j] = __builtin_amdgcn_mfma_f32_16x16x32_bf16(af[i], bfr[j], acc[i][j], 0, 0, 0);
    }
    // C/D layout: col = lane&15, row = quad*4 + reg
#pragma unroll
    for (int j = 0; j < 4; j++) {
        int col = n0 + wn * 64 + j * 16 + lr;
        float bvv = HAS_BIAS ? bias[col] : 0.f;
#pragma unroll
        for (int i = 0; i < 4; i++) {
#pragma unroll
            for (int r = 0; r < 4; r++) {
                int row = m0 + wm * 64 + i * 16 + quad * 4 + r;
                float v = acc[i][j][r] + bvv;
                if (ACT) v = fmaxf(v, 0.f);
                if (OUT_BF16) ((u16*)Cout)[(size_t)row * N + col] = f2bf(v);
                else          ((float*)Cout)[(size_t)row * N + col] = v;
            }
        }
    }
}

// ---------------- bt64: 64x64 bf16 MFMA GEMM, B^T layout, BK=64 glds staging ----------------
template <int ACT, int OUT_BF16>
__global__ __launch_bounds__(256) void gemm_bt64(const u16* __restrict__ A,
                                                 const u16* __restrict__ BT,
                                                 const float* __restrict__ bias,
                                                 void* __restrict__ Cout,
                                                 int M, int N, int K) {
    __shared__ __align__(16) u16 sA[64 * 64];  // 8 KB
    __shared__ __align__(16) u16 sB[64 * 64];
    const int tid  = threadIdx.x;
    const int wave = tid >> 6, lane = tid & 63;
    const int quad = lane >> 4, lr = lane & 15;
    const int m0 = blockIdx.x * 64, n0 = blockIdx.y * 64;
    const int srl = lane >> 3, sc = (lane & 7) * 8;

    floatx4 acc[4];
#pragma unroll
    for (int i = 0; i < 4; i++)
#pragma unroll
        for (int j = 0; j < 4; j++) acc[i][j] = 0.f;

    const u16* apg = A + (size_t)(m0 + wave * 16 + srl) * K + sc;
    const u16* bpg = BT + (size_t)(n0 + wave * 16 + srl) * K + sc;

    for (int k0 = 0; k0 < K; k0 += 64) {
        __syncthreads();
#pragma unroll
        for (int g = 0; g < 2; ++g) {
            glds16(apg + (size_t)(g * 8) * K + k0, &sA[(wave * 16 + g * 8) * 64]);
            glds16(bpg + (size_t)(g * 8) * K + k0, &sB[(wave * 16 + g * 8) * 64]);
        }
        __syncthreads();
#pragma unroll
        for (int ks = 0; ks < 2; ++ks) {
            bf16x8 af = *(const bf16x8*)&sA[(wave * 16 + lr) * 64 + ks * 32 + quad * 8];
#pragma unroll
            for (int nt = 0; nt < 4; nt++) {
                bf16x8 bf = *(const bf16x8*)&sB[(nt * 16 + lr) * 64 + ks * 32 + quad * 8];
                acc[nt] = __builtin_amdgcn_mfma_f32_16x16x32_bf16(af, bf, acc[nt], 0, 0, 0);
            }
        }
    }
#pragma unroll
    for (int nt = 0; nt < 4; nt++) {
        int col = n0 + nt * 16 + lr;
        float bvv = bias ? bias[col] : 0.f;
#pragma unroll
        for (int r = 0; r < 4; r++) {
            int row = m0 + wave * 16 + quad * 4 + r;
            float v = acc[nt][r] + bvv;
            if (ACT) v = fmaxf(v, 0.f);
            if (OUT_BF16) ((u16*)Cout)[(size_t)row * N + col] = f2bf(v);
            else          ((float*)Cout)[(size_t)row * N + col] = v;
        }
    }
}

// ---------------- dtdecay: dtraw = x @ W_dt, fused softplus + decay ----------------
// Replaces the 17th N-tile of the projection GEMM (and the dt_fix pass).
// 512 blocks x 256 thr, 64 KB LDS -> exactly 2 blocks/CU. Memory-bound:
// one 16 MB re-read of xb (~3 us) + L2-resident WdtT.
__global__ __launch_bounds__(256) void dtdecay(const u16* __restrict__ xb,
                                               const u16* __restrict__ WdtT,
                                               const float* __restrict__ dt_bias,
                                               const float* __restrict__ A_log,
                                               float* __restrict__ dtv,
                                               float* __restrict__ decayv) {
    __shared__ __align__(16) u16 sw[NHEAD * D_IN];   // 64 KB, [h][k]
    const int tid = threadIdx.x;
#pragma unroll
    for (int i = 0; i < 16; ++i) {
        int idx = (tid + i * 256) * 8;
        *(uint4*)&sw[idx] = *(const uint4*)(WdtT + idx);
    }
    __syncthreads();
    const int wave = tid >> 6, lane = tid & 63;
#pragma unroll 1
    for (int rr = 0; rr < 2; ++rr) {
        const int row = blockIdx.x * 8 + wave * 2 + rr;
        const u16* xp = xb + (size_t)row * D_IN + lane * 8;
        float acc[NHEAD];
#pragma unroll
        for (int h = 0; h < NHEAD; ++h) acc[h] = 0.f;
#pragma unroll
        for (int k0 = 0; k0 < D_IN; k0 += 512) {
            uint4 xv = *(const uint4*)(xp + k0);
            const u16* xu = (const u16*)&xv;
            float xf[8];
#pragma unroll
            for (int j = 0; j < 8; ++j) xf[j] = bf2f(xu[j]);
#pragma unroll
            for (int h = 0; h < NHEAD; ++h) {
                uint4 wv = *(const uint4*)&sw[h * D_IN + k0 + lane * 8];
                const u16* wu = (const u16*)&wv;
#pragma unroll
                for (int j = 0; j < 8; ++j)
                    acc[h] = fmaf(xf[j], bf2f(wu[j]), acc[h]);
            }
        }
        // butterfly reduce over 64 lanes
#pragma unroll
        for (int m = 1; m < 64; m <<= 1)
#pragma unroll
            for (int h = 0; h < NHEAD; ++h)
                acc[h] += __shfl_xor(acc[h], m);
        if (lane < NHEAD) {
            float z = acc[lane] + dt_bias[lane];
            float sp = (z > 20.f) ? z : log1pf(expf(z));
            int o = row * NHEAD + lane;
            dtv[o] = sp;
            decayv[o] = expf(-expf(A_log[lane]) * sp);
        }
    }
}

// ---------------- seg_state: segment-final states as weighted outer-product sum ----------------
__global__ __launch_bounds__(256) void seg_state(const u16* __restrict__ xw,
                                                 const u16* __restrict__ BCm,
                                                 const float* __restrict__ dtv,
                                                 const float* __restrict__ decayv,
                                                 float* __restrict__ Hbuf) {
    const int blk = blockIdx.x;
    const int seg = blk >> 7;
    const int b   = (blk >> 4) & 7;
    const int h   = blk & 15;
    const int tid = threadIdx.x;
    const int pgrp = tid >> 3;
    const int oct  = tid & 7;

    __shared__ __align__(16) u16 sx[SEGT][PDIM];
    __shared__ __align__(16) u16 sbm[SEGT][NSTATE];
    __shared__ float sw[SEGT];
    __shared__ float sdt[SEGT];
    __shared__ float sdec[SEGT];
    __shared__ float sP[32];

    const int t0 = seg * SEGT;

#pragma unroll
    for (int k = 0; k < 8; ++k) {
        int idx = tid + k * 256;
        int t = idx >> 4, c = (idx & 15) * 8;
        int r = (t0 + t) * B_SZ + b;
        *(uint4*)&sx[t][c] = *(const uint4*)(xw + (size_t)r * D_IN + h * PDIM + c);
    }
#pragma unroll
    for (int k = 0; k < 4; ++k) {
        int idx = tid + k * 256;
        int t = idx >> 3, c = (idx & 7) * 8;
        int r = (t0 + t) * B_SZ + b;
        *(uint4*)&sbm[t][c] = *(const uint4*)(BCm + (size_t)r * BCSTR + h * NSTATE + c);
    }
    if (tid < SEGT)            sdt[tid] = dtv[((t0 + tid) * B_SZ + b) * NHEAD + h];
    else if (tid < 2 * SEGT)   sdec[tid - SEGT] = decayv[((t0 + tid - SEGT) * B_SZ + b) * NHEAD + h];
    __syncthreads();

    if (tid < 32) {
        float p = 1.f;
        for (int i = 3; i >= 0; --i) {
            int t = tid * 4 + i;
            sw[t] = sdt[t] * p;
            p *= sdec[t];
        }
        sP[tid] = p;
    }
    __syncthreads();
    if (tid == 0) {
        float suf = 1.f;
        for (int q = 31; q >= 0; --q) { float tmp = sP[q]; sP[q] = suf; suf *= tmp; }
    }
    __syncthreads();
    if (tid < 32) {
        float m = sP[tid];
        for (int i = 0; i < 4; ++i) sw[tid * 4 + i] *= m;
    }
    __syncthreads();

    float acc[4][8];
#pragma unroll
    for (int i = 0; i < 4; i++)
#pragma unroll
        for (int j = 0; j < 8; j++) acc[i][j] = 0.f;

    for (int t = 0; t < SEGT; ++t) {
        float w = sw[t];
        const u16* xp = &sx[t][pgrp * 4];
        const u16* bp = &sbm[t][oct * 8];
        float xv[4], bv[8];
#pragma unroll
        for (int i = 0; i < 4; i++) xv[i] = w * bf2f(xp[i]);
#pragma unroll
        for (int j = 0; j < 8; j++) bv[j] = bf2f(bp[j]);
#pragma unroll
        for (int i = 0; i < 4; i++)
#pragma unroll
            for (int j = 0; j < 8; j++)
                acc[i][j] = fmaf(xv[i], bv[j], acc[i][j]);
    }

    float* base = Hbuf + (size_t)seg * SLOT +
                  (((size_t)b * NHEAD + h) * PDIM + pgrp * 4) * NSTATE + oct * 8;
#pragma unroll
    for (int i = 0; i < 4; i++) {
        *(float4*)(base + (size_t)i * NSTATE)     = make_float4(acc[i][0], acc[i][1], acc[i][2], acc[i][3]);
        *(float4*)(base + (size_t)i * NSTATE + 4) = make_float4(acc[i][4], acc[i][5], acc[i][6], acc[i][7]);
    }
}

// ---------------- prefix combine -> bf16 prefix states Hbf ----------------
__global__ __launch_bounds__(256) void seg_prefix(const float* __restrict__ Hbuf,
                                                  const float* __restrict__ decayv,
                                                  u16* __restrict__ Hbf) {
    const int blk = blockIdx.x;
    const int b  = blk >> 6;
    const int h  = (blk >> 2) & 15;
    const int ec = blk & 3;
    const int tid = threadIdx.x;

    __shared__ float sA[NSEG];

    if (tid < 64 * (NSEG - 2)) {
        int s = 1 + (tid >> 6);
        int i = tid & 63;
        int t = s * SEGT + i * 2;
        float p = decayv[(t * B_SZ + b) * NHEAD + h] *
                  decayv[((t + 1) * B_SZ + b) * NHEAD + h];
        p *= __shfl_xor(p, 1);
        p *= __shfl_xor(p, 2);
        p *= __shfl_xor(p, 4);
        p *= __shfl_xor(p, 8);
        p *= __shfl_xor(p, 16);
        p *= __shfl_xor(p, 32);
        if (i == 0) sA[s] = p;
    }
    __syncthreads();

    const size_t base = (((size_t)b * NHEAD + h) * PDIM * NSTATE) + (size_t)ec * 2048 + tid * 8;
    float4 P0 = *(const float4*)(Hbuf + base);
    float4 P1 = *(const float4*)(Hbuf + base + 4);
    u16 pk[8];
    pk[0] = f2bf(P0.x); pk[1] = f2bf(P0.y); pk[2] = f2bf(P0.z); pk[3] = f2bf(P0.w);
    pk[4] = f2bf(P1.x); pk[5] = f2bf(P1.y); pk[6] = f2bf(P1.z); pk[7] = f2bf(P1.w);
    *(uint4*)(Hbf + base) = *(const uint4*)pk;
#pragma unroll
    for (int s = 1; s <= NSEG - 2; ++s) {
        float a = sA[s];
        const float* slot = Hbuf + (size_t)s * SLOT + base;
        float4 h0 = *(const float4*)(slot);
        float4 h1 = *(const float4*)(slot + 4);
        P0.x = fmaf(a, P0.x, h0.x); P0.y = fmaf(a, P0.y, h0.y);
        P0.z = fmaf(a, P0.z, h0.z); P0.w = fmaf(a, P0.w, h0.w);
        P1.x = fmaf(a, P1.x, h1.x); P1.y = fmaf(a, P1.y, h1.y);
        P1.z = fmaf(a, P1.z, h1.z); P1.w = fmaf(a, P1.w, h1.w);
        pk[0] = f2bf(P0.x); pk[1] = f2bf(P0.y); pk[2] = f2bf(P0.z); pk[3] = f2bf(P0.w);
        pk[4] = f2bf(P1.x); pk[5] = f2bf(P1.y); pk[6] = f2bf(P1.z); pk[7] = f2bf(P1.w);
        *(uint4*)(Hbf + (size_t)s * SLOT + base) = *(const uint4*)pk;
    }
}

// ---------------- chunk_scan: fused S' build + Y = exp(L).C@Hp^T + S'@X^T ----------------
__global__ __launch_bounds__(256) void chunk_scan(const u16* __restrict__ BCm,
                                                  const float* __restrict__ dtv,
                                                  const float* __restrict__ decayv,
                                                  const u16* __restrict__ Hbf,
                                                  u16* __restrict__ xb) {
    __shared__ __align__(16) u16 sB_[128][68];   // B [t'][n]
    __shared__ __align__(16) u16 sC_[128][68];   // C [t][n]
    __shared__ __align__(16) u16 sS[128][132];   // S' [t][t']
    __shared__ __align__(16) u16 sXT[128][36];   // X^T [p][k-tile]
    __shared__ float sdt[SEGT], sL[SEGT], sEL[SEGT], stmp[32];

    const int blk = blockIdx.x;
    const int seg = blk >> 7, b = (blk >> 4) & 7, h = blk & 15;
    const int tid = threadIdx.x;
    const int wave = tid >> 6, lane = tid & 63;
    const int quad = lane >> 4, lr = lane & 15;
    const int wm = wave & 1, wn = wave >> 1;
    const int t0 = seg * SEGT;

#pragma unroll
    for (int it = 0; it < 4; ++it) {
        int idx = tid + it * 256;
        int t = idx >> 3, c = (idx & 7) * 8;
        int r = (t0 + t) * B_SZ + b;
        *(uint4*)&sB_[t][c] = *(const uint4*)(BCm + (size_t)r * BCSTR + h * NSTATE + c);
        *(uint4*)&sC_[t][c] = *(const uint4*)(BCm + (size_t)r * BCSTR + 1024 + h * NSTATE + c);
    }
    if (tid < SEGT) sdt[tid] = dtv[((t0 + tid) * B_SZ + b) * NHEAD + h];
    else if (tid < 2 * SEGT) {
        int t = tid - SEGT;
        sL[t] = __logf(fmaxf(decayv[((t0 + t) * B_SZ + b) * NHEAD + h], 1e-30f));
    }
    __syncthreads();
    if (tid < 32) {
        float s = 0.f, v[4];
#pragma unroll
        for (int i = 0; i < 4; ++i) { s += sL[tid * 4 + i]; v[i] = s; }
        stmp[tid] = s;
#pragma unroll
        for (int i = 0; i < 4; ++i) sL[tid * 4 + i] = v[i];
    }
    __syncthreads();
    if (tid == 0) {
        float run = 0.f;
        for (int q = 0; q < 32; ++q) { float c2 = stmp[q]; stmp[q] = run; run += c2; }
    }
    __syncthreads();
    if (tid < 32) {
        float off = stmp[tid];
#pragma unroll
        for (int i = 0; i < 4; ++i) sL[tid * 4 + i] += off;
    }
    __syncthreads();
    if (tid < SEGT) sEL[tid] = __expf(sL[tid]);

    floatx4 accS[4][4];
#pragma unroll
    for (int i = 0; i < 4; i++)
#pragma unroll
        for (int j = 0; j < 4; j++)
#pragma unroll
            for (int r = 0; r < 4; r++) accS[i][j][r] = 0.f;
#pragma unroll
    for (int k0 = 0; k0 < 64; k0 += 32) {
        bf16x8 af[4], bfr[4];
#pragma unroll
        for (int i = 0; i < 4; i++)
            af[i] = *(const bf16x8*)&sB_[wm * 64 + i * 16 + lr][k0 + quad * 8];
#pragma unroll
        for (int j = 0; j < 4; j++)
            bfr[j] = *(const bf16x8*)&sC_[wn * 64 + j * 16 + lr][k0 + quad * 8];
#pragma unroll
        for (int i = 0; i < 4; i++)
#pragma unroll
            for (int j = 0; j < 4; j++)
                accS[i][j] = __builtin_amdgcn_mfma_f32_16x16x32_bf16(af[i], bfr[j], accS[i][j], 0, 0, 0);
    }
#pragma unroll
    for (int j = 0; j < 4; j++) {
        int tt = wn * 64 + j * 16 + lr;
        float Lt = sL[tt];
#pragma unroll
        for (int i = 0; i < 4; i++) {
#pragma unroll
            for (int r = 0; r < 4; r++) {
                int tp = wm * 64 + i * 16 + quad * 4 + r;
                float v = 0.f;
                if (tp <= tt) v = accS[i][j][r] * sdt[tp] * __expf(Lt - sL[tp]);
                sS[tt][tp] = f2bf(v);
            }
        }
    }

    floatx4 acc[4][4];
#pragma unroll
    for (int i = 0; i < 4; i++)
#pragma unroll
        for (int j = 0; j < 4; j++)
#pragma unroll
            for (int r = 0; r < 4; r++) acc[i][j][r] = 0.f;
    __syncthreads();
    if (seg > 0) {
        const u16* hbase = Hbf + (size_t)(seg - 1) * SLOT + (((size_t)b * NHEAD + h) * PDIM) * NSTATE;
#pragma unroll
        for (int k0 = 0; k0 < 64; k0 += 32) {
            bf16x8 af[4], bfr[4];
#pragma unroll
            for (int i = 0; i < 4; i++)
                af[i] = *(const bf16x8*)&sC_[wm * 64 + i * 16 + lr][k0 + quad * 8];
#pragma unroll
            for (int j = 0; j < 4; j++)
                bfr[j] = *(const bf16x8*)(hbase + (size_t)(wn * 64 + j * 16 + lr) * NSTATE + k0 + quad * 8);
#pragma unroll
            for (int i = 0; i < 4; i++)
#pragma unroll
                for (int j = 0; j < 4; j++)
                    acc[i][j] = __builtin_amdgcn_mfma_f32_16x16x32_bf16(af[i], bfr[j], acc[i][j], 0, 0, 0);
        }
#pragma unroll
        for (int i = 0; i < 4; i++) {
#pragma unroll
            for (int r = 0; r < 4; r++) {
                float el = sEL[wm * 64 + i * 16 + quad * 4 + r];
#pragma unroll
                for (int j = 0; j < 4; j++) acc[i][j][r] *= el;
            }
        }
    }

    const int px = tid & 127, koh = (tid >> 7) * 16;
    for (int kc = 0; kc < 128; kc += 32) {
        u16 xv[16];
#pragma unroll
        for (int j2 = 0; j2 < 16; ++j2) {
            int tp = kc + koh + j2;
            xv[j2] = xb[(size_t)((t0 + tp) * B_SZ + b) * D_IN + h * PDIM + px];
        }
        __syncthreads();
        *(uint4*)&sXT[px][koh]     = *(const uint4*)&xv[0];
        *(uint4*)&sXT[px][koh + 8] = *(const uint4*)&xv[8];
        __syncthreads();
        bf16x8 af[4], bfr[4];
#pragma unroll
        for (int i = 0; i < 4; i++)
            af[i] = *(const bf16x8*)&sS[wm * 64 + i * 16 + lr][kc + quad * 8];
#pragma unroll
        for (int j = 0; j < 4; j++)
            bfr[j] = *(const bf16x8*)&sXT[wn * 64 + j * 16 + lr][quad * 8];
#pragma unroll
        for (int i = 0; i < 4; i++)
#pragma unroll
            for (int j = 0; j < 4; j++)
                acc[i][j] = __builtin_amdgcn_mfma_f32_16x16x32_bf16(af[i], bfr[j], acc[i][j], 0, 0, 0);
    }

#pragma unroll
    for (int j = 0; j < 4; j++) {
        int p = wn * 64 + j * 16 + lr;
#pragma unroll
        for (int i = 0; i < 4; i++) {
#pragma unroll
            for (int r = 0; r < 4; r++) {
                int t = wm * 64 + i * 16 + quad * 4 + r;
                xb[(size_t)((t0 + t) * B_SZ + b) * D_IN + h * PDIM + p] = f2bf(acc[i][j][r]);
            }
        }
    }
}

// ---------------- launch ----------------
extern "C" void kernel_launch(void* const* d_in, const int* in_sizes, int n_in,
                              void* d_out, int out_size, void* d_ws, size_t ws_size,
                              hipStream_t stream) {
    const float* obs     = (const float*)d_in[0];
    const float* W_in    = (const float*)d_in[1];
    const float* b_in    = (const float*)d_in[2];
    const float* A_log   = (const float*)d_in[3];
    const float* dt_bias = (const float*)d_in[4];
    const float* W_dt    = (const float*)d_in[5];
    const float* W_B     = (const float*)d_in[6];
    const float* W_C     = (const float*)d_in[7];
    const float* W_yo    = (const float*)d_in[8];
    const float* b_yo    = (const float*)d_in[9];
    const float* W_head  = (const float*)d_in[10];
    const float* b_head  = (const float*)d_in[11];

    char* ws = (char*)d_ws;
    size_t o = 0;
    u16*   xb     = (u16*)(ws + o);   o += (size_t)ROWS * D_IN * 2;            // 16 MB (x, then y in-place)
    u16*   BCm    = (u16*)(ws + o);   o += (size_t)ROWS * BCSTR * 2;           // 16 MB (B | C)
    float* dtv    = (float*)(ws + o); o += (size_t)ROWS * NHEAD * 4;
    float* decayv = (float*)(ws + o); o += (size_t)ROWS * NHEAD * 4;
    u16*   zb     = (u16*)(ws + o);   o += (size_t)ROWS * NUNITS * 2;          // 2 MB
    float* Hseg   = (float*)(ws + o); o += (size_t)(NSEG - 1) * SLOT * 4;      // 12 MB
    u16*   Hbf    = (u16*)(ws + o);   o += (size_t)(NSEG - 1) * SLOT * 2;      // 6 MB
    u16*   obsb   = (u16*)(ws + o);   o += (size_t)ROWS * OBS_D * 2;           // 2 MB
    u16*   WinT   = (u16*)(ws + o);   o += (size_t)D_IN * OBS_D * 2;           // 1 MB
    u16*   WBCT   = (u16*)(ws + o);   o += (size_t)BCSTR * D_IN * 2;           // 8 MB
    u16*   WdtT   = (u16*)(ws + o);   o += (size_t)NHEAD * D_IN * 2;           // 64 KB
    u16*   WyoT   = (u16*)(ws + o);   o += (size_t)NUNITS * D_IN * 2;          // 1 MB
    u16*   WheadT = (u16*)(ws + o);   o += (size_t)NACT * NUNITS * 2;

    // zero-work launch of the harness-required symbol (kept referenced)
    ActorAgent_27625229647898_kernel<<<dim3(1), 256, 0, stream>>>((float*)d_out, 0, 0.f);

    // ---- all weight prep in one launch ----
    prep<<<dim3(160 + 5136), 256, 0, stream>>>(obs, W_dt, W_in, W_B, W_C, W_yo, W_head,
                                               obsb, WinT, WBCT, WdtT, WyoT, WheadT);

    // ---- x = relu(obs @ W_in + b_in) -> bf16 ----
    gemm_bt128<1, 1, 1><<<dim3(32, 16), 256, 0, stream>>>(obsb, WinT, b_in, xb, ROWS, D_IN, OBS_D);
    // ---- dt = softplus(x @ W_dt + dt_bias); decay = exp(-exp(A_log)*dt) ----
    dtdecay<<<dim3(512), 256, 0, stream>>>(xb, WdtT, dt_bias, A_log, dtv, decayv);
    // ---- B|C projection (N = 2048, exactly 16 tiles -> 512 blocks = 2/CU) ----
    gemm_bt128<0, 1, 0><<<dim3(32, 16), 256, 0, stream>>>(xb, WBCT, (const float*)nullptr, BCm, ROWS, BCSTR, D_IN);
    // ---- scan: A) segment-local final states ----
    seg_state<<<dim3((NSEG - 1) * 128), 256, 0, stream>>>(xb, BCm, dtv, decayv, Hseg);
    //          B) prefix combine -> bf16 ----
    seg_prefix<<<dim3(512), 256, 0, stream>>>(Hseg, decayv, Hbf);
    //          C) fused S' + Y, in-place over xb ----
    chunk_scan<<<dim3(NSEG * 128), 256, 0, stream>>>(BCm, dtv, decayv, Hbf, xb);
    // ---- z = relu(y @ W_yo + b_yo) -> bf16 ----
    gemm_bt64<1, 1><<<dim3(64, 4), 256, 0, stream>>>(xb, WyoT, b_yo, zb, ROWS, NUNITS, D_IN);
    // ---- logits = z @ W_head + b_head -> d_out (fp32) ----
    gemm_bt64<0, 0><<<dim3(64, 1), 256, 0, stream>>>(zb, WheadT, b_head, (float*)d_out, ROWS, NACT, NUNITS);
}

// Round 3
// 256.353 us; speedup vs baseline: 1.0624x; 1.0624x over previous
//
#include <hip/hip_runtime.h>
#include <cstdint>
#include <cstddef>

typedef unsigned short u16;
typedef __attribute__((ext_vector_type(8))) __bf16 bf16x8;   // MFMA A/B operand
typedef __attribute__((ext_vector_type(4))) float floatx4;   // MFMA C/D operand

// dims
#define T_DIM   512
#define B_SZ    8
#define ROWS    4096      // T*B
#define OBS_D   256
#define D_IN    2048
#define NHEAD   16
#define NSTATE  64
#define PDIM    128
#define NUNITS  256
#define NACT    64
#define NSEG    4
#define SEGT    128       // T_DIM / NSEG
#define SLOT    (B_SZ * NHEAD * PDIM * NSTATE)   // 1048576 elems per seg-state slot
// r19/r20: BCm holds B(1024) | C(1024) | pad(128). The GEMM computes N=2048 (16
// tiles -> 512 blocks = exactly 2/CU, the r18 win) but WRITES with ldc=2176 so
// consecutive-t rows stay 8*4352=34816 B apart (non-pow2). r18's stride 2048
// (32 KB pow2 between t-rows) aliased L2 sets in seg_state/chunk_scan reads —
// the old 17x128 pad was accidentally an anti-aliasing stride.
// (r20 = r19 resubmitted verbatim: round-2 bench was an infra container
// failure, kernel never executed.)
#define BCSTR   2176      // row stride of BCm (u16 elems)
#define BCN     2048      // computed columns (B|C)

__host__ __device__ __forceinline__ float bf2f(u16 u) {
    union { uint32_t i; float f; } v; v.i = ((uint32_t)u) << 16; return v.f;
}
__host__ __device__ __forceinline__ u16 f2bf(float f) {
    union { float f; uint32_t i; } v; v.f = f;
    uint32_t r = v.i + 0x7FFFu + ((v.i >> 16) & 1u);
    return (u16)(r >> 16);
}

// async 16B/lane global->LDS (m97 pattern). lds ptr must be wave-uniform.
__device__ __forceinline__ void glds16(const u16* g, u16* l) {
    __builtin_amdgcn_global_load_lds(
        (__attribute__((address_space(1))) void*)g,
        (__attribute__((address_space(3))) void*)l, 16, 0, 0);
}

// ---------------- harness-required symbol (zero-work launch keeps it referenced) ----------------
__global__ __launch_bounds__(256) void ActorAgent_27625229647898_kernel(
        float* __restrict__ out, int n, float v) {
    for (int i = blockIdx.x * 256 + threadIdx.x; i < n; i += gridDim.x * 256)
        out[i] = v;
}

// ---------------- prep: all weight converts + transposes in ONE launch ----------------
// flat section: obs cvt, W_dt^T scatter into WdtT (16 x 2048).
__global__ __launch_bounds__(256) void prep(const float* __restrict__ obs,
                                            const float* __restrict__ W_dt,
                                            const float* __restrict__ W_in,
                                            const float* __restrict__ W_B,
                                            const float* __restrict__ W_C,
                                            const float* __restrict__ W_yo,
                                            const float* __restrict__ W_head,
                                            u16* __restrict__ obsb,
                                            u16* __restrict__ WinT, u16* __restrict__ WBCT,
                                            u16* __restrict__ WdtT,
                                            u16* __restrict__ WyoT, u16* __restrict__ WheadT) {
    int bid = blockIdx.x;
    if (bid < 160) {
        const int NOBS = ROWS * OBS_D;             // 1048576
        const int NDT  = D_IN * NHEAD;             // 32768
        for (int i = bid * 256 + threadIdx.x; i < NOBS + NDT; i += 160 * 256) {
            if (i < NOBS) obsb[i] = f2bf(obs[i]);
            else {
                int j = i - NOBS;                  // j = k*16 + n
                int k = j >> 4, n = j & 15;
                WdtT[n * D_IN + k] = f2bf(W_dt[j]);
            }
        }
        return;
    }
    bid -= 160;
    const float* src; u16* dst; int R, C, bx, by;
    if (bid < 512)       { src = W_in;   dst = WinT;   R = 256;  C = 2048; bx = bid & 63; by = bid >> 6; }
    else if (bid < 2560) { int i = bid - 512;  src = W_B;  dst = WBCT; R = 2048; C = 1024; bx = i & 31; by = i >> 5; }
    else if (bid < 4608) { int i = bid - 2560; src = W_C;  dst = WBCT + (size_t)1024 * 2048; R = 2048; C = 1024; bx = i & 31; by = i >> 5; }
    else if (bid < 5120) { int i = bid - 4608; src = W_yo; dst = WyoT; R = 2048; C = 256;  bx = i & 7;  by = i >> 3; }
    else                 { int i = bid - 5120; src = W_head; dst = WheadT; R = 256; C = 64; bx = i & 1; by = i >> 1; }
    __shared__ float t[32][33];
    int c0 = bx * 32, r0 = by * 32;
    int tx = threadIdx.x & 31, ty = threadIdx.x >> 5;
#pragma unroll
    for (int i = 0; i < 32; i += 8)
        t[ty + i][tx] = src[(size_t)(r0 + ty + i) * C + c0 + tx];
    __syncthreads();
#pragma unroll
    for (int i = 0; i < 32; i += 8)
        dst[(size_t)(c0 + ty + i) * R + r0 + tx] = f2bf(t[tx][ty + i]);
}

// ---------------- bt128: 128x128 bf16 MFMA GEMM, B^T (N,K), BK=32 glds staging ----------------
// Proven round-13 structure: unpadded [row][32] LDS, 4 glds16/thread-group/iter,
// 16 MFMA per wave-iter, 2 barriers/iter. Best measured variant.
// NOTE (r14/r15/r17 post-mortems): BK=64 (bank conflicts 3x), 128x64 tile
// (MFMA/barrier halved), and XCD swizzle (A thrashes per-XCD L2) all regress.
// ldc decouples the C row stride from the computed column count N.
template <int ACT, int OUT_BF16, int HAS_BIAS>
__global__ __launch_bounds__(256) void gemm_bt128(const u16* __restrict__ A,
                                                  const u16* __restrict__ BT,
                                                  const float* __restrict__ bias,
                                                  void* __restrict__ Cout,
                                                  int M, int N, int K, int ldc) {
    __shared__ __align__(16) u16 sA[128 * 32];
    __shared__ __align__(16) u16 sB[128 * 32];
    const int tid  = threadIdx.x;
    const int wave = tid >> 6, lane = tid & 63;
    const int quad = lane >> 4, lr = lane & 15;
    const int wm = wave & 1, wn = wave >> 1;
    const int m0 = blockIdx.x * 128, n0 = blockIdx.y * 128;
    const int r0 = wave * 32 + (lane >> 2);   // staged row per lane
    const int kel = (lane & 3) * 8;           // k offset (u16) per lane

    floatx4 acc[4][4];
#pragma unroll
    for (int i = 0; i < 4; i++)
#pragma unroll
        for (int j = 0; j < 4; j++)
#pragma unroll
            for (int r = 0; r < 4; r++) acc[i][j][r] = 0.f;

    const u16* apg = A + (size_t)(m0 + r0) * K + kel;
    const u16* bpg = BT + (size_t)(n0 + r0) * K + kel;
    u16* lA0 = &sA[(wave * 32) * 32];
    u16* lA1 = &sA[(wave * 32 + 16) * 32];
    u16* lB0 = &sB[(wave * 32) * 32];
    u16* lB1 = &sB[(wave * 32 + 16) * 32];

    for (int k0 = 0; k0 < K; k0 += 32) {
        __syncthreads();   // previous iteration's LDS readers done
        glds16(apg + k0, lA0);
        glds16(apg + (size_t)16 * K + k0, lA1);
        glds16(bpg + k0, lB0);
        glds16(bpg + (size_t)16 * K + k0, lB1);
        __syncthreads();   // drain vmcnt -> LDS visible
        bf16x8 af[4], bfr[4];
#pragma unroll
        for (int i = 0; i < 4; i++)
            af[i] = *(const bf16x8*)&sA[(wm * 64 + i * 16 + lr) * 32 + quad * 8];
#pragma unroll
        for (int j = 0; j < 4; j++)
            bfr[j] = *(const bf16x8*)&sB[(wn * 64 + j * 16 + lr) * 32 + quad * 8];
#pragma unroll
        for (int i = 0; i < 4; i++)
#pragma unroll
            for (int j = 0; j < 4; j++)
                acc[i][j] = __builtin_amdgcn_mfma_f32_16x16x32_bf16(af[i], bfr[j], acc[i][j], 0, 0, 0);
    }
    // C/D layout: col = lane&15, row = quad*4 + reg
#pragma unroll
    for (int j = 0; j < 4; j++) {
        int col = n0 + wn * 64 + j * 16 + lr;
        float bvv = HAS_BIAS ? bias[col] : 0.f;
#pragma unroll
        for (int i = 0; i < 4; i++) {
#pragma unroll
            for (int r = 0; r < 4; r++) {
                int row = m0 + wm * 64 + i * 16 + quad * 4 + r;
                float v = acc[i][j][r] + bvv;
                if (ACT) v = fmaxf(v, 0.f);
                if (OUT_BF16) ((u16*)Cout)[(size_t)row * ldc + col] = f2bf(v);
                else          ((float*)Cout)[(size_t)row * ldc + col] = v;
            }
        }
    }
}

// ---------------- bt64: 64x64 bf16 MFMA GEMM, B^T layout, BK=64 glds staging ----------------
template <int ACT, int OUT_BF16>
__global__ __launch_bounds__(256) void gemm_bt64(const u16* __restrict__ A,
                                                 const u16* __restrict__ BT,
                                                 const float* __restrict__ bias,
                                                 void* __restrict__ Cout,
                                                 int M, int N, int K) {
    __shared__ __align__(16) u16 sA[64 * 64];  // 8 KB
    __shared__ __align__(16) u16 sB[64 * 64];
    const int tid  = threadIdx.x;
    const int wave = tid >> 6, lane = tid & 63;
    const int quad = lane >> 4, lr = lane & 15;
    const int m0 = blockIdx.x * 64, n0 = blockIdx.y * 64;
    const int srl = lane >> 3, sc = (lane & 7) * 8;

    floatx4 acc[4];
#pragma unroll
    for (int i = 0; i < 4; i++)
#pragma unroll
        for (int j = 0; j < 4; j++) acc[i][j] = 0.f;

    const u16* apg = A + (size_t)(m0 + wave * 16 + srl) * K + sc;
    const u16* bpg = BT + (size_t)(n0 + wave * 16 + srl) * K + sc;

    for (int k0 = 0; k0 < K; k0 += 64) {
        __syncthreads();
#pragma unroll
        for (int g = 0; g < 2; ++g) {
            glds16(apg + (size_t)(g * 8) * K + k0, &sA[(wave * 16 + g * 8) * 64]);
            glds16(bpg + (size_t)(g * 8) * K + k0, &sB[(wave * 16 + g * 8) * 64]);
        }
        __syncthreads();
#pragma unroll
        for (int ks = 0; ks < 2; ++ks) {
            bf16x8 af = *(const bf16x8*)&sA[(wave * 16 + lr) * 64 + ks * 32 + quad * 8];
#pragma unroll
            for (int nt = 0; nt < 4; nt++) {
                bf16x8 bf = *(const bf16x8*)&sB[(nt * 16 + lr) * 64 + ks * 32 + quad * 8];
                acc[nt] = __builtin_amdgcn_mfma_f32_16x16x32_bf16(af, bf, acc[nt], 0, 0, 0);
            }
        }
    }
#pragma unroll
    for (int nt = 0; nt < 4; nt++) {
        int col = n0 + nt * 16 + lr;
        float bvv = bias ? bias[col] : 0.f;
#pragma unroll
        for (int r = 0; r < 4; r++) {
            int row = m0 + wave * 16 + quad * 4 + r;
            float v = acc[nt][r] + bvv;
            if (ACT) v = fmaxf(v, 0.f);
            if (OUT_BF16) ((u16*)Cout)[(size_t)row * N + col] = f2bf(v);
            else          ((float*)Cout)[(size_t)row * N + col] = v;
        }
    }
}

// ---------------- dtdecay: dtraw = x @ W_dt, fused softplus + decay ----------------
// r19 rewrite: register-lean. 512 thr/block, one row per wave, each QUAD owns 4
// heads (acc[4], one weight uint4 live at a time, 16 shuffles instead of 96).
// r18's acc[16] + full 512-fma unroll + 96 shfl was a VGPR blow-up risk.
__global__ __launch_bounds__(512) void dtdecay(const u16* __restrict__ xb,
                                               const u16* __restrict__ WdtT,
                                               const float* __restrict__ dt_bias,
                                               const float* __restrict__ A_log,
                                               float* __restrict__ dtv,
                                               float* __restrict__ decayv) {
    __shared__ __align__(16) u16 sw[NHEAD * D_IN];   // 64 KB, [h][k]
    const int tid = threadIdx.x;
#pragma unroll
    for (int i = 0; i < 8; ++i) {
        int idx = (tid + i * 512) * 8;
        *(uint4*)&sw[idx] = *(const uint4*)(WdtT + idx);
    }
    __syncthreads();
    const int wave = tid >> 6, lane = tid & 63;
    const int q = lane >> 4, lr = lane & 15;
    const int row = blockIdx.x * 8 + wave;
    const u16* xp = xb + (size_t)row * D_IN;
    float acc[4] = {0.f, 0.f, 0.f, 0.f};
#pragma unroll 4
    for (int k0 = 0; k0 < 16; ++k0) {
        const int kk = k0 * 128 + lr * 8;
        uint4 xv = *(const uint4*)(xp + kk);
        const u16* xu = (const u16*)&xv;
        float xf[8];
#pragma unroll
        for (int j = 0; j < 8; ++j) xf[j] = bf2f(xu[j]);
#pragma unroll
        for (int j = 0; j < 4; ++j) {
            uint4 wv = *(const uint4*)&sw[(q * 4 + j) * D_IN + kk];
            const u16* wu = (const u16*)&wv;
#pragma unroll
            for (int jj = 0; jj < 8; ++jj)
                acc[j] = fmaf(xf[jj], bf2f(wu[jj]), acc[j]);
        }
    }
    // reduce across the 16 lanes of each quad (masks 1,2,4,8 stay in-quad)
#pragma unroll
    for (int m = 1; m <= 8; m <<= 1)
#pragma unroll
        for (int j = 0; j < 4; ++j) acc[j] += __shfl_xor(acc[j], m);
    if (lr == 0) {
#pragma unroll
        for (int j = 0; j < 4; ++j) {
            int h = q * 4 + j;
            float z = acc[j] + dt_bias[h];
            float sp = (z > 20.f) ? z : log1pf(expf(z));
            int o = row * NHEAD + h;
            dtv[o] = sp;
            decayv[o] = expf(-expf(A_log[h]) * sp);
        }
    }
}

// ---------------- seg_state: segment-final states as weighted outer-product sum ----------------
__global__ __launch_bounds__(256) void seg_state(const u16* __restrict__ xw,
                                                 const u16* __restrict__ BCm,
                                                 const float* __restrict__ dtv,
                                                 const float* __restrict__ decayv,
                                                 float* __restrict__ Hbuf) {
    const int blk = blockIdx.x;
    const int seg = blk >> 7;
    const int b   = (blk >> 4) & 7;
    const int h   = blk & 15;
    const int tid = threadIdx.x;
    const int pgrp = tid >> 3;
    const int oct  = tid & 7;

    __shared__ __align__(16) u16 sx[SEGT][PDIM];
    __shared__ __align__(16) u16 sbm[SEGT][NSTATE];
    __shared__ float sw[SEGT];
    __shared__ float sdt[SEGT];
    __shared__ float sdec[SEGT];
    __shared__ float sP[32];

    const int t0 = seg * SEGT;

#pragma unroll
    for (int k = 0; k < 8; ++k) {
        int idx = tid + k * 256;
        int t = idx >> 4, c = (idx & 15) * 8;
        int r = (t0 + t) * B_SZ + b;
        *(uint4*)&sx[t][c] = *(const uint4*)(xw + (size_t)r * D_IN + h * PDIM + c);
    }
#pragma unroll
    for (int k = 0; k < 4; ++k) {
        int idx = tid + k * 256;
        int t = idx >> 3, c = (idx & 7) * 8;
        int r = (t0 + t) * B_SZ + b;
        *(uint4*)&sbm[t][c] = *(const uint4*)(BCm + (size_t)r * BCSTR + h * NSTATE + c);
    }
    if (tid < SEGT)            sdt[tid] = dtv[((t0 + tid) * B_SZ + b) * NHEAD + h];
    else if (tid < 2 * SEGT)   sdec[tid - SEGT] = decayv[((t0 + tid - SEGT) * B_SZ + b) * NHEAD + h];
    __syncthreads();

    if (tid < 32) {
        float p = 1.f;
        for (int i = 3; i >= 0; --i) {
            int t = tid * 4 + i;
            sw[t] = sdt[t] * p;
            p *= sdec[t];
        }
        sP[tid] = p;
    }
    __syncthreads();
    if (tid == 0) {
        float suf = 1.f;
        for (int q = 31; q >= 0; --q) { float tmp = sP[q]; sP[q] = suf; suf *= tmp; }
    }
    __syncthreads();
    if (tid < 32) {
        float m = sP[tid];
        for (int i = 0; i < 4; ++i) sw[tid * 4 + i] *= m;
    }
    __syncthreads();

    float acc[4][8];
#pragma unroll
    for (int i = 0; i < 4; i++)
#pragma unroll
        for (int j = 0; j < 8; j++) acc[i][j] = 0.f;

    for (int t = 0; t < SEGT; ++t) {
        float w = sw[t];
        const u16* xp = &sx[t][pgrp * 4];
        const u16* bp = &sbm[t][oct * 8];
        float xv[4], bv[8];
#pragma unroll
        for (int i = 0; i < 4; i++) xv[i] = w * bf2f(xp[i]);
#pragma unroll
        for (int j = 0; j < 8; j++) bv[j] = bf2f(bp[j]);
#pragma unroll
        for (int i = 0; i < 4; i++)
#pragma unroll
            for (int j = 0; j < 8; j++)
                acc[i][j] = fmaf(xv[i], bv[j], acc[i][j]);
    }

    float* base = Hbuf + (size_t)seg * SLOT +
                  (((size_t)b * NHEAD + h) * PDIM + pgrp * 4) * NSTATE + oct * 8;
#pragma unroll
    for (int i = 0; i < 4; i++) {
        *(float4*)(base + (size_t)i * NSTATE)     = make_float4(acc[i][0], acc[i][1], acc[i][2], acc[i][3]);
        *(float4*)(base + (size_t)i * NSTATE + 4) = make_float4(acc[i][4], acc[i][5], acc[i][6], acc[i][7]);
    }
}

// ---------------- prefix combine -> bf16 prefix states Hbf ----------------
__global__ __launch_bounds__(256) void seg_prefix(const float* __restrict__ Hbuf,
                                                  const float* __restrict__ decayv,
                                                  u16* __restrict__ Hbf) {
    const int blk = blockIdx.x;
    const int b  = blk >> 6;
    const int h  = (blk >> 2) & 15;
    const int ec = blk & 3;
    const int tid = threadIdx.x;

    __shared__ float sA[NSEG];

    if (tid < 64 * (NSEG - 2)) {
        int s = 1 + (tid >> 6);
        int i = tid & 63;
        int t = s * SEGT + i * 2;
        float p = decayv[(t * B_SZ + b) * NHEAD + h] *
                  decayv[((t + 1) * B_SZ + b) * NHEAD + h];
        p *= __shfl_xor(p, 1);
        p *= __shfl_xor(p, 2);
        p *= __shfl_xor(p, 4);
        p *= __shfl_xor(p, 8);
        p *= __shfl_xor(p, 16);
        p *= __shfl_xor(p, 32);
        if (i == 0) sA[s] = p;
    }
    __syncthreads();

    const size_t base = (((size_t)b * NHEAD + h) * PDIM * NSTATE) + (size_t)ec * 2048 + tid * 8;
    float4 P0 = *(const float4*)(Hbuf + base);
    float4 P1 = *(const float4*)(Hbuf + base + 4);
    u16 pk[8];
    pk[0] = f2bf(P0.x); pk[1] = f2bf(P0.y); pk[2] = f2bf(P0.z); pk[3] = f2bf(P0.w);
    pk[4] = f2bf(P1.x); pk[5] = f2bf(P1.y); pk[6] = f2bf(P1.z); pk[7] = f2bf(P1.w);
    *(uint4*)(Hbf + base) = *(const uint4*)pk;
#pragma unroll
    for (int s = 1; s <= NSEG - 2; ++s) {
        float a = sA[s];
        const float* slot = Hbuf + (size_t)s * SLOT + base;
        float4 h0 = *(const float4*)(slot);
        float4 h1 = *(const float4*)(slot + 4);
        P0.x = fmaf(a, P0.x, h0.x); P0.y = fmaf(a, P0.y, h0.y);
        P0.z = fmaf(a, P0.z, h0.z); P0.w = fmaf(a, P0.w, h0.w);
        P1.x = fmaf(a, P1.x, h1.x); P1.y = fmaf(a, P1.y, h1.y);
        P1.z = fmaf(a, P1.z, h1.z); P1.w = fmaf(a, P1.w, h1.w);
        pk[0] = f2bf(P0.x); pk[1] = f2bf(P0.y); pk[2] = f2bf(P0.z); pk[3] = f2bf(P0.w);
        pk[4] = f2bf(P1.x); pk[5] = f2bf(P1.y); pk[6] = f2bf(P1.z); pk[7] = f2bf(P1.w);
        *(uint4*)(Hbf + (size_t)s * SLOT + base) = *(const uint4*)pk;
    }
}

// ---------------- chunk_scan: fused S' build + Y = exp(L).C@Hp^T + S'@X^T ----------------
__global__ __launch_bounds__(256) void chunk_scan(const u16* __restrict__ BCm,
                                                  const float* __restrict__ dtv,
                                                  const float* __restrict__ decayv,
                                                  const u16* __restrict__ Hbf,
                                                  u16* __restrict__ xb) {
    __shared__ __align__(16) u16 sB_[128][68];   // B [t'][n]
    __shared__ __align__(16) u16 sC_[128][68];   // C [t][n]
    __shared__ __align__(16) u16 sS[128][132];   // S' [t][t']
    __shared__ __align__(16) u16 sXT[128][36];   // X^T [p][k-tile]
    __shared__ float sdt[SEGT], sL[SEGT], sEL[SEGT], stmp[32];

    const int blk = blockIdx.x;
    const int seg = blk >> 7, b = (blk >> 4) & 7, h = blk & 15;
    const int tid = threadIdx.x;
    const int wave = tid >> 6, lane = tid & 63;
    const int quad = lane >> 4, lr = lane & 15;
    const int wm = wave & 1, wn = wave >> 1;
    const int t0 = seg * SEGT;

#pragma unroll
    for (int it = 0; it < 4; ++it) {
        int idx = tid + it * 256;
        int t = idx >> 3, c = (idx & 7) * 8;
        int r = (t0 + t) * B_SZ + b;
        *(uint4*)&sB_[t][c] = *(const uint4*)(BCm + (size_t)r * BCSTR + h * NSTATE + c);
        *(uint4*)&sC_[t][c] = *(const uint4*)(BCm + (size_t)r * BCSTR + 1024 + h * NSTATE + c);
    }
    if (tid < SEGT) sdt[tid] = dtv[((t0 + tid) * B_SZ + b) * NHEAD + h];
    else if (tid < 2 * SEGT) {
        int t = tid - SEGT;
        sL[t] = __logf(fmaxf(decayv[((t0 + t) * B_SZ + b) * NHEAD + h], 1e-30f));
    }
    __syncthreads();
    if (tid < 32) {
        float s = 0.f, v[4];
#pragma unroll
        for (int i = 0; i < 4; ++i) { s += sL[tid * 4 + i]; v[i] = s; }
        stmp[tid] = s;
#pragma unroll
        for (int i = 0; i < 4; ++i) sL[tid * 4 + i] = v[i];
    }
    __syncthreads();
    if (tid == 0) {
        float run = 0.f;
        for (int q = 0; q < 32; ++q) { float c2 = stmp[q]; stmp[q] = run; run += c2; }
    }
    __syncthreads();
    if (tid < 32) {
        float off = stmp[tid];
#pragma unroll
        for (int i = 0; i < 4; ++i) sL[tid * 4 + i] += off;
    }
    __syncthreads();
    if (tid < SEGT) sEL[tid] = __expf(sL[tid]);

    floatx4 accS[4][4];
#pragma unroll
    for (int i = 0; i < 4; i++)
#pragma unroll
        for (int j = 0; j < 4; j++)
#pragma unroll
            for (int r = 0; r < 4; r++) accS[i][j][r] = 0.f;
#pragma unroll
    for (int k0 = 0; k0 < 64; k0 += 32) {
        bf16x8 af[4], bfr[4];
#pragma unroll
        for (int i = 0; i < 4; i++)
            af[i] = *(const bf16x8*)&sB_[wm * 64 + i * 16 + lr][k0 + quad * 8];
#pragma unroll
        for (int j = 0; j < 4; j++)
            bfr[j] = *(const bf16x8*)&sC_[wn * 64 + j * 16 + lr][k0 + quad * 8];
#pragma unroll
        for (int i = 0; i < 4; i++)
#pragma unroll
            for (int j = 0; j < 4; j++)
                accS[i][j] = __builtin_amdgcn_mfma_f32_16x16x32_bf16(af[i], bfr[j], accS[i][j], 0, 0, 0);
    }
#pragma unroll
    for (int j = 0; j < 4; j++) {
        int tt = wn * 64 + j * 16 + lr;
        float Lt = sL[tt];
#pragma unroll
        for (int i = 0; i < 4; i++) {
#pragma unroll
            for (int r = 0; r < 4; r++) {
                int tp = wm * 64 + i * 16 + quad * 4 + r;
                float v = 0.f;
                if (tp <= tt) v = accS[i][j][r] * sdt[tp] * __expf(Lt - sL[tp]);
                sS[tt][tp] = f2bf(v);
            }
        }
    }

    floatx4 acc[4][4];
#pragma unroll
    for (int i = 0; i < 4; i++)
#pragma unroll
        for (int j = 0; j < 4; j++)
#pragma unroll
            for (int r = 0; r < 4; r++) acc[i][j][r] = 0.f;
    __syncthreads();
    if (seg > 0) {
        const u16* hbase = Hbf + (size_t)(seg - 1) * SLOT + (((size_t)b * NHEAD + h) * PDIM) * NSTATE;
#pragma unroll
        for (int k0 = 0; k0 < 64; k0 += 32) {
            bf16x8 af[4], bfr[4];
#pragma unroll
            for (int i = 0; i < 4; i++)
                af[i] = *(const bf16x8*)&sC_[wm * 64 + i * 16 + lr][k0 + quad * 8];
#pragma unroll
            for (int j = 0; j < 4; j++)
                bfr[j] = *(const bf16x8*)(hbase + (size_t)(wn * 64 + j * 16 + lr) * NSTATE + k0 + quad * 8);
#pragma unroll
            for (int i = 0; i < 4; i++)
#pragma unroll
                for (int j = 0; j < 4; j++)
                    acc[i][j] = __builtin_amdgcn_mfma_f32_16x16x32_bf16(af[i], bfr[j], acc[i][j], 0, 0, 0);
        }
#pragma unroll
        for (int i = 0; i < 4; i++) {
#pragma unroll
            for (int r = 0; r < 4; r++) {
                float el = sEL[wm * 64 + i * 16 + quad * 4 + r];
#pragma unroll
                for (int j = 0; j < 4; j++) acc[i][j][r] *= el;
            }
        }
    }

    const int px = tid & 127, koh = (tid >> 7) * 16;
    for (int kc = 0; kc < 128; kc += 32) {
        u16 xv[16];
#pragma unroll
        for (int j2 = 0; j2 < 16; ++j2) {
            int tp = kc + koh + j2;
            xv[j2] = xb[(size_t)((t0 + tp) * B_SZ + b) * D_IN + h * PDIM + px];
        }
        __syncthreads();
        *(uint4*)&sXT[px][koh]     = *(const uint4*)&xv[0];
        *(uint4*)&sXT[px][koh + 8] = *(const uint4*)&xv[8];
        __syncthreads();
        bf16x8 af[4], bfr[4];
#pragma unroll
        for (int i = 0; i < 4; i++)
            af[i] = *(const bf16x8*)&sS[wm * 64 + i * 16 + lr][kc + quad * 8];
#pragma unroll
        for (int j = 0; j < 4; j++)
            bfr[j] = *(const bf16x8*)&sXT[wn * 64 + j * 16 + lr][quad * 8];
#pragma unroll
        for (int i = 0; i < 4; i++)
#pragma unroll
            for (int j = 0; j < 4; j++)
                acc[i][j] = __builtin_amdgcn_mfma_f32_16x16x32_bf16(af[i], bfr[j], acc[i][j], 0, 0, 0);
    }

#pragma unroll
    for (int j = 0; j < 4; j++) {
        int p = wn * 64 + j * 16 + lr;
#pragma unroll
        for (int i = 0; i < 4; i++) {
#pragma unroll
            for (int r = 0; r < 4; r++) {
                int t = wm * 64 + i * 16 + quad * 4 + r;
                xb[(size_t)((t0 + t) * B_SZ + b) * D_IN + h * PDIM + p] = f2bf(acc[i][j][r]);
            }
        }
    }
}

// ---------------- launch ----------------
extern "C" void kernel_launch(void* const* d_in, const int* in_sizes, int n_in,
                              void* d_out, int out_size, void* d_ws, size_t ws_size,
                              hipStream_t stream) {
    const float* obs     = (const float*)d_in[0];
    const float* W_in    = (const float*)d_in[1];
    const float* b_in    = (const float*)d_in[2];
    const float* A_log   = (const float*)d_in[3];
    const float* dt_bias = (const float*)d_in[4];
    const float* W_dt    = (const float*)d_in[5];
    const float* W_B     = (const float*)d_in[6];
    const float* W_C     = (const float*)d_in[7];
    const float* W_yo    = (const float*)d_in[8];
    const float* b_yo    = (const float*)d_in[9];
    const float* W_head  = (const float*)d_in[10];
    const float* b_head  = (const float*)d_in[11];

    char* ws = (char*)d_ws;
    size_t o = 0;
    u16*   xb     = (u16*)(ws + o);   o += (size_t)ROWS * D_IN * 2;            // 16 MB (x, then y in-place)
    u16*   BCm    = (u16*)(ws + o);   o += (size_t)ROWS * BCSTR * 2;           // 17.8 MB (B | C | pad)
    float* dtv    = (float*)(ws + o); o += (size_t)ROWS * NHEAD * 4;
    float* decayv = (float*)(ws + o); o += (size_t)ROWS * NHEAD * 4;
    u16*   zb     = (u16*)(ws + o);   o += (size_t)ROWS * NUNITS * 2;          // 2 MB
    float* Hseg   = (float*)(ws + o); o += (size_t)(NSEG - 1) * SLOT * 4;      // 12 MB
    u16*   Hbf    = (u16*)(ws + o);   o += (size_t)(NSEG - 1) * SLOT * 2;      // 6 MB
    u16*   obsb   = (u16*)(ws + o);   o += (size_t)ROWS * OBS_D * 2;           // 2 MB
    u16*   WinT   = (u16*)(ws + o);   o += (size_t)D_IN * OBS_D * 2;           // 1 MB
    u16*   WBCT   = (u16*)(ws + o);   o += (size_t)BCN * D_IN * 2;             // 8 MB
    u16*   WdtT   = (u16*)(ws + o);   o += (size_t)NHEAD * D_IN * 2;           // 64 KB
    u16*   WyoT   = (u16*)(ws + o);   o += (size_t)NUNITS * D_IN * 2;          // 1 MB
    u16*   WheadT = (u16*)(ws + o);   o += (size_t)NACT * NUNITS * 2;

    // zero-work launch of the harness-required symbol (kept referenced)
    ActorAgent_27625229647898_kernel<<<dim3(1), 256, 0, stream>>>((float*)d_out, 0, 0.f);

    // ---- all weight prep in one launch ----
    prep<<<dim3(160 + 5136), 256, 0, stream>>>(obs, W_dt, W_in, W_B, W_C, W_yo, W_head,
                                               obsb, WinT, WBCT, WdtT, WyoT, WheadT);

    // ---- x = relu(obs @ W_in + b_in) -> bf16 ----
    gemm_bt128<1, 1, 1><<<dim3(32, 16), 256, 0, stream>>>(obsb, WinT, b_in, xb, ROWS, D_IN, OBS_D, D_IN);
    // ---- dt = softplus(x @ W_dt + dt_bias); decay = exp(-exp(A_log)*dt) ----
    dtdecay<<<dim3(512), 512, 0, stream>>>(xb, WdtT, dt_bias, A_log, dtv, decayv);
    // ---- B|C projection: N=2048 (16 tiles -> 512 blocks = 2/CU), ldc=2176 (non-pow2 stride) ----
    gemm_bt128<0, 1, 0><<<dim3(32, 16), 256, 0, stream>>>(xb, WBCT, (const float*)nullptr, BCm, ROWS, BCN, D_IN, BCSTR);
    // ---- scan: A) segment-local final states ----
    seg_state<<<dim3((NSEG - 1) * 128), 256, 0, stream>>>(xb, BCm, dtv, decayv, Hseg);
    //          B) prefix combine -> bf16 ----
    seg_prefix<<<dim3(512), 256, 0, stream>>>(Hseg, decayv, Hbf);
    //          C) fused S' + Y, in-place over xb ----
    chunk_scan<<<dim3(NSEG * 128), 256, 0, stream>>>(BCm, dtv, decayv, Hbf, xb);
    // ---- z = relu(y @ W_yo + b_yo) -> bf16 ----
    gemm_bt64<1, 1><<<dim3(64, 4), 256, 0, stream>>>(xb, WyoT, b_yo, zb, ROWS, NUNITS, D_IN);
    // ---- logits = z @ W_head + b_head -> d_out (fp32) ----
    gemm_bt64<0, 0><<<dim3(64, 1), 256, 0, stream>>>(zb, WheadT, b_head, (float*)d_out, ROWS, NACT, NUNITS);
}

// Round 4
// 255.053 us; speedup vs baseline: 1.0678x; 1.0051x over previous
//
#include <hip/hip_runtime.h>
#include <cstdint>
#include <cstddef>

typedef unsigned short u16;
typedef __attribute__((ext_vector_type(8))) __bf16 bf16x8;   // MFMA A/B operand
typedef __attribute__((ext_vector_type(4))) float floatx4;   // MFMA C/D operand

// dims
#define T_DIM   512
#define B_SZ    8
#define ROWS    4096      // T*B
#define OBS_D   256
#define D_IN    2048
#define NHEAD   16
#define NSTATE  64
#define PDIM    128
#define NUNITS  256
#define NACT    64
#define NSEG    4
#define SEGT    128       // T_DIM / NSEG
#define SLOT    (B_SZ * NHEAD * PDIM * NSTATE)   // 1048576 elems per seg-state slot
// BCm holds B(1024) | C(1024) | pad(128). GEMM computes N=2048 (16 tiles ->
// 512 blocks = exactly 2/CU) but WRITES with ldc=2176 (non-pow2 row stride;
// pow2 stride aliased L2 sets in seg_state/chunk_scan reads — r18 lesson).
#define BCSTR   2176      // row stride of BCm (u16 elems)
#define BCN     2048      // computed columns (B|C)

__host__ __device__ __forceinline__ float bf2f(u16 u) {
    union { uint32_t i; float f; } v; v.i = ((uint32_t)u) << 16; return v.f;
}
__host__ __device__ __forceinline__ u16 f2bf(float f) {
    union { float f; uint32_t i; } v; v.f = f;
    uint32_t r = v.i + 0x7FFFu + ((v.i >> 16) & 1u);
    return (u16)(r >> 16);
}

// async 16B/lane global->LDS (m97 pattern). lds ptr must be wave-uniform.
__device__ __forceinline__ void glds16(const u16* g, u16* l) {
    __builtin_amdgcn_global_load_lds(
        (__attribute__((address_space(1))) void*)g,
        (__attribute__((address_space(3))) void*)l, 16, 0, 0);
}

// ---------------- harness-required symbol (zero-work launch keeps it referenced) ----------------
__global__ __launch_bounds__(256) void ActorAgent_27625229647898_kernel(
        float* __restrict__ out, int n, float v) {
    for (int i = blockIdx.x * 256 + threadIdx.x; i < n; i += gridDim.x * 256)
        out[i] = v;
}

// ---------------- prep: all weight converts + transposes in ONE launch ----------------
__global__ __launch_bounds__(256) void prep(const float* __restrict__ obs,
                                            const float* __restrict__ W_dt,
                                            const float* __restrict__ W_in,
                                            const float* __restrict__ W_B,
                                            const float* __restrict__ W_C,
                                            const float* __restrict__ W_yo,
                                            const float* __restrict__ W_head,
                                            u16* __restrict__ obsb,
                                            u16* __restrict__ WinT, u16* __restrict__ WBCT,
                                            u16* __restrict__ WdtT,
                                            u16* __restrict__ WyoT, u16* __restrict__ WheadT) {
    int bid = blockIdx.x;
    if (bid < 160) {
        const int NOBS = ROWS * OBS_D;             // 1048576
        const int NDT  = D_IN * NHEAD;             // 32768
        for (int i = bid * 256 + threadIdx.x; i < NOBS + NDT; i += 160 * 256) {
            if (i < NOBS) obsb[i] = f2bf(obs[i]);
            else {
                int j = i - NOBS;                  // j = k*16 + n
                int k = j >> 4, n = j & 15;
                WdtT[n * D_IN + k] = f2bf(W_dt[j]);
            }
        }
        return;
    }
    bid -= 160;
    const float* src; u16* dst; int R, C, bx, by;
    if (bid < 512)       { src = W_in;   dst = WinT;   R = 256;  C = 2048; bx = bid & 63; by = bid >> 6; }
    else if (bid < 2560) { int i = bid - 512;  src = W_B;  dst = WBCT; R = 2048; C = 1024; bx = i & 31; by = i >> 5; }
    else if (bid < 4608) { int i = bid - 2560; src = W_C;  dst = WBCT + (size_t)1024 * 2048; R = 2048; C = 1024; bx = i & 31; by = i >> 5; }
    else if (bid < 5120) { int i = bid - 4608; src = W_yo; dst = WyoT; R = 2048; C = 256;  bx = i & 7;  by = i >> 3; }
    else                 { int i = bid - 5120; src = W_head; dst = WheadT; R = 256; C = 64; bx = i & 1; by = i >> 1; }
    __shared__ float t[32][33];
    int c0 = bx * 32, r0 = by * 32;
    int tx = threadIdx.x & 31, ty = threadIdx.x >> 5;
#pragma unroll
    for (int i = 0; i < 32; i += 8)
        t[ty + i][tx] = src[(size_t)(r0 + ty + i) * C + c0 + tx];
    __syncthreads();
#pragma unroll
    for (int i = 0; i < 32; i += 8)
        dst[(size_t)(c0 + ty + i) * R + r0 + tx] = f2bf(t[tx][ty + i]);
}

// ---------------- bt128: 128x128 bf16 MFMA GEMM, B^T (N,K), BK=32 glds staging ----------------
// r21: T3 "minimum 2-phase" double-buffer. Stage NEXT k-tile into buf^1 BEFORE
// computing buf, single vmcnt(0)+raw-barrier per iter -> the 16-MFMA cluster
// hides most of the glds latency (old structure drained vmcnt with zero work
// in between). Raw s_barrier avoids __syncthreads' implicit full drain.
// NOTE (r14/r15/r17 post-mortems): BK=64 (bank conflicts 3x), 128x64 tile
// (MFMA/barrier halved), and XCD swizzle (A thrashes per-XCD L2) all regress.
template <int ACT, int OUT_BF16, int HAS_BIAS>
__global__ __launch_bounds__(256) void gemm_bt128(const u16* __restrict__ A,
                                                  const u16* __restrict__ BT,
                                                  const float* __restrict__ bias,
                                                  void* __restrict__ Cout,
                                                  int M, int N, int K, int ldc) {
    __shared__ __align__(16) u16 sA[2][128 * 32];
    __shared__ __align__(16) u16 sB[2][128 * 32];
    const int tid  = threadIdx.x;
    const int wave = tid >> 6, lane = tid & 63;
    const int quad = lane >> 4, lr = lane & 15;
    const int wm = wave & 1, wn = wave >> 1;
    const int m0 = blockIdx.x * 128, n0 = blockIdx.y * 128;
    const int r0 = wave * 32 + (lane >> 2);   // staged row per lane
    const int kel = (lane & 3) * 8;           // k offset (u16) per lane

    floatx4 acc[4][4];
#pragma unroll
    for (int i = 0; i < 4; i++)
#pragma unroll
        for (int j = 0; j < 4; j++)
#pragma unroll
            for (int r = 0; r < 4; r++) acc[i][j][r] = 0.f;

    const u16* apg = A + (size_t)(m0 + r0) * K + kel;
    const u16* bpg = BT + (size_t)(n0 + r0) * K + kel;
    const int lofs = (wave * 32) * 32;

    // prologue: stage k-tile 0 into buf 0
    glds16(apg, &sA[0][lofs]);
    glds16(apg + (size_t)16 * K, &sA[0][lofs + 16 * 32]);
    glds16(bpg, &sB[0][lofs]);
    glds16(bpg + (size_t)16 * K, &sB[0][lofs + 16 * 32]);
    asm volatile("s_waitcnt vmcnt(0)" ::: "memory");
    __builtin_amdgcn_s_barrier();

    int cur = 0;
    for (int k0 = 0; k0 < K; k0 += 32) {
        if (k0 + 32 < K) {   // stage next tile into the other buffer
            int nb = cur ^ 1;
            glds16(apg + k0 + 32, &sA[nb][lofs]);
            glds16(apg + (size_t)16 * K + k0 + 32, &sA[nb][lofs + 16 * 32]);
            glds16(bpg + k0 + 32, &sB[nb][lofs]);
            glds16(bpg + (size_t)16 * K + k0 + 32, &sB[nb][lofs + 16 * 32]);
        }
        bf16x8 af[4], bfr[4];
#pragma unroll
        for (int i = 0; i < 4; i++)
            af[i] = *(const bf16x8*)&sA[cur][(wm * 64 + i * 16 + lr) * 32 + quad * 8];
#pragma unroll
        for (int j = 0; j < 4; j++)
            bfr[j] = *(const bf16x8*)&sB[cur][(wn * 64 + j * 16 + lr) * 32 + quad * 8];
#pragma unroll
        for (int i = 0; i < 4; i++)
#pragma unroll
            for (int j = 0; j < 4; j++)
                acc[i][j] = __builtin_amdgcn_mfma_f32_16x16x32_bf16(af[i], bfr[j], acc[i][j], 0, 0, 0);
        asm volatile("s_waitcnt vmcnt(0)" ::: "memory");   // next tile landed
        __builtin_amdgcn_s_barrier();                      // all reads of cur done
        cur ^= 1;
    }
    // C/D layout: col = lane&15, row = quad*4 + reg
#pragma unroll
    for (int j = 0; j < 4; j++) {
        int col = n0 + wn * 64 + j * 16 + lr;
        float bvv = HAS_BIAS ? bias[col] : 0.f;
#pragma unroll
        for (int i = 0; i < 4; i++) {
#pragma unroll
            for (int r = 0; r < 4; r++) {
                int row = m0 + wm * 64 + i * 16 + quad * 4 + r;
                float v = acc[i][j][r] + bvv;
                if (ACT) v = fmaxf(v, 0.f);
                if (OUT_BF16) ((u16*)Cout)[(size_t)row * ldc + col] = f2bf(v);
                else          ((float*)Cout)[(size_t)row * ldc + col] = v;
            }
        }
    }
}

// ---------------- bt64: 64x64 bf16 MFMA GEMM, B^T layout, BK=64, 2-phase dbuf ----------------
template <int ACT, int OUT_BF16>
__global__ __launch_bounds__(256) void gemm_bt64(const u16* __restrict__ A,
                                                 const u16* __restrict__ BT,
                                                 const float* __restrict__ bias,
                                                 void* __restrict__ Cout,
                                                 int M, int N, int K) {
    __shared__ __align__(16) u16 sA[2][64 * 64];  // 2 x 8 KB
    __shared__ __align__(16) u16 sB[2][64 * 64];
    const int tid  = threadIdx.x;
    const int wave = tid >> 6, lane = tid & 63;
    const int quad = lane >> 4, lr = lane & 15;
    const int m0 = blockIdx.x * 64, n0 = blockIdx.y * 64;
    const int srl = lane >> 3, sc = (lane & 7) * 8;

    floatx4 acc[4];
#pragma unroll
    for (int i = 0; i < 4; i++)
#pragma unroll
        for (int j = 0; j < 4; j++) acc[i][j] = 0.f;

    const u16* apg = A + (size_t)(m0 + wave * 16 + srl) * K + sc;
    const u16* bpg = BT + (size_t)(n0 + wave * 16 + srl) * K + sc;

    // prologue: stage k-tile 0 into buf 0
#pragma unroll
    for (int g = 0; g < 2; ++g) {
        glds16(apg + (size_t)(g * 8) * K, &sA[0][(wave * 16 + g * 8) * 64]);
        glds16(bpg + (size_t)(g * 8) * K, &sB[0][(wave * 16 + g * 8) * 64]);
    }
    asm volatile("s_waitcnt vmcnt(0)" ::: "memory");
    __builtin_amdgcn_s_barrier();

    int cur = 0;
    for (int k0 = 0; k0 < K; k0 += 64) {
        if (k0 + 64 < K) {
            int nb = cur ^ 1;
#pragma unroll
            for (int g = 0; g < 2; ++g) {
                glds16(apg + (size_t)(g * 8) * K + k0 + 64, &sA[nb][(wave * 16 + g * 8) * 64]);
                glds16(bpg + (size_t)(g * 8) * K + k0 + 64, &sB[nb][(wave * 16 + g * 8) * 64]);
            }
        }
#pragma unroll
        for (int ks = 0; ks < 2; ++ks) {
            bf16x8 af = *(const bf16x8*)&sA[cur][(wave * 16 + lr) * 64 + ks * 32 + quad * 8];
#pragma unroll
            for (int nt = 0; nt < 4; nt++) {
                bf16x8 bf = *(const bf16x8*)&sB[cur][(nt * 16 + lr) * 64 + ks * 32 + quad * 8];
                acc[nt] = __builtin_amdgcn_mfma_f32_16x16x32_bf16(af, bf, acc[nt], 0, 0, 0);
            }
        }
        asm volatile("s_waitcnt vmcnt(0)" ::: "memory");
        __builtin_amdgcn_s_barrier();
        cur ^= 1;
    }
#pragma unroll
    for (int nt = 0; nt < 4; nt++) {
        int col = n0 + nt * 16 + lr;
        float bvv = bias ? bias[col] : 0.f;
#pragma unroll
        for (int r = 0; r < 4; r++) {
            int row = m0 + wave * 16 + quad * 4 + r;
            float v = acc[nt][r] + bvv;
            if (ACT) v = fmaxf(v, 0.f);
            if (OUT_BF16) ((u16*)Cout)[(size_t)row * N + col] = f2bf(v);
            else          ((float*)Cout)[(size_t)row * N + col] = v;
        }
    }
}

// ---------------- dtdecay: dtraw = x @ W_dt, fused softplus + decay ----------------
// r21: 256 blocks x 16 rows (was 512 x 8) — the 64 KB W-preload is amortized
// over 2x the x-rows, halving total preload traffic (32 -> 16 MB).
__global__ __launch_bounds__(512) void dtdecay(const u16* __restrict__ xb,
                                               const u16* __restrict__ WdtT,
                                               const float* __restrict__ dt_bias,
                                               const float* __restrict__ A_log,
                                               float* __restrict__ dtv,
                                               float* __restrict__ decayv) {
    __shared__ __align__(16) u16 sw[NHEAD * D_IN];   // 64 KB, [h][k]
    const int tid = threadIdx.x;
#pragma unroll
    for (int i = 0; i < 8; ++i) {
        int idx = (tid + i * 512) * 8;
        *(uint4*)&sw[idx] = *(const uint4*)(WdtT + idx);
    }
    __syncthreads();
    const int wave = tid >> 6, lane = tid & 63;
    const int q = lane >> 4, lr = lane & 15;
#pragma unroll 1
    for (int rr = 0; rr < 2; ++rr) {
        const int row = blockIdx.x * 16 + wave * 2 + rr;
        const u16* xp = xb + (size_t)row * D_IN;
        float acc[4] = {0.f, 0.f, 0.f, 0.f};
#pragma unroll 4
        for (int k0 = 0; k0 < 16; ++k0) {
            const int kk = k0 * 128 + lr * 8;
            uint4 xv = *(const uint4*)(xp + kk);
            const u16* xu = (const u16*)&xv;
            float xf[8];
#pragma unroll
            for (int j = 0; j < 8; ++j) xf[j] = bf2f(xu[j]);
#pragma unroll
            for (int j = 0; j < 4; ++j) {
                uint4 wv = *(const uint4*)&sw[(q * 4 + j) * D_IN + kk];
                const u16* wu = (const u16*)&wv;
#pragma unroll
                for (int jj = 0; jj < 8; ++jj)
                    acc[j] = fmaf(xf[jj], bf2f(wu[jj]), acc[j]);
            }
        }
        // reduce across the 16 lanes of each quad (masks 1,2,4,8 stay in-quad)
#pragma unroll
        for (int m = 1; m <= 8; m <<= 1)
#pragma unroll
            for (int j = 0; j < 4; ++j) acc[j] += __shfl_xor(acc[j], m);
        if (lr == 0) {
#pragma unroll
            for (int j = 0; j < 4; ++j) {
                int h = q * 4 + j;
                float z = acc[j] + dt_bias[h];
                float sp = (z > 20.f) ? z : log1pf(expf(z));
                int o = row * NHEAD + h;
                dtv[o] = sp;
                decayv[o] = expf(-expf(A_log[h]) * sp);
            }
        }
    }
}

// ---------------- seg_state: segment-final states as weighted outer-product sum ----------------
__global__ __launch_bounds__(256) void seg_state(const u16* __restrict__ xw,
                                                 const u16* __restrict__ BCm,
                                                 const float* __restrict__ dtv,
                                                 const float* __restrict__ decayv,
                                                 float* __restrict__ Hbuf) {
    const int blk = blockIdx.x;
    const int seg = blk >> 7;
    const int b   = (blk >> 4) & 7;
    const int h   = blk & 15;
    const int tid = threadIdx.x;
    const int pgrp = tid >> 3;
    const int oct  = tid & 7;

    __shared__ __align__(16) u16 sx[SEGT][PDIM];
    __shared__ __align__(16) u16 sbm[SEGT][NSTATE];
    __shared__ float sw[SEGT];
    __shared__ float sdt[SEGT];
    __shared__ float sdec[SEGT];
    __shared__ float sP[32];

    const int t0 = seg * SEGT;

#pragma unroll
    for (int k = 0; k < 8; ++k) {
        int idx = tid + k * 256;
        int t = idx >> 4, c = (idx & 15) * 8;
        int r = (t0 + t) * B_SZ + b;
        *(uint4*)&sx[t][c] = *(const uint4*)(xw + (size_t)r * D_IN + h * PDIM + c);
    }
#pragma unroll
    for (int k = 0; k < 4; ++k) {
        int idx = tid + k * 256;
        int t = idx >> 3, c = (idx & 7) * 8;
        int r = (t0 + t) * B_SZ + b;
        *(uint4*)&sbm[t][c] = *(const uint4*)(BCm + (size_t)r * BCSTR + h * NSTATE + c);
    }
    if (tid < SEGT)            sdt[tid] = dtv[((t0 + tid) * B_SZ + b) * NHEAD + h];
    else if (tid < 2 * SEGT)   sdec[tid - SEGT] = decayv[((t0 + tid - SEGT) * B_SZ + b) * NHEAD + h];
    __syncthreads();

    if (tid < 32) {
        float p = 1.f;
        for (int i = 3; i >= 0; --i) {
            int t = tid * 4 + i;
            sw[t] = sdt[t] * p;
            p *= sdec[t];
        }
        sP[tid] = p;
    }
    __syncthreads();
    if (tid == 0) {
        float suf = 1.f;
        for (int q = 31; q >= 0; --q) { float tmp = sP[q]; sP[q] = suf; suf *= tmp; }
    }
    __syncthreads();
    if (tid < 32) {
        float m = sP[tid];
        for (int i = 0; i < 4; ++i) sw[tid * 4 + i] *= m;
    }
    __syncthreads();

    float acc[4][8];
#pragma unroll
    for (int i = 0; i < 4; i++)
#pragma unroll
        for (int j = 0; j < 8; j++) acc[i][j] = 0.f;

    for (int t = 0; t < SEGT; ++t) {
        float w = sw[t];
        const u16* xp = &sx[t][pgrp * 4];
        const u16* bp = &sbm[t][oct * 8];
        float xv[4], bv[8];
#pragma unroll
        for (int i = 0; i < 4; i++) xv[i] = w * bf2f(xp[i]);
#pragma unroll
        for (int j = 0; j < 8; j++) bv[j] = bf2f(bp[j]);
#pragma unroll
        for (int i = 0; i < 4; i++)
#pragma unroll
            for (int j = 0; j < 8; j++)
                acc[i][j] = fmaf(xv[i], bv[j], acc[i][j]);
    }

    float* base = Hbuf + (size_t)seg * SLOT +
                  (((size_t)b * NHEAD + h) * PDIM + pgrp * 4) * NSTATE + oct * 8;
#pragma unroll
    for (int i = 0; i < 4; i++) {
        *(float4*)(base + (size_t)i * NSTATE)     = make_float4(acc[i][0], acc[i][1], acc[i][2], acc[i][3]);
        *(float4*)(base + (size_t)i * NSTATE + 4) = make_float4(acc[i][4], acc[i][5], acc[i][6], acc[i][7]);
    }
}

// ---------------- prefix combine -> bf16 prefix states Hbf ----------------
__global__ __launch_bounds__(256) void seg_prefix(const float* __restrict__ Hbuf,
                                                  const float* __restrict__ decayv,
                                                  u16* __restrict__ Hbf) {
    const int blk = blockIdx.x;
    const int b  = blk >> 6;
    const int h  = (blk >> 2) & 15;
    const int ec = blk & 3;
    const int tid = threadIdx.x;

    __shared__ float sA[NSEG];

    if (tid < 64 * (NSEG - 2)) {
        int s = 1 + (tid >> 6);
        int i = tid & 63;
        int t = s * SEGT + i * 2;
        float p = decayv[(t * B_SZ + b) * NHEAD + h] *
                  decayv[((t + 1) * B_SZ + b) * NHEAD + h];
        p *= __shfl_xor(p, 1);
        p *= __shfl_xor(p, 2);
        p *= __shfl_xor(p, 4);
        p *= __shfl_xor(p, 8);
        p *= __shfl_xor(p, 16);
        p *= __shfl_xor(p, 32);
        if (i == 0) sA[s] = p;
    }
    __syncthreads();

    const size_t base = (((size_t)b * NHEAD + h) * PDIM * NSTATE) + (size_t)ec * 2048 + tid * 8;
    float4 P0 = *(const float4*)(Hbuf + base);
    float4 P1 = *(const float4*)(Hbuf + base + 4);
    u16 pk[8];
    pk[0] = f2bf(P0.x); pk[1] = f2bf(P0.y); pk[2] = f2bf(P0.z); pk[3] = f2bf(P0.w);
    pk[4] = f2bf(P1.x); pk[5] = f2bf(P1.y); pk[6] = f2bf(P1.z); pk[7] = f2bf(P1.w);
    *(uint4*)(Hbf + base) = *(const uint4*)pk;
#pragma unroll
    for (int s = 1; s <= NSEG - 2; ++s) {
        float a = sA[s];
        const float* slot = Hbuf + (size_t)s * SLOT + base;
        float4 h0 = *(const float4*)(slot);
        float4 h1 = *(const float4*)(slot + 4);
        P0.x = fmaf(a, P0.x, h0.x); P0.y = fmaf(a, P0.y, h0.y);
        P0.z = fmaf(a, P0.z, h0.z); P0.w = fmaf(a, P0.w, h0.w);
        P1.x = fmaf(a, P1.x, h1.x); P1.y = fmaf(a, P1.y, h1.y);
        P1.z = fmaf(a, P1.z, h1.z); P1.w = fmaf(a, P1.w, h1.w);
        pk[0] = f2bf(P0.x); pk[1] = f2bf(P0.y); pk[2] = f2bf(P0.z); pk[3] = f2bf(P0.w);
        pk[4] = f2bf(P1.x); pk[5] = f2bf(P1.y); pk[6] = f2bf(P1.z); pk[7] = f2bf(P1.w);
        *(uint4*)(Hbf + (size_t)s * SLOT + base) = *(const uint4*)pk;
    }
}

// ---------------- chunk_scan: fused S' build + Y = exp(L).C@Hp^T + S'@X^T ----------------
__global__ __launch_bounds__(256) void chunk_scan(const u16* __restrict__ BCm,
                                                  const float* __restrict__ dtv,
                                                  const float* __restrict__ decayv,
                                                  const u16* __restrict__ Hbf,
                                                  u16* __restrict__ xb) {
    __shared__ __align__(16) u16 sB_[128][68];   // B [t'][n]
    __shared__ __align__(16) u16 sC_[128][68];   // C [t][n]
    __shared__ __align__(16) u16 sS[128][132];   // S' [t][t']
    __shared__ __align__(16) u16 sXT[128][36];   // X^T [p][k-tile]
    __shared__ float sdt[SEGT], sL[SEGT], sEL[SEGT], stmp[32];

    const int blk = blockIdx.x;
    const int seg = blk >> 7, b = (blk >> 4) & 7, h = blk & 15;
    const int tid = threadIdx.x;
    const int wave = tid >> 6, lane = tid & 63;
    const int quad = lane >> 4, lr = lane & 15;
    const int wm = wave & 1, wn = wave >> 1;
    const int t0 = seg * SEGT;

#pragma unroll
    for (int it = 0; it < 4; ++it) {
        int idx = tid + it * 256;
        int t = idx >> 3, c = (idx & 7) * 8;
        int r = (t0 + t) * B_SZ + b;
        *(uint4*)&sB_[t][c] = *(const uint4*)(BCm + (size_t)r * BCSTR + h * NSTATE + c);
        *(uint4*)&sC_[t][c] = *(const uint4*)(BCm + (size_t)r * BCSTR + 1024 + h * NSTATE + c);
    }
    if (tid < SEGT) sdt[tid] = dtv[((t0 + tid) * B_SZ + b) * NHEAD + h];
    else if (tid < 2 * SEGT) {
        int t = tid - SEGT;
        sL[t] = __logf(fmaxf(decayv[((t0 + t) * B_SZ + b) * NHEAD + h], 1e-30f));
    }
    __syncthreads();
    if (tid < 32) {
        float s = 0.f, v[4];
#pragma unroll
        for (int i = 0; i < 4; ++i) { s += sL[tid * 4 + i]; v[i] = s; }
        stmp[tid] = s;
#pragma unroll
        for (int i = 0; i < 4; ++i) sL[tid * 4 + i] = v[i];
    }
    __syncthreads();
    if (tid == 0) {
        float run = 0.f;
        for (int q = 0; q < 32; ++q) { float c2 = stmp[q]; stmp[q] = run; run += c2; }
    }
    __syncthreads();
    if (tid < 32) {
        float off = stmp[tid];
#pragma unroll
        for (int i = 0; i < 4; ++i) sL[tid * 4 + i] += off;
    }
    __syncthreads();
    if (tid < SEGT) sEL[tid] = __expf(sL[tid]);

    floatx4 accS[4][4];
#pragma unroll
    for (int i = 0; i < 4; i++)
#pragma unroll
        for (int j = 0; j < 4; j++)
#pragma unroll
            for (int r = 0; r < 4; r++) accS[i][j][r] = 0.f;
#pragma unroll
    for (int k0 = 0; k0 < 64; k0 += 32) {
        bf16x8 af[4], bfr[4];
#pragma unroll
        for (int i = 0; i < 4; i++)
            af[i] = *(const bf16x8*)&sB_[wm * 64 + i * 16 + lr][k0 + quad * 8];
#pragma unroll
        for (int j = 0; j < 4; j++)
            bfr[j] = *(const bf16x8*)&sC_[wn * 64 + j * 16 + lr][k0 + quad * 8];
#pragma unroll
        for (int i = 0; i < 4; i++)
#pragma unroll
            for (int j = 0; j < 4; j++)
                accS[i][j] = __builtin_amdgcn_mfma_f32_16x16x32_bf16(af[i], bfr[j], accS[i][j], 0, 0, 0);
    }
#pragma unroll
    for (int j = 0; j < 4; j++) {
        int tt = wn * 64 + j * 16 + lr;
        float Lt = sL[tt];
#pragma unroll
        for (int i = 0; i < 4; i++) {
#pragma unroll
            for (int r = 0; r < 4; r++) {
                int tp = wm * 64 + i * 16 + quad * 4 + r;
                float v = 0.f;
                if (tp <= tt) v = accS[i][j][r] * sdt[tp] * __expf(Lt - sL[tp]);
                sS[tt][tp] = f2bf(v);
            }
        }
    }

    floatx4 acc[4][4];
#pragma unroll
    for (int i = 0; i < 4; i++)
#pragma unroll
        for (int j = 0; j < 4; j++)
#pragma unroll
            for (int r = 0; r < 4; r++) acc[i][j][r] = 0.f;
    __syncthreads();
    if (seg > 0) {
        const u16* hbase = Hbf + (size_t)(seg - 1) * SLOT + (((size_t)b * NHEAD + h) * PDIM) * NSTATE;
#pragma unroll
        for (int k0 = 0; k0 < 64; k0 += 32) {
            bf16x8 af[4], bfr[4];
#pragma unroll
            for (int i = 0; i < 4; i++)
                af[i] = *(const bf16x8*)&sC_[wm * 64 + i * 16 + lr][k0 + quad * 8];
#pragma unroll
            for (int j = 0; j < 4; j++)
                bfr[j] = *(const bf16x8*)(hbase + (size_t)(wn * 64 + j * 16 + lr) * NSTATE + k0 + quad * 8);
#pragma unroll
            for (int i = 0; i < 4; i++)
#pragma unroll
                for (int j = 0; j < 4; j++)
                    acc[i][j] = __builtin_amdgcn_mfma_f32_16x16x32_bf16(af[i], bfr[j], acc[i][j], 0, 0, 0);
        }
#pragma unroll
        for (int i = 0; i < 4; i++) {
#pragma unroll
            for (int r = 0; r < 4; r++) {
                float el = sEL[wm * 64 + i * 16 + quad * 4 + r];
#pragma unroll
                for (int j = 0; j < 4; j++) acc[i][j][r] *= el;
            }
        }
    }

    const int px = tid & 127, koh = (tid >> 7) * 16;
    for (int kc = 0; kc < 128; kc += 32) {
        u16 xv[16];
#pragma unroll
        for (int j2 = 0; j2 < 16; ++j2) {
            int tp = kc + koh + j2;
            xv[j2] = xb[(size_t)((t0 + tp) * B_SZ + b) * D_IN + h * PDIM + px];
        }
        __syncthreads();
        *(uint4*)&sXT[px][koh]     = *(const uint4*)&xv[0];
        *(uint4*)&sXT[px][koh + 8] = *(const uint4*)&xv[8];
        __syncthreads();
        bf16x8 af[4], bfr[4];
#pragma unroll
        for (int i = 0; i < 4; i++)
            af[i] = *(const bf16x8*)&sS[wm * 64 + i * 16 + lr][kc + quad * 8];
#pragma unroll
        for (int j = 0; j < 4; j++)
            bfr[j] = *(const bf16x8*)&sXT[wn * 64 + j * 16 + lr][quad * 8];
#pragma unroll
        for (int i = 0; i < 4; i++)
#pragma unroll
            for (int j = 0; j < 4; j++)
                acc[i][j] = __builtin_amdgcn_mfma_f32_16x16x32_bf16(af[i], bfr[j], acc[i][j], 0, 0, 0);
    }

#pragma unroll
    for (int j = 0; j < 4; j++) {
        int p = wn * 64 + j * 16 + lr;
#pragma unroll
        for (int i = 0; i < 4; i++) {
#pragma unroll
            for (int r = 0; r < 4; r++) {
                int t = wm * 64 + i * 16 + quad * 4 + r;
                xb[(size_t)((t0 + t) * B_SZ + b) * D_IN + h * PDIM + p] = f2bf(acc[i][j][r]);
            }
        }
    }
}

// ---------------- launch ----------------
extern "C" void kernel_launch(void* const* d_in, const int* in_sizes, int n_in,
                              void* d_out, int out_size, void* d_ws, size_t ws_size,
                              hipStream_t stream) {
    const float* obs     = (const float*)d_in[0];
    const float* W_in    = (const float*)d_in[1];
    const float* b_in    = (const float*)d_in[2];
    const float* A_log   = (const float*)d_in[3];
    const float* dt_bias = (const float*)d_in[4];
    const float* W_dt    = (const float*)d_in[5];
    const float* W_B     = (const float*)d_in[6];
    const float* W_C     = (const float*)d_in[7];
    const float* W_yo    = (const float*)d_in[8];
    const float* b_yo    = (const float*)d_in[9];
    const float* W_head  = (const float*)d_in[10];
    const float* b_head  = (const float*)d_in[11];

    char* ws = (char*)d_ws;
    size_t o = 0;
    u16*   xb     = (u16*)(ws + o);   o += (size_t)ROWS * D_IN * 2;            // 16 MB (x, then y in-place)
    u16*   BCm    = (u16*)(ws + o);   o += (size_t)ROWS * BCSTR * 2;           // 17.8 MB (B | C | pad)
    float* dtv    = (float*)(ws + o); o += (size_t)ROWS * NHEAD * 4;
    float* decayv = (float*)(ws + o); o += (size_t)ROWS * NHEAD * 4;
    u16*   zb     = (u16*)(ws + o);   o += (size_t)ROWS * NUNITS * 2;          // 2 MB
    float* Hseg   = (float*)(ws + o); o += (size_t)(NSEG - 1) * SLOT * 4;      // 12 MB
    u16*   Hbf    = (u16*)(ws + o);   o += (size_t)(NSEG - 1) * SLOT * 2;      // 6 MB
    u16*   obsb   = (u16*)(ws + o);   o += (size_t)ROWS * OBS_D * 2;           // 2 MB
    u16*   WinT   = (u16*)(ws + o);   o += (size_t)D_IN * OBS_D * 2;           // 1 MB
    u16*   WBCT   = (u16*)(ws + o);   o += (size_t)BCN * D_IN * 2;             // 8 MB
    u16*   WdtT   = (u16*)(ws + o);   o += (size_t)NHEAD * D_IN * 2;           // 64 KB
    u16*   WyoT   = (u16*)(ws + o);   o += (size_t)NUNITS * D_IN * 2;          // 1 MB
    u16*   WheadT = (u16*)(ws + o);   o += (size_t)NACT * NUNITS * 2;

    // zero-work launch of the harness-required symbol (kept referenced)
    ActorAgent_27625229647898_kernel<<<dim3(1), 256, 0, stream>>>((float*)d_out, 0, 0.f);

    // ---- all weight prep in one launch ----
    prep<<<dim3(160 + 5136), 256, 0, stream>>>(obs, W_dt, W_in, W_B, W_C, W_yo, W_head,
                                               obsb, WinT, WBCT, WdtT, WyoT, WheadT);

    // ---- x = relu(obs @ W_in + b_in) -> bf16 ----
    gemm_bt128<1, 1, 1><<<dim3(32, 16), 256, 0, stream>>>(obsb, WinT, b_in, xb, ROWS, D_IN, OBS_D, D_IN);
    // ---- dt = softplus(x @ W_dt + dt_bias); decay = exp(-exp(A_log)*dt) ----
    dtdecay<<<dim3(256), 512, 0, stream>>>(xb, WdtT, dt_bias, A_log, dtv, decayv);
    // ---- B|C projection: N=2048 (16 tiles -> 512 blocks = 2/CU), ldc=2176 (non-pow2 stride) ----
    gemm_bt128<0, 1, 0><<<dim3(32, 16), 256, 0, stream>>>(xb, WBCT, (const float*)nullptr, BCm, ROWS, BCN, D_IN, BCSTR);
    // ---- scan: A) segment-local final states ----
    seg_state<<<dim3((NSEG - 1) * 128), 256, 0, stream>>>(xb, BCm, dtv, decayv, Hseg);
    //          B) prefix combine -> bf16 ----
    seg_prefix<<<dim3(512), 256, 0, stream>>>(Hseg, decayv, Hbf);
    //          C) fused S' + Y, in-place over xb ----
    chunk_scan<<<dim3(NSEG * 128), 256, 0, stream>>>(BCm, dtv, decayv, Hbf, xb);
    // ---- z = relu(y @ W_yo + b_yo) -> bf16 ----
    gemm_bt64<1, 1><<<dim3(64, 4), 256, 0, stream>>>(xb, WyoT, b_yo, zb, ROWS, NUNITS, D_IN);
    // ---- logits = z @ W_head + b_head -> d_out (fp32) ----
    gemm_bt64<0, 0><<<dim3(64, 1), 256, 0, stream>>>(zb, WheadT, b_head, (float*)d_out, ROWS, NACT, NUNITS);
}

// Round 5
// 247.507 us; speedup vs baseline: 1.1004x; 1.0305x over previous
//
#include <hip/hip_runtime.h>
#include <cstdint>
#include <cstddef>

typedef unsigned short u16;
typedef __attribute__((ext_vector_type(8))) __bf16 bf16x8;   // MFMA A/B operand
typedef __attribute__((ext_vector_type(4))) float floatx4;   // MFMA C/D operand

// dims
#define T_DIM   512
#define B_SZ    8
#define ROWS    4096      // T*B
#define OBS_D   256
#define D_IN    2048
#define NHEAD   16
#define NSTATE  64
#define PDIM    128
#define NUNITS  256
#define NACT    64
#define NSEG    4
#define SEGT    128       // T_DIM / NSEG
#define SLOT    (B_SZ * NHEAD * PDIM * NSTATE)   // 1048576 elems per seg-state slot
// BCm holds B(1024) | C(1024) | pad(128). GEMM computes N=2048 (16 tiles ->
// 512 blocks = exactly 2/CU) but WRITES with ldc=2176 (non-pow2 row stride;
// pow2 stride aliased L2 sets in seg_state/chunk_scan reads — r18 lesson).
#define BCSTR   2176      // row stride of BCm (u16 elems)
#define BCN     2048      // computed columns (B|C)

__host__ __device__ __forceinline__ float bf2f(u16 u) {
    union { uint32_t i; float f; } v; v.i = ((uint32_t)u) << 16; return v.f;
}
__host__ __device__ __forceinline__ u16 f2bf(float f) {
    union { float f; uint32_t i; } v; v.f = f;
    uint32_t r = v.i + 0x7FFFu + ((v.i >> 16) & 1u);
    return (u16)(r >> 16);
}

// async 16B/lane global->LDS (m97 pattern). lds ptr must be wave-uniform.
__device__ __forceinline__ void glds16(const u16* g, u16* l) {
    __builtin_amdgcn_global_load_lds(
        (__attribute__((address_space(1))) void*)g,
        (__attribute__((address_space(3))) void*)l, 16, 0, 0);
}

// ---------------- harness-required symbol (zero-work launch keeps it referenced) ----------------
__global__ __launch_bounds__(256) void ActorAgent_27625229647898_kernel(
        float* __restrict__ out, int n, float v) {
    for (int i = blockIdx.x * 256 + threadIdx.x; i < n; i += gridDim.x * 256)
        out[i] = v;
}

// ---------------- prep: all weight converts + transposes in ONE launch ----------------
__global__ __launch_bounds__(256) void prep(const float* __restrict__ obs,
                                            const float* __restrict__ W_dt,
                                            const float* __restrict__ W_in,
                                            const float* __restrict__ W_B,
                                            const float* __restrict__ W_C,
                                            const float* __restrict__ W_yo,
                                            const float* __restrict__ W_head,
                                            u16* __restrict__ obsb,
                                            u16* __restrict__ WinT, u16* __restrict__ WBCT,
                                            u16* __restrict__ WdtT,
                                            u16* __restrict__ WyoT, u16* __restrict__ WheadT) {
    int bid = blockIdx.x;
    if (bid < 160) {
        const int NOBS = ROWS * OBS_D;             // 1048576
        const int NDT  = D_IN * NHEAD;             // 32768
        for (int i = bid * 256 + threadIdx.x; i < NOBS + NDT; i += 160 * 256) {
            if (i < NOBS) obsb[i] = f2bf(obs[i]);
            else {
                int j = i - NOBS;                  // j = k*16 + n
                int k = j >> 4, n = j & 15;
                WdtT[n * D_IN + k] = f2bf(W_dt[j]);
            }
        }
        return;
    }
    bid -= 160;
    const float* src; u16* dst; int R, C, bx, by;
    if (bid < 512)       { src = W_in;   dst = WinT;   R = 256;  C = 2048; bx = bid & 63; by = bid >> 6; }
    else if (bid < 2560) { int i = bid - 512;  src = W_B;  dst = WBCT; R = 2048; C = 1024; bx = i & 31; by = i >> 5; }
    else if (bid < 4608) { int i = bid - 2560; src = W_C;  dst = WBCT + (size_t)1024 * 2048; R = 2048; C = 1024; bx = i & 31; by = i >> 5; }
    else if (bid < 5120) { int i = bid - 4608; src = W_yo; dst = WyoT; R = 2048; C = 256;  bx = i & 7;  by = i >> 3; }
    else                 { int i = bid - 5120; src = W_head; dst = WheadT; R = 256; C = 64; bx = i & 1; by = i >> 1; }
    __shared__ float t[32][33];
    int c0 = bx * 32, r0 = by * 32;
    int tx = threadIdx.x & 31, ty = threadIdx.x >> 5;
#pragma unroll
    for (int i = 0; i < 32; i += 8)
        t[ty + i][tx] = src[(size_t)(r0 + ty + i) * C + c0 + tx];
    __syncthreads();
#pragma unroll
    for (int i = 0; i < 32; i += 8)
        dst[(size_t)(c0 + ty + i) * R + r0 + tx] = f2bf(t[tx][ty + i]);
}

// ---------------- bt128: 128x128 bf16 MFMA GEMM, B^T (N,K), BK=32 glds staging ----------------
// r22: T4 counted-vmcnt pipeline, depth 2, 3 LDS buffers. The r21 depth-1 dbuf
// still waited a full load round-trip per iter (vmcnt(0) right after issuing
// the next tile; 16 MFMA ~100cyc can't cover ~300cyc latency -> MfmaUtil 22%).
// Now tile t+2 is staged while waiting only for tile t (issued 2 iters ago,
// already landed) via vmcnt(8) -> wait ~0. Buffer-reuse safe: STAGE(t+2)
// overwrites tile t-1's buffer, whose reads finished before the end barrier
// of iter t-1. vmcnt is per-wave, so barrier #1 after the wait makes all
// waves' tile-t loads visible. Tail peeled: vmcnt(4), vmcnt(0).
// NOTE (r14/r15/r17): BK=64, 128x64 tile, XCD swizzle all regress.
template <int ACT, int OUT_BF16, int HAS_BIAS>
__global__ __launch_bounds__(256) void gemm_bt128(const u16* __restrict__ A,
                                                  const u16* __restrict__ BT,
                                                  const float* __restrict__ bias,
                                                  void* __restrict__ Cout,
                                                  int M, int N, int K, int ldc) {
    __shared__ __align__(16) u16 sA[3][128 * 32];   // 3 x 8 KB
    __shared__ __align__(16) u16 sB[3][128 * 32];
    const int tid  = threadIdx.x;
    const int wave = tid >> 6, lane = tid & 63;
    const int quad = lane >> 4, lr = lane & 15;
    const int wm = wave & 1, wn = wave >> 1;
    const int m0 = blockIdx.x * 128, n0 = blockIdx.y * 128;
    const int r0 = wave * 32 + (lane >> 2);   // staged row per lane
    const int kel = (lane & 3) * 8;           // k offset (u16) per lane

    floatx4 acc[4][4];
#pragma unroll
    for (int i = 0; i < 4; i++)
#pragma unroll
        for (int j = 0; j < 4; j++)
#pragma unroll
            for (int r = 0; r < 4; r++) acc[i][j][r] = 0.f;

    const u16* apg = A + (size_t)(m0 + r0) * K + kel;
    const u16* bpg = BT + (size_t)(n0 + r0) * K + kel;
    const int lofs = (wave * 32) * 32;
    const int ntk = K >> 5;   // K tiles (>= 3 for all uses: 8, 64)

#define STAGE128(t, sb) do {                                        \
        int kk_ = (t) << 5;                                         \
        glds16(apg + kk_, &sA[sb][lofs]);                           \
        glds16(apg + (size_t)16 * K + kk_, &sA[sb][lofs + 16 * 32]);\
        glds16(bpg + kk_, &sB[sb][lofs]);                           \
        glds16(bpg + (size_t)16 * K + kk_, &sB[sb][lofs + 16 * 32]);\
    } while (0)

    STAGE128(0, 0);
    STAGE128(1, 1);
    int s = 0;
    for (int t = 0; t < ntk; ++t) {
        if (t + 2 < ntk) {
            int ns = s + 2; if (ns >= 3) ns -= 3;
            STAGE128(t + 2, ns);                                // 12 in flight
            asm volatile("s_waitcnt vmcnt(8)" ::: "memory");    // tile t landed
        } else if (t + 1 < ntk) {
            asm volatile("s_waitcnt vmcnt(4)" ::: "memory");
        } else {
            asm volatile("s_waitcnt vmcnt(0)" ::: "memory");
        }
        __builtin_amdgcn_s_barrier();     // all waves' tile-t loads visible
        asm volatile("" ::: "memory");
        bf16x8 af[4], bfr[4];
#pragma unroll
        for (int i = 0; i < 4; i++)
            af[i] = *(const bf16x8*)&sA[s][(wm * 64 + i * 16 + lr) * 32 + quad * 8];
#pragma unroll
        for (int j = 0; j < 4; j++)
            bfr[j] = *(const bf16x8*)&sB[s][(wn * 64 + j * 16 + lr) * 32 + quad * 8];
#pragma unroll
        for (int i = 0; i < 4; i++)
#pragma unroll
            for (int j = 0; j < 4; j++)
                acc[i][j] = __builtin_amdgcn_mfma_f32_16x16x32_bf16(af[i], bfr[j], acc[i][j], 0, 0, 0);
        asm volatile("" ::: "memory");
        __builtin_amdgcn_s_barrier();     // all reads of buf s done (reuse guard)
        ++s; if (s == 3) s = 0;
    }
#undef STAGE128
    // C/D layout: col = lane&15, row = quad*4 + reg
#pragma unroll
    for (int j = 0; j < 4; j++) {
        int col = n0 + wn * 64 + j * 16 + lr;
        float bvv = HAS_BIAS ? bias[col] : 0.f;
#pragma unroll
        for (int i = 0; i < 4; i++) {
#pragma unroll
            for (int r = 0; r < 4; r++) {
                int row = m0 + wm * 64 + i * 16 + quad * 4 + r;
                float v = acc[i][j][r] + bvv;
                if (ACT) v = fmaxf(v, 0.f);
                if (OUT_BF16) ((u16*)Cout)[(size_t)row * ldc + col] = f2bf(v);
                else          ((float*)Cout)[(size_t)row * ldc + col] = v;
            }
        }
    }
}

// ---------------- bt64: 64x64 bf16 MFMA GEMM, B^T layout, BK=64, depth-2 pipeline ----------------
template <int ACT, int OUT_BF16>
__global__ __launch_bounds__(256) void gemm_bt64(const u16* __restrict__ A,
                                                 const u16* __restrict__ BT,
                                                 const float* __restrict__ bias,
                                                 void* __restrict__ Cout,
                                                 int M, int N, int K) {
    __shared__ __align__(16) u16 sA[3][64 * 64];  // 3 x 8 KB
    __shared__ __align__(16) u16 sB[3][64 * 64];
    const int tid  = threadIdx.x;
    const int wave = tid >> 6, lane = tid & 63;
    const int quad = lane >> 4, lr = lane & 15;
    const int m0 = blockIdx.x * 64, n0 = blockIdx.y * 64;
    const int srl = lane >> 3, sc = (lane & 7) * 8;

    floatx4 acc[4];
#pragma unroll
    for (int i = 0; i < 4; i++)
#pragma unroll
        for (int j = 0; j < 4; j++) acc[i][j] = 0.f;

    const u16* apg = A + (size_t)(m0 + wave * 16 + srl) * K + sc;
    const u16* bpg = BT + (size_t)(n0 + wave * 16 + srl) * K + sc;
    const int ntk = K >> 6;   // K tiles (>= 3 for K=2048; K=256 -> 4)

#define STAGE64(t, sb) do {                                            \
        int kk_ = (t) << 6;                                            \
        glds16(apg + kk_,                 &sA[sb][(wave * 16) * 64]);  \
        glds16(apg + (size_t)8 * K + kk_, &sA[sb][(wave * 16 + 8) * 64]);\
        glds16(bpg + kk_,                 &sB[sb][(wave * 16) * 64]);  \
        glds16(bpg + (size_t)8 * K + kk_, &sB[sb][(wave * 16 + 8) * 64]);\
    } while (0)

    STAGE64(0, 0);
    STAGE64(1, 1);
    int s = 0;
    for (int t = 0; t < ntk; ++t) {
        if (t + 2 < ntk) {
            int ns = s + 2; if (ns >= 3) ns -= 3;
            STAGE64(t + 2, ns);
            asm volatile("s_waitcnt vmcnt(8)" ::: "memory");
        } else if (t + 1 < ntk) {
            asm volatile("s_waitcnt vmcnt(4)" ::: "memory");
        } else {
            asm volatile("s_waitcnt vmcnt(0)" ::: "memory");
        }
        __builtin_amdgcn_s_barrier();
        asm volatile("" ::: "memory");
#pragma unroll
        for (int ks = 0; ks < 2; ++ks) {
            bf16x8 af = *(const bf16x8*)&sA[s][(wave * 16 + lr) * 64 + ks * 32 + quad * 8];
#pragma unroll
            for (int nt = 0; nt < 4; nt++) {
                bf16x8 bf = *(const bf16x8*)&sB[s][(nt * 16 + lr) * 64 + ks * 32 + quad * 8];
                acc[nt] = __builtin_amdgcn_mfma_f32_16x16x32_bf16(af, bf, acc[nt], 0, 0, 0);
            }
        }
        asm volatile("" ::: "memory");
        __builtin_amdgcn_s_barrier();
        ++s; if (s == 3) s = 0;
    }
#undef STAGE64
#pragma unroll
    for (int nt = 0; nt < 4; nt++) {
        int col = n0 + nt * 16 + lr;
        float bvv = bias ? bias[col] : 0.f;
#pragma unroll
        for (int r = 0; r < 4; r++) {
            int row = m0 + wave * 16 + quad * 4 + r;
            float v = acc[nt][r] + bvv;
            if (ACT) v = fmaxf(v, 0.f);
            if (OUT_BF16) ((u16*)Cout)[(size_t)row * N + col] = f2bf(v);
            else          ((float*)Cout)[(size_t)row * N + col] = v;
        }
    }
}

// ---------------- dtdecay: dtraw = x @ W_dt, fused softplus + decay ----------------
// r22: the wave's 2 rows are processed TOGETHER in one k-pass so the 32
// weight bf2f converts per k-step are shared (112 vs 144 VALU/k0, -22% on a
// VALU-bound kernel). 256 blocks x 16 rows.
__global__ __launch_bounds__(512) void dtdecay(const u16* __restrict__ xb,
                                               const u16* __restrict__ WdtT,
                                               const float* __restrict__ dt_bias,
                                               const float* __restrict__ A_log,
                                               float* __restrict__ dtv,
                                               float* __restrict__ decayv) {
    __shared__ __align__(16) u16 sw[NHEAD * D_IN];   // 64 KB, [h][k]
    const int tid = threadIdx.x;
#pragma unroll
    for (int i = 0; i < 8; ++i) {
        int idx = (tid + i * 512) * 8;
        *(uint4*)&sw[idx] = *(const uint4*)(WdtT + idx);
    }
    __syncthreads();
    const int wave = tid >> 6, lane = tid & 63;
    const int q = lane >> 4, lr = lane & 15;
    const int row0 = blockIdx.x * 16 + wave * 2;
    const u16* xp0 = xb + (size_t)row0 * D_IN;
    const u16* xp1 = xb + (size_t)(row0 + 1) * D_IN;
    float acc0[4] = {0.f, 0.f, 0.f, 0.f};
    float acc1[4] = {0.f, 0.f, 0.f, 0.f};
#pragma unroll 4
    for (int k0 = 0; k0 < 16; ++k0) {
        const int kk = k0 * 128 + lr * 8;
        uint4 xv0 = *(const uint4*)(xp0 + kk);
        uint4 xv1 = *(const uint4*)(xp1 + kk);
        const u16* xu0 = (const u16*)&xv0;
        const u16* xu1 = (const u16*)&xv1;
        float xf0[8], xf1[8];
#pragma unroll
        for (int j = 0; j < 8; ++j) { xf0[j] = bf2f(xu0[j]); xf1[j] = bf2f(xu1[j]); }
#pragma unroll
        for (int j = 0; j < 4; ++j) {
            uint4 wv = *(const uint4*)&sw[(q * 4 + j) * D_IN + kk];
            const u16* wu = (const u16*)&wv;
#pragma unroll
            for (int jj = 0; jj < 8; ++jj) {
                float wf = bf2f(wu[jj]);
                acc0[j] = fmaf(xf0[jj], wf, acc0[j]);
                acc1[j] = fmaf(xf1[jj], wf, acc1[j]);
            }
        }
    }
    // reduce across the 16 lanes of each quad (masks 1,2,4,8 stay in-quad)
#pragma unroll
    for (int m = 1; m <= 8; m <<= 1)
#pragma unroll
        for (int j = 0; j < 4; ++j) {
            acc0[j] += __shfl_xor(acc0[j], m);
            acc1[j] += __shfl_xor(acc1[j], m);
        }
    if (lr == 0) {
#pragma unroll
        for (int j = 0; j < 4; ++j) {
            int h = q * 4 + j;
            float ae = expf(A_log[h]);
            float z0 = acc0[j] + dt_bias[h];
            float sp0 = (z0 > 20.f) ? z0 : log1pf(expf(z0));
            float z1 = acc1[j] + dt_bias[h];
            float sp1 = (z1 > 20.f) ? z1 : log1pf(expf(z1));
            dtv[row0 * NHEAD + h] = sp0;
            decayv[row0 * NHEAD + h] = expf(-ae * sp0);
            dtv[(row0 + 1) * NHEAD + h] = sp1;
            decayv[(row0 + 1) * NHEAD + h] = expf(-ae * sp1);
        }
    }
}

// ---------------- seg_state: segment-final states as weighted outer-product sum ----------------
__global__ __launch_bounds__(256) void seg_state(const u16* __restrict__ xw,
                                                 const u16* __restrict__ BCm,
                                                 const float* __restrict__ dtv,
                                                 const float* __restrict__ decayv,
                                                 float* __restrict__ Hbuf) {
    const int blk = blockIdx.x;
    const int seg = blk >> 7;
    const int b   = (blk >> 4) & 7;
    const int h   = blk & 15;
    const int tid = threadIdx.x;
    const int pgrp = tid >> 3;
    const int oct  = tid & 7;

    __shared__ __align__(16) u16 sx[SEGT][PDIM];
    __shared__ __align__(16) u16 sbm[SEGT][NSTATE];
    __shared__ float sw[SEGT];
    __shared__ float sdt[SEGT];
    __shared__ float sdec[SEGT];
    __shared__ float sP[32];

    const int t0 = seg * SEGT;

#pragma unroll
    for (int k = 0; k < 8; ++k) {
        int idx = tid + k * 256;
        int t = idx >> 4, c = (idx & 15) * 8;
        int r = (t0 + t) * B_SZ + b;
        *(uint4*)&sx[t][c] = *(const uint4*)(xw + (size_t)r * D_IN + h * PDIM + c);
    }
#pragma unroll
    for (int k = 0; k < 4; ++k) {
        int idx = tid + k * 256;
        int t = idx >> 3, c = (idx & 7) * 8;
        int r = (t0 + t) * B_SZ + b;
        *(uint4*)&sbm[t][c] = *(const uint4*)(BCm + (size_t)r * BCSTR + h * NSTATE + c);
    }
    if (tid < SEGT)            sdt[tid] = dtv[((t0 + tid) * B_SZ + b) * NHEAD + h];
    else if (tid < 2 * SEGT)   sdec[tid - SEGT] = decayv[((t0 + tid - SEGT) * B_SZ + b) * NHEAD + h];
    __syncthreads();

    if (tid < 32) {
        float p = 1.f;
        for (int i = 3; i >= 0; --i) {
            int t = tid * 4 + i;
            sw[t] = sdt[t] * p;
            p *= sdec[t];
        }
        sP[tid] = p;
    }
    __syncthreads();
    if (tid == 0) {
        float suf = 1.f;
        for (int q = 31; q >= 0; --q) { float tmp = sP[q]; sP[q] = suf; suf *= tmp; }
    }
    __syncthreads();
    if (tid < 32) {
        float m = sP[tid];
        for (int i = 0; i < 4; ++i) sw[tid * 4 + i] *= m;
    }
    __syncthreads();

    float acc[4][8];
#pragma unroll
    for (int i = 0; i < 4; i++)
#pragma unroll
        for (int j = 0; j < 8; j++) acc[i][j] = 0.f;

    for (int t = 0; t < SEGT; ++t) {
        float w = sw[t];
        const u16* xp = &sx[t][pgrp * 4];
        const u16* bp = &sbm[t][oct * 8];
        float xv[4], bv[8];
#pragma unroll
        for (int i = 0; i < 4; i++) xv[i] = w * bf2f(xp[i]);
#pragma unroll
        for (int j = 0; j < 8; j++) bv[j] = bf2f(bp[j]);
#pragma unroll
        for (int i = 0; i < 4; i++)
#pragma unroll
            for (int j = 0; j < 8; j++)
                acc[i][j] = fmaf(xv[i], bv[j], acc[i][j]);
    }

    float* base = Hbuf + (size_t)seg * SLOT +
                  (((size_t)b * NHEAD + h) * PDIM + pgrp * 4) * NSTATE + oct * 8;
#pragma unroll
    for (int i = 0; i < 4; i++) {
        *(float4*)(base + (size_t)i * NSTATE)     = make_float4(acc[i][0], acc[i][1], acc[i][2], acc[i][3]);
        *(float4*)(base + (size_t)i * NSTATE + 4) = make_float4(acc[i][4], acc[i][5], acc[i][6], acc[i][7]);
    }
}

// ---------------- prefix combine -> bf16 prefix states Hbf ----------------
__global__ __launch_bounds__(256) void seg_prefix(const float* __restrict__ Hbuf,
                                                  const float* __restrict__ decayv,
                                                  u16* __restrict__ Hbf) {
    const int blk = blockIdx.x;
    const int b  = blk >> 6;
    const int h  = (blk >> 2) & 15;
    const int ec = blk & 3;
    const int tid = threadIdx.x;

    __shared__ float sA[NSEG];

    if (tid < 64 * (NSEG - 2)) {
        int s = 1 + (tid >> 6);
        int i = tid & 63;
        int t = s * SEGT + i * 2;
        float p = decayv[(t * B_SZ + b) * NHEAD + h] *
                  decayv[((t + 1) * B_SZ + b) * NHEAD + h];
        p *= __shfl_xor(p, 1);
        p *= __shfl_xor(p, 2);
        p *= __shfl_xor(p, 4);
        p *= __shfl_xor(p, 8);
        p *= __shfl_xor(p, 16);
        p *= __shfl_xor(p, 32);
        if (i == 0) sA[s] = p;
    }
    __syncthreads();

    const size_t base = (((size_t)b * NHEAD + h) * PDIM * NSTATE) + (size_t)ec * 2048 + tid * 8;
    float4 P0 = *(const float4*)(Hbuf + base);
    float4 P1 = *(const float4*)(Hbuf + base + 4);
    u16 pk[8];
    pk[0] = f2bf(P0.x); pk[1] = f2bf(P0.y); pk[2] = f2bf(P0.z); pk[3] = f2bf(P0.w);
    pk[4] = f2bf(P1.x); pk[5] = f2bf(P1.y); pk[6] = f2bf(P1.z); pk[7] = f2bf(P1.w);
    *(uint4*)(Hbf + base) = *(const uint4*)pk;
#pragma unroll
    for (int s = 1; s <= NSEG - 2; ++s) {
        float a = sA[s];
        const float* slot = Hbuf + (size_t)s * SLOT + base;
        float4 h0 = *(const float4*)(slot);
        float4 h1 = *(const float4*)(slot + 4);
        P0.x = fmaf(a, P0.x, h0.x); P0.y = fmaf(a, P0.y, h0.y);
        P0.z = fmaf(a, P0.z, h0.z); P0.w = fmaf(a, P0.w, h0.w);
        P1.x = fmaf(a, P1.x, h1.x); P1.y = fmaf(a, P1.y, h1.y);
        P1.z = fmaf(a, P1.z, h1.z); P1.w = fmaf(a, P1.w, h1.w);
        pk[0] = f2bf(P0.x); pk[1] = f2bf(P0.y); pk[2] = f2bf(P0.z); pk[3] = f2bf(P0.w);
        pk[4] = f2bf(P1.x); pk[5] = f2bf(P1.y); pk[6] = f2bf(P1.z); pk[7] = f2bf(P1.w);
        *(uint4*)(Hbf + (size_t)s * SLOT + base) = *(const uint4*)pk;
    }
}

// ---------------- chunk_scan: fused S' build + Y = exp(L).C@Hp^T + S'@X^T ----------------
__global__ __launch_bounds__(256) void chunk_scan(const u16* __restrict__ BCm,
                                                  const float* __restrict__ dtv,
                                                  const float* __restrict__ decayv,
                                                  const u16* __restrict__ Hbf,
                                                  u16* __restrict__ xb) {
    __shared__ __align__(16) u16 sB_[128][68];   // B [t'][n]
    __shared__ __align__(16) u16 sC_[128][68];   // C [t][n]
    __shared__ __align__(16) u16 sS[128][132];   // S' [t][t']
    __shared__ __align__(16) u16 sXT[128][36];   // X^T [p][k-tile]
    __shared__ float sdt[SEGT], sL[SEGT], sEL[SEGT], stmp[32];

    const int blk = blockIdx.x;
    const int seg = blk >> 7, b = (blk >> 4) & 7, h = blk & 15;
    const int tid = threadIdx.x;
    const int wave = tid >> 6, lane = tid & 63;
    const int quad = lane >> 4, lr = lane & 15;
    const int wm = wave & 1, wn = wave >> 1;
    const int t0 = seg * SEGT;

#pragma unroll
    for (int it = 0; it < 4; ++it) {
        int idx = tid + it * 256;
        int t = idx >> 3, c = (idx & 7) * 8;
        int r = (t0 + t) * B_SZ + b;
        *(uint4*)&sB_[t][c] = *(const uint4*)(BCm + (size_t)r * BCSTR + h * NSTATE + c);
        *(uint4*)&sC_[t][c] = *(const uint4*)(BCm + (size_t)r * BCSTR + 1024 + h * NSTATE + c);
    }
    if (tid < SEGT) sdt[tid] = dtv[((t0 + tid) * B_SZ + b) * NHEAD + h];
    else if (tid < 2 * SEGT) {
        int t = tid - SEGT;
        sL[t] = __logf(fmaxf(decayv[((t0 + t) * B_SZ + b) * NHEAD + h], 1e-30f));
    }
    __syncthreads();
    if (tid < 32) {
        float s = 0.f, v[4];
#pragma unroll
        for (int i = 0; i < 4; ++i) { s += sL[tid * 4 + i]; v[i] = s; }
        stmp[tid] = s;
#pragma unroll
        for (int i = 0; i < 4; ++i) sL[tid * 4 + i] = v[i];
    }
    __syncthreads();
    if (tid == 0) {
        float run = 0.f;
        for (int q = 0; q < 32; ++q) { float c2 = stmp[q]; stmp[q] = run; run += c2; }
    }
    __syncthreads();
    if (tid < 32) {
        float off = stmp[tid];
#pragma unroll
        for (int i = 0; i < 4; ++i) sL[tid * 4 + i] += off;
    }
    __syncthreads();
    if (tid < SEGT) sEL[tid] = __expf(sL[tid]);

    floatx4 accS[4][4];
#pragma unroll
    for (int i = 0; i < 4; i++)
#pragma unroll
        for (int j = 0; j < 4; j++)
#pragma unroll
            for (int r = 0; r < 4; r++) accS[i][j][r] = 0.f;
#pragma unroll
    for (int k0 = 0; k0 < 64; k0 += 32) {
        bf16x8 af[4], bfr[4];
#pragma unroll
        for (int i = 0; i < 4; i++)
            af[i] = *(const bf16x8*)&sB_[wm * 64 + i * 16 + lr][k0 + quad * 8];
#pragma unroll
        for (int j = 0; j < 4; j++)
            bfr[j] = *(const bf16x8*)&sC_[wn * 64 + j * 16 + lr][k0 + quad * 8];
#pragma unroll
        for (int i = 0; i < 4; i++)
#pragma unroll
            for (int j = 0; j < 4; j++)
                accS[i][j] = __builtin_amdgcn_mfma_f32_16x16x32_bf16(af[i], bfr[j], accS[i][j], 0, 0, 0);
    }
#pragma unroll
    for (int j = 0; j < 4; j++) {
        int tt = wn * 64 + j * 16 + lr;
        float Lt = sL[tt];
#pragma unroll
        for (int i = 0; i < 4; i++) {
#pragma unroll
            for (int r = 0; r < 4; r++) {
                int tp = wm * 64 + i * 16 + quad * 4 + r;
                float v = 0.f;
                if (tp <= tt) v = accS[i][j][r] * sdt[tp] * __expf(Lt - sL[tp]);
                sS[tt][tp] = f2bf(v);
            }
        }
    }

    floatx4 acc[4][4];
#pragma unroll
    for (int i = 0; i < 4; i++)
#pragma unroll
        for (int j = 0; j < 4; j++)
#pragma unroll
            for (int r = 0; r < 4; r++) acc[i][j][r] = 0.f;
    __syncthreads();
    if (seg > 0) {
        const u16* hbase = Hbf + (size_t)(seg - 1) * SLOT + (((size_t)b * NHEAD + h) * PDIM) * NSTATE;
#pragma unroll
        for (int k0 = 0; k0 < 64; k0 += 32) {
            bf16x8 af[4], bfr[4];
#pragma unroll
            for (int i = 0; i < 4; i++)
                af[i] = *(const bf16x8*)&sC_[wm * 64 + i * 16 + lr][k0 + quad * 8];
#pragma unroll
            for (int j = 0; j < 4; j++)
                bfr[j] = *(const bf16x8*)(hbase + (size_t)(wn * 64 + j * 16 + lr) * NSTATE + k0 + quad * 8);
#pragma unroll
            for (int i = 0; i < 4; i++)
#pragma unroll
                for (int j = 0; j < 4; j++)
                    acc[i][j] = __builtin_amdgcn_mfma_f32_16x16x32_bf16(af[i], bfr[j], acc[i][j], 0, 0, 0);
        }
#pragma unroll
        for (int i = 0; i < 4; i++) {
#pragma unroll
            for (int r = 0; r < 4; r++) {
                float el = sEL[wm * 64 + i * 16 + quad * 4 + r];
#pragma unroll
                for (int j = 0; j < 4; j++) acc[i][j][r] *= el;
            }
        }
    }

    const int px = tid & 127, koh = (tid >> 7) * 16;
    for (int kc = 0; kc < 128; kc += 32) {
        u16 xv[16];
#pragma unroll
        for (int j2 = 0; j2 < 16; ++j2) {
            int tp = kc + koh + j2;
            xv[j2] = xb[(size_t)((t0 + tp) * B_SZ + b) * D_IN + h * PDIM + px];
        }
        __syncthreads();
        *(uint4*)&sXT[px][koh]     = *(const uint4*)&xv[0];
        *(uint4*)&sXT[px][koh + 8] = *(const uint4*)&xv[8];
        __syncthreads();
        bf16x8 af[4], bfr[4];
#pragma unroll
        for (int i = 0; i < 4; i++)
            af[i] = *(const bf16x8*)&sS[wm * 64 + i * 16 + lr][kc + quad * 8];
#pragma unroll
        for (int j = 0; j < 4; j++)
            bfr[j] = *(const bf16x8*)&sXT[wn * 64 + j * 16 + lr][quad * 8];
#pragma unroll
        for (int i = 0; i < 4; i++)
#pragma unroll
            for (int j = 0; j < 4; j++)
                acc[i][j] = __builtin_amdgcn_mfma_f32_16x16x32_bf16(af[i], bfr[j], acc[i][j], 0, 0, 0);
    }

#pragma unroll
    for (int j = 0; j < 4; j++) {
        int p = wn * 64 + j * 16 + lr;
#pragma unroll
        for (int i = 0; i < 4; i++) {
#pragma unroll
            for (int r = 0; r < 4; r++) {
                int t = wm * 64 + i * 16 + quad * 4 + r;
                xb[(size_t)((t0 + t) * B_SZ + b) * D_IN + h * PDIM + p] = f2bf(acc[i][j][r]);
            }
        }
    }
}

// ---------------- launch ----------------
extern "C" void kernel_launch(void* const* d_in, const int* in_sizes, int n_in,
                              void* d_out, int out_size, void* d_ws, size_t ws_size,
                              hipStream_t stream) {
    const float* obs     = (const float*)d_in[0];
    const float* W_in    = (const float*)d_in[1];
    const float* b_in    = (const float*)d_in[2];
    const float* A_log   = (const float*)d_in[3];
    const float* dt_bias = (const float*)d_in[4];
    const float* W_dt    = (const float*)d_in[5];
    const float* W_B     = (const float*)d_in[6];
    const float* W_C     = (const float*)d_in[7];
    const float* W_yo    = (const float*)d_in[8];
    const float* b_yo    = (const float*)d_in[9];
    const float* W_head  = (const float*)d_in[10];
    const float* b_head  = (const float*)d_in[11];

    char* ws = (char*)d_ws;
    size_t o = 0;
    u16*   xb     = (u16*)(ws + o);   o += (size_t)ROWS * D_IN * 2;            // 16 MB (x, then y in-place)
    u16*   BCm    = (u16*)(ws + o);   o += (size_t)ROWS * BCSTR * 2;           // 17.8 MB (B | C | pad)
    float* dtv    = (float*)(ws + o); o += (size_t)ROWS * NHEAD * 4;
    float* decayv = (float*)(ws + o); o += (size_t)ROWS * NHEAD * 4;
    u16*   zb     = (u16*)(ws + o);   o += (size_t)ROWS * NUNITS * 2;          // 2 MB
    float* Hseg   = (float*)(ws + o); o += (size_t)(NSEG - 1) * SLOT * 4;      // 12 MB
    u16*   Hbf    = (u16*)(ws + o);   o += (size_t)(NSEG - 1) * SLOT * 2;      // 6 MB
    u16*   obsb   = (u16*)(ws + o);   o += (size_t)ROWS * OBS_D * 2;           // 2 MB
    u16*   WinT   = (u16*)(ws + o);   o += (size_t)D_IN * OBS_D * 2;           // 1 MB
    u16*   WBCT   = (u16*)(ws + o);   o += (size_t)BCN * D_IN * 2;             // 8 MB
    u16*   WdtT   = (u16*)(ws + o);   o += (size_t)NHEAD * D_IN * 2;           // 64 KB
    u16*   WyoT   = (u16*)(ws + o);   o += (size_t)NUNITS * D_IN * 2;          // 1 MB
    u16*   WheadT = (u16*)(ws + o);   o += (size_t)NACT * NUNITS * 2;

    // zero-work launch of the harness-required symbol (kept referenced)
    ActorAgent_27625229647898_kernel<<<dim3(1), 256, 0, stream>>>((float*)d_out, 0, 0.f);

    // ---- all weight prep in one launch ----
    prep<<<dim3(160 + 5136), 256, 0, stream>>>(obs, W_dt, W_in, W_B, W_C, W_yo, W_head,
                                               obsb, WinT, WBCT, WdtT, WyoT, WheadT);

    // ---- x = relu(obs @ W_in + b_in) -> bf16 ----
    gemm_bt128<1, 1, 1><<<dim3(32, 16), 256, 0, stream>>>(obsb, WinT, b_in, xb, ROWS, D_IN, OBS_D, D_IN);
    // ---- dt = softplus(x @ W_dt + dt_bias); decay = exp(-exp(A_log)*dt) ----
    dtdecay<<<dim3(256), 512, 0, stream>>>(xb, WdtT, dt_bias, A_log, dtv, decayv);
    // ---- B|C projection: N=2048 (16 tiles -> 512 blocks = 2/CU), ldc=2176 (non-pow2 stride) ----
    gemm_bt128<0, 1, 0><<<dim3(32, 16), 256, 0, stream>>>(xb, WBCT, (const float*)nullptr, BCm, ROWS, BCN, D_IN, BCSTR);
    // ---- scan: A) segment-local final states ----
    seg_state<<<dim3((NSEG - 1) * 128), 256, 0, stream>>>(xb, BCm, dtv, decayv, Hseg);
    //          B) prefix combine -> bf16 ----
    seg_prefix<<<dim3(512), 256, 0, stream>>>(Hseg, decayv, Hbf);
    //          C) fused S' + Y, in-place over xb ----
    chunk_scan<<<dim3(NSEG * 128), 256, 0, stream>>>(BCm, dtv, decayv, Hbf, xb);
    // ---- z = relu(y @ W_yo + b_yo) -> bf16 ----
    gemm_bt64<1, 1><<<dim3(64, 4), 256, 0, stream>>>(xb, WyoT, b_yo, zb, ROWS, NUNITS, D_IN);
    // ---- logits = z @ W_head + b_head -> d_out (fp32) ----
    gemm_bt64<0, 0><<<dim3(64, 1), 256, 0, stream>>>(zb, WheadT, b_head, (float*)d_out, ROWS, NACT, NUNITS);
}

// Round 6
// 239.321 us; speedup vs baseline: 1.1380x; 1.0342x over previous
//
#include <hip/hip_runtime.h>
#include <cstdint>
#include <cstddef>

typedef unsigned short u16;
typedef __attribute__((ext_vector_type(8))) __bf16 bf16x8;   // MFMA A/B operand
typedef __attribute__((ext_vector_type(4))) float floatx4;   // MFMA C/D operand

// dims
#define T_DIM   512
#define B_SZ    8
#define ROWS    4096      // T*B
#define OBS_D   256
#define D_IN    2048
#define NHEAD   16
#define NSTATE  64
#define PDIM    128
#define NUNITS  256
#define NACT    64
#define NSEG    4
#define SEGT    128       // T_DIM / NSEG
#define SLOT    (B_SZ * NHEAD * PDIM * NSTATE)   // 1048576 elems per seg-state slot
// BCm holds B(1024) | C(1024) | pad(128). GEMM computes N=2048 (16 tiles ->
// 512 blocks = exactly 2/CU) but WRITES with ldc=2176 (non-pow2 row stride;
// pow2 stride aliased L2 sets in seg_state/chunk_scan reads — r18 lesson).
#define BCSTR   2176      // row stride of BCm (u16 elems)
#define BCN     2048      // computed columns (B|C)

__host__ __device__ __forceinline__ float bf2f(u16 u) {
    union { uint32_t i; float f; } v; v.i = ((uint32_t)u) << 16; return v.f;
}
__host__ __device__ __forceinline__ u16 f2bf(float f) {
    union { float f; uint32_t i; } v; v.f = f;
    uint32_t r = v.i + 0x7FFFu + ((v.i >> 16) & 1u);
    return (u16)(r >> 16);
}

// async 16B/lane global->LDS (m97 pattern). lds ptr must be wave-uniform.
__device__ __forceinline__ void glds16(const u16* g, u16* l) {
    __builtin_amdgcn_global_load_lds(
        (__attribute__((address_space(1))) void*)g,
        (__attribute__((address_space(3))) void*)l, 16, 0, 0);
}

// ---------------- harness-required symbol (zero-work launch keeps it referenced) ----------------
__global__ __launch_bounds__(256) void ActorAgent_27625229647898_kernel(
        float* __restrict__ out, int n, float v) {
    for (int i = blockIdx.x * 256 + threadIdx.x; i < n; i += gridDim.x * 256)
        out[i] = v;
}

// ---------------- prep: all weight converts + transposes in ONE launch ----------------
__global__ __launch_bounds__(256) void prep(const float* __restrict__ obs,
                                            const float* __restrict__ W_dt,
                                            const float* __restrict__ W_in,
                                            const float* __restrict__ W_B,
                                            const float* __restrict__ W_C,
                                            const float* __restrict__ W_yo,
                                            const float* __restrict__ W_head,
                                            u16* __restrict__ obsb,
                                            u16* __restrict__ WinT, u16* __restrict__ WBCT,
                                            u16* __restrict__ WdtT,
                                            u16* __restrict__ WyoT, u16* __restrict__ WheadT) {
    int bid = blockIdx.x;
    if (bid < 160) {
        const int NOBS = ROWS * OBS_D;             // 1048576
        const int NDT  = D_IN * NHEAD;             // 32768
        for (int i = bid * 256 + threadIdx.x; i < NOBS + NDT; i += 160 * 256) {
            if (i < NOBS) obsb[i] = f2bf(obs[i]);
            else {
                int j = i - NOBS;                  // j = k*16 + n
                int k = j >> 4, n = j & 15;
                WdtT[n * D_IN + k] = f2bf(W_dt[j]);
            }
        }
        return;
    }
    bid -= 160;
    const float* src; u16* dst; int R, C, bx, by;
    if (bid < 512)       { src = W_in;   dst = WinT;   R = 256;  C = 2048; bx = bid & 63; by = bid >> 6; }
    else if (bid < 2560) { int i = bid - 512;  src = W_B;  dst = WBCT; R = 2048; C = 1024; bx = i & 31; by = i >> 5; }
    else if (bid < 4608) { int i = bid - 2560; src = W_C;  dst = WBCT + (size_t)1024 * 2048; R = 2048; C = 1024; bx = i & 31; by = i >> 5; }
    else if (bid < 5120) { int i = bid - 4608; src = W_yo; dst = WyoT; R = 2048; C = 256;  bx = i & 7;  by = i >> 3; }
    else                 { int i = bid - 5120; src = W_head; dst = WheadT; R = 256; C = 64; bx = i & 1; by = i >> 1; }
    __shared__ float t[32][33];
    int c0 = bx * 32, r0 = by * 32;
    int tx = threadIdx.x & 31, ty = threadIdx.x >> 5;
#pragma unroll
    for (int i = 0; i < 32; i += 8)
        t[ty + i][tx] = src[(size_t)(r0 + ty + i) * C + c0 + tx];
    __syncthreads();
#pragma unroll
    for (int i = 0; i < 32; i += 8)
        dst[(size_t)(c0 + ty + i) * R + r0 + tx] = f2bf(t[tx][ty + i]);
}

// ---------------- bt128: 128x128 bf16 MFMA GEMM, B^T (N,K), BK=32 glds staging ----------------
// r23: ONE barrier per K-iter (was 2). 4 LDS buffers, stage-after-compute:
//   wait vmcnt(4) -> s_barrier -> ds_read+16 MFMA(buf t&3) -> STAGE(t+2 -> buf (t+2)&3)
// The old end-of-iter barrier guarded staging (issued pre-barrier) against the
// previous iter's readers; with stage-after-compute, the START barrier of iter
// t already proves all waves finished iter t-1's reads, and buf (t+2)&3 was
// last read at iter t-2 (two barriers ago) -> race-free. In-flight stays 2
// tiles (8 loads); the vmcnt(4) wait has a full compute phase of cover.
// Hazard matrix checked: stage target never collides within barrier skew
// (max skew = one iter; fast wave's stage hits buf (t-2)&3, never t&3/t+1&3).
// NOTE (r14/r15/r17): BK=64, 128x64 tile, XCD swizzle all regress (old struct).
template <int ACT, int OUT_BF16, int HAS_BIAS>
__global__ __launch_bounds__(256) void gemm_bt128(const u16* __restrict__ A,
                                                  const u16* __restrict__ BT,
                                                  const float* __restrict__ bias,
                                                  void* __restrict__ Cout,
                                                  int M, int N, int K, int ldc) {
    __shared__ __align__(16) u16 sA[4][128 * 32];   // 4 x 8 KB
    __shared__ __align__(16) u16 sB[4][128 * 32];
    const int tid  = threadIdx.x;
    const int wave = tid >> 6, lane = tid & 63;
    const int quad = lane >> 4, lr = lane & 15;
    const int wm = wave & 1, wn = wave >> 1;
    const int m0 = blockIdx.x * 128, n0 = blockIdx.y * 128;
    const int r0 = wave * 32 + (lane >> 2);   // staged row per lane
    const int kel = (lane & 3) * 8;           // k offset (u16) per lane

    floatx4 acc[4][4];
#pragma unroll
    for (int i = 0; i < 4; i++)
#pragma unroll
        for (int j = 0; j < 4; j++)
#pragma unroll
            for (int r = 0; r < 4; r++) acc[i][j][r] = 0.f;

    const u16* apg = A + (size_t)(m0 + r0) * K + kel;
    const u16* bpg = BT + (size_t)(n0 + r0) * K + kel;
    const int lofs = (wave * 32) * 32;
    const int ntk = K >> 5;   // K tiles (8 or 64 for our shapes; always >= 2)

#define STAGE128(t, sb) do {                                        \
        int kk_ = (t) << 5;                                         \
        glds16(apg + kk_, &sA[sb][lofs]);                           \
        glds16(apg + (size_t)16 * K + kk_, &sA[sb][lofs + 16 * 32]);\
        glds16(bpg + kk_, &sB[sb][lofs]);                           \
        glds16(bpg + (size_t)16 * K + kk_, &sB[sb][lofs + 16 * 32]);\
    } while (0)

    STAGE128(0, 0);
    STAGE128(1, 1);
    for (int t = 0; t < ntk; ++t) {
        const int s = t & 3;
        if (t + 1 < ntk) {
            asm volatile("s_waitcnt vmcnt(4)" ::: "memory");   // tile t landed
        } else {
            asm volatile("s_waitcnt vmcnt(0)" ::: "memory");
        }
        __builtin_amdgcn_s_barrier();     // all waves' tile-t loads visible
        asm volatile("" ::: "memory");
        bf16x8 af[4], bfr[4];
#pragma unroll
        for (int i = 0; i < 4; i++)
            af[i] = *(const bf16x8*)&sA[s][(wm * 64 + i * 16 + lr) * 32 + quad * 8];
#pragma unroll
        for (int j = 0; j < 4; j++)
            bfr[j] = *(const bf16x8*)&sB[s][(wn * 64 + j * 16 + lr) * 32 + quad * 8];
#pragma unroll
        for (int i = 0; i < 4; i++)
#pragma unroll
            for (int j = 0; j < 4; j++)
                acc[i][j] = __builtin_amdgcn_mfma_f32_16x16x32_bf16(af[i], bfr[j], acc[i][j], 0, 0, 0);
        asm volatile("" ::: "memory");
        if (t + 2 < ntk) STAGE128(t + 2, (t + 2) & 3);
    }
#undef STAGE128
    // C/D layout: col = lane&15, row = quad*4 + reg
#pragma unroll
    for (int j = 0; j < 4; j++) {
        int col = n0 + wn * 64 + j * 16 + lr;
        float bvv = HAS_BIAS ? bias[col] : 0.f;
#pragma unroll
        for (int i = 0; i < 4; i++) {
#pragma unroll
            for (int r = 0; r < 4; r++) {
                int row = m0 + wm * 64 + i * 16 + quad * 4 + r;
                float v = acc[i][j][r] + bvv;
                if (ACT) v = fmaxf(v, 0.f);
                if (OUT_BF16) ((u16*)Cout)[(size_t)row * ldc + col] = f2bf(v);
                else          ((float*)Cout)[(size_t)row * ldc + col] = v;
            }
        }
    }
}

// ---------------- bt64: 64x64 bf16 MFMA GEMM, B^T layout, BK=64, 1-barrier 4-buf pipeline ----------------
template <int ACT, int OUT_BF16>
__global__ __launch_bounds__(256) void gemm_bt64(const u16* __restrict__ A,
                                                 const u16* __restrict__ BT,
                                                 const float* __restrict__ bias,
                                                 void* __restrict__ Cout,
                                                 int M, int N, int K) {
    __shared__ __align__(16) u16 sA[4][64 * 64];  // 4 x 8 KB
    __shared__ __align__(16) u16 sB[4][64 * 64];
    const int tid  = threadIdx.x;
    const int wave = tid >> 6, lane = tid & 63;
    const int quad = lane >> 4, lr = lane & 15;
    const int m0 = blockIdx.x * 64, n0 = blockIdx.y * 64;
    const int srl = lane >> 3, sc = (lane & 7) * 8;

    floatx4 acc[4];
#pragma unroll
    for (int i = 0; i < 4; i++)
#pragma unroll
        for (int j = 0; j < 4; j++) acc[i][j] = 0.f;

    const u16* apg = A + (size_t)(m0 + wave * 16 + srl) * K + sc;
    const u16* bpg = BT + (size_t)(n0 + wave * 16 + srl) * K + sc;
    const int ntk = K >> 6;   // K tiles (32 or 4 for our shapes; always >= 2)

#define STAGE64(t, sb) do {                                            \
        int kk_ = (t) << 6;                                            \
        glds16(apg + kk_,                 &sA[sb][(wave * 16) * 64]);  \
        glds16(apg + (size_t)8 * K + kk_, &sA[sb][(wave * 16 + 8) * 64]);\
        glds16(bpg + kk_,                 &sB[sb][(wave * 16) * 64]);  \
        glds16(bpg + (size_t)8 * K + kk_, &sB[sb][(wave * 16 + 8) * 64]);\
    } while (0)

    STAGE64(0, 0);
    STAGE64(1, 1);
    for (int t = 0; t < ntk; ++t) {
        const int s = t & 3;
        if (t + 1 < ntk) {
            asm volatile("s_waitcnt vmcnt(4)" ::: "memory");
        } else {
            asm volatile("s_waitcnt vmcnt(0)" ::: "memory");
        }
        __builtin_amdgcn_s_barrier();
        asm volatile("" ::: "memory");
#pragma unroll
        for (int ks = 0; ks < 2; ++ks) {
            bf16x8 af = *(const bf16x8*)&sA[s][(wave * 16 + lr) * 64 + ks * 32 + quad * 8];
#pragma unroll
            for (int nt = 0; nt < 4; nt++) {
                bf16x8 bf = *(const bf16x8*)&sB[s][(nt * 16 + lr) * 64 + ks * 32 + quad * 8];
                acc[nt] = __builtin_amdgcn_mfma_f32_16x16x32_bf16(af, bf, acc[nt], 0, 0, 0);
            }
        }
        asm volatile("" ::: "memory");
        if (t + 2 < ntk) STAGE64(t + 2, (t + 2) & 3);
    }
#undef STAGE64
#pragma unroll
    for (int nt = 0; nt < 4; nt++) {
        int col = n0 + nt * 16 + lr;
        float bvv = bias ? bias[col] : 0.f;
#pragma unroll
        for (int r = 0; r < 4; r++) {
            int row = m0 + wave * 16 + quad * 4 + r;
            float v = acc[nt][r] + bvv;
            if (ACT) v = fmaxf(v, 0.f);
            if (OUT_BF16) ((u16*)Cout)[(size_t)row * N + col] = f2bf(v);
            else          ((float*)Cout)[(size_t)row * N + col] = v;
        }
    }
}

// ---------------- dtdecay: dtraw = x @ W_dt, fused softplus + decay ----------------
// r22: the wave's 2 rows are processed TOGETHER in one k-pass so the 32
// weight bf2f converts per k-step are shared. 256 blocks x 16 rows.
__global__ __launch_bounds__(512) void dtdecay(const u16* __restrict__ xb,
                                               const u16* __restrict__ WdtT,
                                               const float* __restrict__ dt_bias,
                                               const float* __restrict__ A_log,
                                               float* __restrict__ dtv,
                                               float* __restrict__ decayv) {
    __shared__ __align__(16) u16 sw[NHEAD * D_IN];   // 64 KB, [h][k]
    const int tid = threadIdx.x;
#pragma unroll
    for (int i = 0; i < 8; ++i) {
        int idx = (tid + i * 512) * 8;
        *(uint4*)&sw[idx] = *(const uint4*)(WdtT + idx);
    }
    __syncthreads();
    const int wave = tid >> 6, lane = tid & 63;
    const int q = lane >> 4, lr = lane & 15;
    const int row0 = blockIdx.x * 16 + wave * 2;
    const u16* xp0 = xb + (size_t)row0 * D_IN;
    const u16* xp1 = xb + (size_t)(row0 + 1) * D_IN;
    float acc0[4] = {0.f, 0.f, 0.f, 0.f};
    float acc1[4] = {0.f, 0.f, 0.f, 0.f};
#pragma unroll 4
    for (int k0 = 0; k0 < 16; ++k0) {
        const int kk = k0 * 128 + lr * 8;
        uint4 xv0 = *(const uint4*)(xp0 + kk);
        uint4 xv1 = *(const uint4*)(xp1 + kk);
        const u16* xu0 = (const u16*)&xv0;
        const u16* xu1 = (const u16*)&xv1;
        float xf0[8], xf1[8];
#pragma unroll
        for (int j = 0; j < 8; ++j) { xf0[j] = bf2f(xu0[j]); xf1[j] = bf2f(xu1[j]); }
#pragma unroll
        for (int j = 0; j < 4; ++j) {
            uint4 wv = *(const uint4*)&sw[(q * 4 + j) * D_IN + kk];
            const u16* wu = (const u16*)&wv;
#pragma unroll
            for (int jj = 0; jj < 8; ++jj) {
                float wf = bf2f(wu[jj]);
                acc0[j] = fmaf(xf0[jj], wf, acc0[j]);
                acc1[j] = fmaf(xf1[jj], wf, acc1[j]);
            }
        }
    }
    // reduce across the 16 lanes of each quad (masks 1,2,4,8 stay in-quad)
#pragma unroll
    for (int m = 1; m <= 8; m <<= 1)
#pragma unroll
        for (int j = 0; j < 4; ++j) {
            acc0[j] += __shfl_xor(acc0[j], m);
            acc1[j] += __shfl_xor(acc1[j], m);
        }
    if (lr == 0) {
#pragma unroll
        for (int j = 0; j < 4; ++j) {
            int h = q * 4 + j;
            float ae = expf(A_log[h]);
            float z0 = acc0[j] + dt_bias[h];
            float sp0 = (z0 > 20.f) ? z0 : log1pf(expf(z0));
            float z1 = acc1[j] + dt_bias[h];
            float sp1 = (z1 > 20.f) ? z1 : log1pf(expf(z1));
            dtv[row0 * NHEAD + h] = sp0;
            decayv[row0 * NHEAD + h] = expf(-ae * sp0);
            dtv[(row0 + 1) * NHEAD + h] = sp1;
            decayv[(row0 + 1) * NHEAD + h] = expf(-ae * sp1);
        }
    }
}

// ---------------- seg_state: segment-final states as weighted outer-product sum ----------------
__global__ __launch_bounds__(256) void seg_state(const u16* __restrict__ xw,
                                                 const u16* __restrict__ BCm,
                                                 const float* __restrict__ dtv,
                                                 const float* __restrict__ decayv,
                                                 float* __restrict__ Hbuf) {
    const int blk = blockIdx.x;
    const int seg = blk >> 7;
    const int b   = (blk >> 4) & 7;
    const int h   = blk & 15;
    const int tid = threadIdx.x;
    const int pgrp = tid >> 3;
    const int oct  = tid & 7;

    __shared__ __align__(16) u16 sx[SEGT][PDIM];
    __shared__ __align__(16) u16 sbm[SEGT][NSTATE];
    __shared__ float sw[SEGT];
    __shared__ float sdt[SEGT];
    __shared__ float sdec[SEGT];
    __shared__ float sP[32];

    const int t0 = seg * SEGT;

#pragma unroll
    for (int k = 0; k < 8; ++k) {
        int idx = tid + k * 256;
        int t = idx >> 4, c = (idx & 15) * 8;
        int r = (t0 + t) * B_SZ + b;
        *(uint4*)&sx[t][c] = *(const uint4*)(xw + (size_t)r * D_IN + h * PDIM + c);
    }
#pragma unroll
    for (int k = 0; k < 4; ++k) {
        int idx = tid + k * 256;
        int t = idx >> 3, c = (idx & 7) * 8;
        int r = (t0 + t) * B_SZ + b;
        *(uint4*)&sbm[t][c] = *(const uint4*)(BCm + (size_t)r * BCSTR + h * NSTATE + c);
    }
    if (tid < SEGT)            sdt[tid] = dtv[((t0 + tid) * B_SZ + b) * NHEAD + h];
    else if (tid < 2 * SEGT)   sdec[tid - SEGT] = decayv[((t0 + tid - SEGT) * B_SZ + b) * NHEAD + h];
    __syncthreads();

    if (tid < 32) {
        float p = 1.f;
        for (int i = 3; i >= 0; --i) {
            int t = tid * 4 + i;
            sw[t] = sdt[t] * p;
            p *= sdec[t];
        }
        sP[tid] = p;
    }
    __syncthreads();
    if (tid == 0) {
        float suf = 1.f;
        for (int q = 31; q >= 0; --q) { float tmp = sP[q]; sP[q] = suf; suf *= tmp; }
    }
    __syncthreads();
    if (tid < 32) {
        float m = sP[tid];
        for (int i = 0; i < 4; ++i) sw[tid * 4 + i] *= m;
    }
    __syncthreads();

    float acc[4][8];
#pragma unroll
    for (int i = 0; i < 4; i++)
#pragma unroll
        for (int j = 0; j < 8; j++) acc[i][j] = 0.f;

    for (int t = 0; t < SEGT; ++t) {
        float w = sw[t];
        const u16* xp = &sx[t][pgrp * 4];
        const u16* bp = &sbm[t][oct * 8];
        float xv[4], bv[8];
#pragma unroll
        for (int i = 0; i < 4; i++) xv[i] = w * bf2f(xp[i]);
#pragma unroll
        for (int j = 0; j < 8; j++) bv[j] = bf2f(bp[j]);
#pragma unroll
        for (int i = 0; i < 4; i++)
#pragma unroll
            for (int j = 0; j < 8; j++)
                acc[i][j] = fmaf(xv[i], bv[j], acc[i][j]);
    }

    float* base = Hbuf + (size_t)seg * SLOT +
                  (((size_t)b * NHEAD + h) * PDIM + pgrp * 4) * NSTATE + oct * 8;
#pragma unroll
    for (int i = 0; i < 4; i++) {
        *(float4*)(base + (size_t)i * NSTATE)     = make_float4(acc[i][0], acc[i][1], acc[i][2], acc[i][3]);
        *(float4*)(base + (size_t)i * NSTATE + 4) = make_float4(acc[i][4], acc[i][5], acc[i][6], acc[i][7]);
    }
}

// ---------------- prefix combine -> bf16 prefix states Hbf ----------------
__global__ __launch_bounds__(256) void seg_prefix(const float* __restrict__ Hbuf,
                                                  const float* __restrict__ decayv,
                                                  u16* __restrict__ Hbf) {
    const int blk = blockIdx.x;
    const int b  = blk >> 6;
    const int h  = (blk >> 2) & 15;
    const int ec = blk & 3;
    const int tid = threadIdx.x;

    __shared__ float sA[NSEG];

    if (tid < 64 * (NSEG - 2)) {
        int s = 1 + (tid >> 6);
        int i = tid & 63;
        int t = s * SEGT + i * 2;
        float p = decayv[(t * B_SZ + b) * NHEAD + h] *
                  decayv[((t + 1) * B_SZ + b) * NHEAD + h];
        p *= __shfl_xor(p, 1);
        p *= __shfl_xor(p, 2);
        p *= __shfl_xor(p, 4);
        p *= __shfl_xor(p, 8);
        p *= __shfl_xor(p, 16);
        p *= __shfl_xor(p, 32);
        if (i == 0) sA[s] = p;
    }
    __syncthreads();

    const size_t base = (((size_t)b * NHEAD + h) * PDIM * NSTATE) + (size_t)ec * 2048 + tid * 8;
    float4 P0 = *(const float4*)(Hbuf + base);
    float4 P1 = *(const float4*)(Hbuf + base + 4);
    u16 pk[8];
    pk[0] = f2bf(P0.x); pk[1] = f2bf(P0.y); pk[2] = f2bf(P0.z); pk[3] = f2bf(P0.w);
    pk[4] = f2bf(P1.x); pk[5] = f2bf(P1.y); pk[6] = f2bf(P1.z); pk[7] = f2bf(P1.w);
    *(uint4*)(Hbf + base) = *(const uint4*)pk;
#pragma unroll
    for (int s = 1; s <= NSEG - 2; ++s) {
        float a = sA[s];
        const float* slot = Hbuf + (size_t)s * SLOT + base;
        float4 h0 = *(const float4*)(slot);
        float4 h1 = *(const float4*)(slot + 4);
        P0.x = fmaf(a, P0.x, h0.x); P0.y = fmaf(a, P0.y, h0.y);
        P0.z = fmaf(a, P0.z, h0.z); P0.w = fmaf(a, P0.w, h0.w);
        P1.x = fmaf(a, P1.x, h1.x); P1.y = fmaf(a, P1.y, h1.y);
        P1.z = fmaf(a, P1.z, h1.z); P1.w = fmaf(a, P1.w, h1.w);
        pk[0] = f2bf(P0.x); pk[1] = f2bf(P0.y); pk[2] = f2bf(P0.z); pk[3] = f2bf(P0.w);
        pk[4] = f2bf(P1.x); pk[5] = f2bf(P1.y); pk[6] = f2bf(P1.z); pk[7] = f2bf(P1.w);
        *(uint4*)(Hbf + (size_t)s * SLOT + base) = *(const uint4*)pk;
    }
}

// ---------------- chunk_scan: fused S' build + Y = exp(L).C@Hp^T + S'@X^T ----------------
__global__ __launch_bounds__(256) void chunk_scan(const u16* __restrict__ BCm,
                                                  const float* __restrict__ dtv,
                                                  const float* __restrict__ decayv,
                                                  const u16* __restrict__ Hbf,
                                                  u16* __restrict__ xb) {
    __shared__ __align__(16) u16 sB_[128][68];   // B [t'][n]
    __shared__ __align__(16) u16 sC_[128][68];   // C [t][n]
    __shared__ __align__(16) u16 sS[128][132];   // S' [t][t']
    __shared__ __align__(16) u16 sXT[128][36];   // X^T [p][k-tile]
    __shared__ float sdt[SEGT], sL[SEGT], sEL[SEGT], stmp[32];

    const int blk = blockIdx.x;
    const int seg = blk >> 7, b = (blk >> 4) & 7, h = blk & 15;
    const int tid = threadIdx.x;
    const int wave = tid >> 6, lane = tid & 63;
    const int quad = lane >> 4, lr = lane & 15;
    const int wm = wave & 1, wn = wave >> 1;
    const int t0 = seg * SEGT;

#pragma unroll
    for (int it = 0; it < 4; ++it) {
        int idx = tid + it * 256;
        int t = idx >> 3, c = (idx & 7) * 8;
        int r = (t0 + t) * B_SZ + b;
        *(uint4*)&sB_[t][c] = *(const uint4*)(BCm + (size_t)r * BCSTR + h * NSTATE + c);
        *(uint4*)&sC_[t][c] = *(const uint4*)(BCm + (size_t)r * BCSTR + 1024 + h * NSTATE + c);
    }
    if (tid < SEGT) sdt[tid] = dtv[((t0 + tid) * B_SZ + b) * NHEAD + h];
    else if (tid < 2 * SEGT) {
        int t = tid - SEGT;
        sL[t] = __logf(fmaxf(decayv[((t0 + t) * B_SZ + b) * NHEAD + h], 1e-30f));
    }
    __syncthreads();
    if (tid < 32) {
        float s = 0.f, v[4];
#pragma unroll
        for (int i = 0; i < 4; ++i) { s += sL[tid * 4 + i]; v[i] = s; }
        stmp[tid] = s;
#pragma unroll
        for (int i = 0; i < 4; ++i) sL[tid * 4 + i] = v[i];
    }
    __syncthreads();
    if (tid == 0) {
        float run = 0.f;
        for (int q = 0; q < 32; ++q) { float c2 = stmp[q]; stmp[q] = run; run += c2; }
    }
    __syncthreads();
    if (tid < 32) {
        float off = stmp[tid];
#pragma unroll
        for (int i = 0; i < 4; ++i) sL[tid * 4 + i] += off;
    }
    __syncthreads();
    if (tid < SEGT) sEL[tid] = __expf(sL[tid]);

    floatx4 accS[4][4];
#pragma unroll
    for (int i = 0; i < 4; i++)
#pragma unroll
        for (int j = 0; j < 4; j++)
#pragma unroll
            for (int r = 0; r < 4; r++) accS[i][j][r] = 0.f;
#pragma unroll
    for (int k0 = 0; k0 < 64; k0 += 32) {
        bf16x8 af[4], bfr[4];
#pragma unroll
        for (int i = 0; i < 4; i++)
            af[i] = *(const bf16x8*)&sB_[wm * 64 + i * 16 + lr][k0 + quad * 8];
#pragma unroll
        for (int j = 0; j < 4; j++)
            bfr[j] = *(const bf16x8*)&sC_[wn * 64 + j * 16 + lr][k0 + quad * 8];
#pragma unroll
        for (int i = 0; i < 4; i++)
#pragma unroll
            for (int j = 0; j < 4; j++)
                accS[i][j] = __builtin_amdgcn_mfma_f32_16x16x32_bf16(af[i], bfr[j], accS[i][j], 0, 0, 0);
    }
#pragma unroll
    for (int j = 0; j < 4; j++) {
        int tt = wn * 64 + j * 16 + lr;
        float Lt = sL[tt];
#pragma unroll
        for (int i = 0; i < 4; i++) {
#pragma unroll
            for (int r = 0; r < 4; r++) {
                int tp = wm * 64 + i * 16 + quad * 4 + r;
                float v = 0.f;
                if (tp <= tt) v = accS[i][j][r] * sdt[tp] * __expf(Lt - sL[tp]);
                sS[tt][tp] = f2bf(v);
            }
        }
    }

    floatx4 acc[4][4];
#pragma unroll
    for (int i = 0; i < 4; i++)
#pragma unroll
        for (int j = 0; j < 4; j++)
#pragma unroll
            for (int r = 0; r < 4; r++) acc[i][j][r] = 0.f;
    __syncthreads();
    if (seg > 0) {
        const u16* hbase = Hbf + (size_t)(seg - 1) * SLOT + (((size_t)b * NHEAD + h) * PDIM) * NSTATE;
#pragma unroll
        for (int k0 = 0; k0 < 64; k0 += 32) {
            bf16x8 af[4], bfr[4];
#pragma unroll
            for (int i = 0; i < 4; i++)
                af[i] = *(const bf16x8*)&sC_[wm * 64 + i * 16 + lr][k0 + quad * 8];
#pragma unroll
            for (int j = 0; j < 4; j++)
                bfr[j] = *(const bf16x8*)(hbase + (size_t)(wn * 64 + j * 16 + lr) * NSTATE + k0 + quad * 8);
#pragma unroll
            for (int i = 0; i < 4; i++)
#pragma unroll
                for (int j = 0; j < 4; j++)
                    acc[i][j] = __builtin_amdgcn_mfma_f32_16x16x32_bf16(af[i], bfr[j], acc[i][j], 0, 0, 0);
        }
#pragma unroll
        for (int i = 0; i < 4; i++) {
#pragma unroll
            for (int r = 0; r < 4; r++) {
                float el = sEL[wm * 64 + i * 16 + quad * 4 + r];
#pragma unroll
                for (int j = 0; j < 4; j++) acc[i][j][r] *= el;
            }
        }
    }

    const int px = tid & 127, koh = (tid >> 7) * 16;
    for (int kc = 0; kc < 128; kc += 32) {
        u16 xv[16];
#pragma unroll
        for (int j2 = 0; j2 < 16; ++j2) {
            int tp = kc + koh + j2;
            xv[j2] = xb[(size_t)((t0 + tp) * B_SZ + b) * D_IN + h * PDIM + px];
        }
        __syncthreads();
        *(uint4*)&sXT[px][koh]     = *(const uint4*)&xv[0];
        *(uint4*)&sXT[px][koh + 8] = *(const uint4*)&xv[8];
        __syncthreads();
        bf16x8 af[4], bfr[4];
#pragma unroll
        for (int i = 0; i < 4; i++)
            af[i] = *(const bf16x8*)&sS[wm * 64 + i * 16 + lr][kc + quad * 8];
#pragma unroll
        for (int j = 0; j < 4; j++)
            bfr[j] = *(const bf16x8*)&sXT[wn * 64 + j * 16 + lr][quad * 8];
#pragma unroll
        for (int i = 0; i < 4; i++)
#pragma unroll
            for (int j = 0; j < 4; j++)
                acc[i][j] = __builtin_amdgcn_mfma_f32_16x16x32_bf16(af[i], bfr[j], acc[i][j], 0, 0, 0);
    }

#pragma unroll
    for (int j = 0; j < 4; j++) {
        int p = wn * 64 + j * 16 + lr;
#pragma unroll
        for (int i = 0; i < 4; i++) {
#pragma unroll
            for (int r = 0; r < 4; r++) {
                int t = wm * 64 + i * 16 + quad * 4 + r;
                xb[(size_t)((t0 + t) * B_SZ + b) * D_IN + h * PDIM + p] = f2bf(acc[i][j][r]);
            }
        }
    }
}

// ---------------- launch ----------------
extern "C" void kernel_launch(void* const* d_in, const int* in_sizes, int n_in,
                              void* d_out, int out_size, void* d_ws, size_t ws_size,
                              hipStream_t stream) {
    const float* obs     = (const float*)d_in[0];
    const float* W_in    = (const float*)d_in[1];
    const float* b_in    = (const float*)d_in[2];
    const float* A_log   = (const float*)d_in[3];
    const float* dt_bias = (const float*)d_in[4];
    const float* W_dt    = (const float*)d_in[5];
    const float* W_B     = (const float*)d_in[6];
    const float* W_C     = (const float*)d_in[7];
    const float* W_yo    = (const float*)d_in[8];
    const float* b_yo    = (const float*)d_in[9];
    const float* W_head  = (const float*)d_in[10];
    const float* b_head  = (const float*)d_in[11];

    char* ws = (char*)d_ws;
    size_t o = 0;
    u16*   xb     = (u16*)(ws + o);   o += (size_t)ROWS * D_IN * 2;            // 16 MB (x, then y in-place)
    u16*   BCm    = (u16*)(ws + o);   o += (size_t)ROWS * BCSTR * 2;           // 17.8 MB (B | C | pad)
    float* dtv    = (float*)(ws + o); o += (size_t)ROWS * NHEAD * 4;
    float* decayv = (float*)(ws + o); o += (size_t)ROWS * NHEAD * 4;
    u16*   zb     = (u16*)(ws + o);   o += (size_t)ROWS * NUNITS * 2;          // 2 MB
    float* Hseg   = (float*)(ws + o); o += (size_t)(NSEG - 1) * SLOT * 4;      // 12 MB
    u16*   Hbf    = (u16*)(ws + o);   o += (size_t)(NSEG - 1) * SLOT * 2;      // 6 MB
    u16*   obsb   = (u16*)(ws + o);   o += (size_t)ROWS * OBS_D * 2;           // 2 MB
    u16*   WinT   = (u16*)(ws + o);   o += (size_t)D_IN * OBS_D * 2;           // 1 MB
    u16*   WBCT   = (u16*)(ws + o);   o += (size_t)BCN * D_IN * 2;             // 8 MB
    u16*   WdtT   = (u16*)(ws + o);   o += (size_t)NHEAD * D_IN * 2;           // 64 KB
    u16*   WyoT   = (u16*)(ws + o);   o += (size_t)NUNITS * D_IN * 2;          // 1 MB
    u16*   WheadT = (u16*)(ws + o);   o += (size_t)NACT * NUNITS * 2;

    // zero-work launch of the harness-required symbol (kept referenced)
    ActorAgent_27625229647898_kernel<<<dim3(1), 256, 0, stream>>>((float*)d_out, 0, 0.f);

    // ---- all weight prep in one launch ----
    prep<<<dim3(160 + 5136), 256, 0, stream>>>(obs, W_dt, W_in, W_B, W_C, W_yo, W_head,
                                               obsb, WinT, WBCT, WdtT, WyoT, WheadT);

    // ---- x = relu(obs @ W_in + b_in) -> bf16 ----
    gemm_bt128<1, 1, 1><<<dim3(32, 16), 256, 0, stream>>>(obsb, WinT, b_in, xb, ROWS, D_IN, OBS_D, D_IN);
    // ---- dt = softplus(x @ W_dt + dt_bias); decay = exp(-exp(A_log)*dt) ----
    dtdecay<<<dim3(256), 512, 0, stream>>>(xb, WdtT, dt_bias, A_log, dtv, decayv);
    // ---- B|C projection: N=2048 (16 tiles -> 512 blocks = 2/CU), ldc=2176 (non-pow2 stride) ----
    gemm_bt128<0, 1, 0><<<dim3(32, 16), 256, 0, stream>>>(xb, WBCT, (const float*)nullptr, BCm, ROWS, BCN, D_IN, BCSTR);
    // ---- scan: A) segment-local final states ----
    seg_state<<<dim3((NSEG - 1) * 128), 256, 0, stream>>>(xb, BCm, dtv, decayv, Hseg);
    //          B) prefix combine -> bf16 ----
    seg_prefix<<<dim3(512), 256, 0, stream>>>(Hseg, decayv, Hbf);
    //          C) fused S' + Y, in-place over xb ----
    chunk_scan<<<dim3(NSEG * 128), 256, 0, stream>>>(BCm, dtv, decayv, Hbf, xb);
    // ---- z = relu(y @ W_yo + b_yo) -> bf16 ----
    gemm_bt64<1, 1><<<dim3(64, 4), 256, 0, stream>>>(xb, WyoT, b_yo, zb, ROWS, NUNITS, D_IN);
    // ---- logits = z @ W_head + b_head -> d_out (fp32) ----
    gemm_bt64<0, 0><<<dim3(64, 1), 256, 0, stream>>>(zb, WheadT, b_head, (float*)d_out, ROWS, NACT, NUNITS);
}

// Round 7
// 238.814 us; speedup vs baseline: 1.1404x; 1.0021x over previous
//
#include <hip/hip_runtime.h>
#include <cstdint>
#include <cstddef>

typedef unsigned short u16;
typedef __attribute__((ext_vector_type(8))) __bf16 bf16x8;   // MFMA A/B operand
typedef __attribute__((ext_vector_type(4))) float floatx4;   // MFMA C/D operand

// dims
#define T_DIM   512
#define B_SZ    8
#define ROWS    4096      // T*B
#define OBS_D   256
#define D_IN    2048
#define NHEAD   16
#define NSTATE  64
#define PDIM    128
#define NUNITS  256
#define NACT    64
#define NSEG    4
#define SEGT    128       // T_DIM / NSEG
#define SLOT    (B_SZ * NHEAD * PDIM * NSTATE)   // 1048576 elems per seg-state slot
// BCm holds B(1024) | C(1024) | pad(128). GEMM computes N=2048 (16 tiles ->
// 512 blocks = exactly 2/CU) but WRITES with ldc=2176 (non-pow2 row stride;
// pow2 stride aliased L2 sets in seg_state/chunk_scan reads — r18 lesson).
#define BCSTR   2176      // row stride of BCm (u16 elems)
#define BCN     2048      // computed columns (B|C)

__host__ __device__ __forceinline__ float bf2f(u16 u) {
    union { uint32_t i; float f; } v; v.i = ((uint32_t)u) << 16; return v.f;
}
__host__ __device__ __forceinline__ u16 f2bf(float f) {
    union { float f; uint32_t i; } v; v.f = f;
    uint32_t r = v.i + 0x7FFFu + ((v.i >> 16) & 1u);
    return (u16)(r >> 16);
}

// async 16B/lane global->LDS (m97 pattern). lds ptr must be wave-uniform.
__device__ __forceinline__ void glds16(const u16* g, u16* l) {
    __builtin_amdgcn_global_load_lds(
        (__attribute__((address_space(1))) void*)g,
        (__attribute__((address_space(3))) void*)l, 16, 0, 0);
}

// ---------------- harness-required symbol (zero-work launch keeps it referenced) ----------------
__global__ __launch_bounds__(256) void ActorAgent_27625229647898_kernel(
        float* __restrict__ out, int n, float v) {
    for (int i = blockIdx.x * 256 + threadIdx.x; i < n; i += gridDim.x * 256)
        out[i] = v;
}

// ---------------- prep: all weight converts + transposes in ONE launch ----------------
__global__ __launch_bounds__(256) void prep(const float* __restrict__ obs,
                                            const float* __restrict__ W_dt,
                                            const float* __restrict__ W_in,
                                            const float* __restrict__ W_B,
                                            const float* __restrict__ W_C,
                                            const float* __restrict__ W_yo,
                                            const float* __restrict__ W_head,
                                            u16* __restrict__ obsb,
                                            u16* __restrict__ WinT, u16* __restrict__ WBCT,
                                            u16* __restrict__ WdtT,
                                            u16* __restrict__ WyoT, u16* __restrict__ WheadT) {
    int bid = blockIdx.x;
    if (bid < 160) {
        const int NOBS = ROWS * OBS_D;             // 1048576
        const int NDT  = D_IN * NHEAD;             // 32768
        for (int i = bid * 256 + threadIdx.x; i < NOBS + NDT; i += 160 * 256) {
            if (i < NOBS) obsb[i] = f2bf(obs[i]);
            else {
                int j = i - NOBS;                  // j = k*16 + n
                int k = j >> 4, n = j & 15;
                WdtT[n * D_IN + k] = f2bf(W_dt[j]);
            }
        }
        return;
    }
    bid -= 160;
    const float* src; u16* dst; int R, C, bx, by;
    if (bid < 512)       { src = W_in;   dst = WinT;   R = 256;  C = 2048; bx = bid & 63; by = bid >> 6; }
    else if (bid < 2560) { int i = bid - 512;  src = W_B;  dst = WBCT; R = 2048; C = 1024; bx = i & 31; by = i >> 5; }
    else if (bid < 4608) { int i = bid - 2560; src = W_C;  dst = WBCT + (size_t)1024 * 2048; R = 2048; C = 1024; bx = i & 31; by = i >> 5; }
    else if (bid < 5120) { int i = bid - 4608; src = W_yo; dst = WyoT; R = 2048; C = 256;  bx = i & 7;  by = i >> 3; }
    else                 { int i = bid - 5120; src = W_head; dst = WheadT; R = 256; C = 64; bx = i & 1; by = i >> 1; }
    __shared__ float t[32][33];
    int c0 = bx * 32, r0 = by * 32;
    int tx = threadIdx.x & 31, ty = threadIdx.x >> 5;
#pragma unroll
    for (int i = 0; i < 32; i += 8)
        t[ty + i][tx] = src[(size_t)(r0 + ty + i) * C + c0 + tx];
    __syncthreads();
#pragma unroll
    for (int i = 0; i < 32; i += 8)
        dst[(size_t)(c0 + ty + i) * R + r0 + tx] = f2bf(t[tx][ty + i]);
}

// ---------------- bt128: 128x128 bf16 MFMA GEMM, B^T (N,K), BK=32 glds staging ----------------
// r23: ONE barrier per K-iter, 4 LDS buffers, stage-after-compute, counted
// vmcnt(4). See r23 note in history; proven +5 us.
// r24: T2 LDS swizzle via pre-swizzled GLOBAL source (rule #21: glds16 dest
// must stay linear, so permute the per-lane global k-chunk and apply the same
// XOR on the ds_read). Old read sA[row*32 + quad*8]: row stride 64B on 128B
// bank period -> start bank (16*lr+4*quad)%32, 16 lanes on 2 slots = 4-way
// conflict = the constant SQ_LDS_BANK_CONFLICT 4.19M (~14% of wall). Swizzle
// slot = quad ^ ((row>>1)&3): each 8-lane phase covers all 32 banks once.
// XOR is an involution: stage loads chunk kc^s(row), read of logical quad
// fetches slot quad^s(row) -> data (row, quad). Coalescing unchanged (permute
// stays within each row's 64B).
template <int ACT, int OUT_BF16, int HAS_BIAS>
__global__ __launch_bounds__(256) void gemm_bt128(const u16* __restrict__ A,
                                                  const u16* __restrict__ BT,
                                                  const float* __restrict__ bias,
                                                  void* __restrict__ Cout,
                                                  int M, int N, int K, int ldc) {
    __shared__ __align__(16) u16 sA[4][128 * 32];   // 4 x 8 KB
    __shared__ __align__(16) u16 sB[4][128 * 32];
    const int tid  = threadIdx.x;
    const int wave = tid >> 6, lane = tid & 63;
    const int quad = lane >> 4, lr = lane & 15;
    const int wm = wave & 1, wn = wave >> 1;
    const int m0 = blockIdx.x * 128, n0 = blockIdx.y * 128;
    const int r0 = wave * 32 + (lane >> 2);               // staged row per lane
    const int kel = (((lane & 3) ^ ((lane >> 3) & 3))) * 8; // swizzled k-chunk (u16)
    const int ksw = (lr >> 1) & 3;                        // read-side slot XOR

    floatx4 acc[4][4];
#pragma unroll
    for (int i = 0; i < 4; i++)
#pragma unroll
        for (int j = 0; j < 4; j++)
#pragma unroll
            for (int r = 0; r < 4; r++) acc[i][j][r] = 0.f;

    const u16* apg = A + (size_t)(m0 + r0) * K + kel;
    const u16* bpg = BT + (size_t)(n0 + r0) * K + kel;
    const int lofs = (wave * 32) * 32;
    const int ntk = K >> 5;   // K tiles (8 or 64 for our shapes; always >= 2)

#define STAGE128(t, sb) do {                                        \
        int kk_ = (t) << 5;                                         \
        glds16(apg + kk_, &sA[sb][lofs]);                           \
        glds16(apg + (size_t)16 * K + kk_, &sA[sb][lofs + 16 * 32]);\
        glds16(bpg + kk_, &sB[sb][lofs]);                           \
        glds16(bpg + (size_t)16 * K + kk_, &sB[sb][lofs + 16 * 32]);\
    } while (0)

    STAGE128(0, 0);
    STAGE128(1, 1);
    for (int t = 0; t < ntk; ++t) {
        const int s = t & 3;
        if (t + 1 < ntk) {
            asm volatile("s_waitcnt vmcnt(4)" ::: "memory");   // tile t landed
        } else {
            asm volatile("s_waitcnt vmcnt(0)" ::: "memory");
        }
        __builtin_amdgcn_s_barrier();     // all waves' tile-t loads visible
        asm volatile("" ::: "memory");
        bf16x8 af[4], bfr[4];
#pragma unroll
        for (int i = 0; i < 4; i++)
            af[i] = *(const bf16x8*)&sA[s][(wm * 64 + i * 16 + lr) * 32 + (quad ^ ksw) * 8];
#pragma unroll
        for (int j = 0; j < 4; j++)
            bfr[j] = *(const bf16x8*)&sB[s][(wn * 64 + j * 16 + lr) * 32 + (quad ^ ksw) * 8];
#pragma unroll
        for (int i = 0; i < 4; i++)
#pragma unroll
            for (int j = 0; j < 4; j++)
                acc[i][j] = __builtin_amdgcn_mfma_f32_16x16x32_bf16(af[i], bfr[j], acc[i][j], 0, 0, 0);
        asm volatile("" ::: "memory");
        if (t + 2 < ntk) STAGE128(t + 2, (t + 2) & 3);
    }
#undef STAGE128
    // C/D layout: col = lane&15, row = quad*4 + reg
#pragma unroll
    for (int j = 0; j < 4; j++) {
        int col = n0 + wn * 64 + j * 16 + lr;
        float bvv = HAS_BIAS ? bias[col] : 0.f;
#pragma unroll
        for (int i = 0; i < 4; i++) {
#pragma unroll
            for (int r = 0; r < 4; r++) {
                int row = m0 + wm * 64 + i * 16 + quad * 4 + r;
                float v = acc[i][j][r] + bvv;
                if (ACT) v = fmaxf(v, 0.f);
                if (OUT_BF16) ((u16*)Cout)[(size_t)row * ldc + col] = f2bf(v);
                else          ((float*)Cout)[(size_t)row * ldc + col] = v;
            }
        }
    }
}

// ---------------- bt64: 64x64 bf16 MFMA GEMM, B^T layout, BK=64, 1-barrier 4-buf pipeline ----------------
// r24: same T2 swizzle. Old read sA[row*64 + ks*32 + quad*8]: row stride 128B
// -> start bank (32*lr+...)%32 INDEPENDENT of lr = 16-way conflict (5.7x,
// m136) on every fragment read. Swizzle slot(3b) = (ks*4+quad) ^ (row&7).
template <int ACT, int OUT_BF16>
__global__ __launch_bounds__(256) void gemm_bt64(const u16* __restrict__ A,
                                                 const u16* __restrict__ BT,
                                                 const float* __restrict__ bias,
                                                 void* __restrict__ Cout,
                                                 int M, int N, int K) {
    __shared__ __align__(16) u16 sA[4][64 * 64];  // 4 x 8 KB
    __shared__ __align__(16) u16 sB[4][64 * 64];
    const int tid  = threadIdx.x;
    const int wave = tid >> 6, lane = tid & 63;
    const int quad = lane >> 4, lr = lane & 15;
    const int m0 = blockIdx.x * 64, n0 = blockIdx.y * 64;
    const int srl = lane >> 3;
    const int sc = (((lane & 7) ^ ((lane >> 3) & 7))) * 8;  // swizzled k-chunk (u16)
    const int rsw = lr & 7;                                 // read-side slot XOR

    floatx4 acc[4];
#pragma unroll
    for (int i = 0; i < 4; i++)
#pragma unroll
        for (int j = 0; j < 4; j++) acc[i][j] = 0.f;

    const u16* apg = A + (size_t)(m0 + wave * 16 + srl) * K + sc;
    const u16* bpg = BT + (size_t)(n0 + wave * 16 + srl) * K + sc;
    const int ntk = K >> 6;   // K tiles (32 or 4 for our shapes; always >= 2)

#define STAGE64(t, sb) do {                                            \
        int kk_ = (t) << 6;                                            \
        glds16(apg + kk_,                 &sA[sb][(wave * 16) * 64]);  \
        glds16(apg + (size_t)8 * K + kk_, &sA[sb][(wave * 16 + 8) * 64]);\
        glds16(bpg + kk_,                 &sB[sb][(wave * 16) * 64]);  \
        glds16(bpg + (size_t)8 * K + kk_, &sB[sb][(wave * 16 + 8) * 64]);\
    } while (0)

    STAGE64(0, 0);
    STAGE64(1, 1);
    for (int t = 0; t < ntk; ++t) {
        const int s = t & 3;
        if (t + 1 < ntk) {
            asm volatile("s_waitcnt vmcnt(4)" ::: "memory");
        } else {
            asm volatile("s_waitcnt vmcnt(0)" ::: "memory");
        }
        __builtin_amdgcn_s_barrier();
        asm volatile("" ::: "memory");
#pragma unroll
        for (int ks = 0; ks < 2; ++ks) {
            bf16x8 af = *(const bf16x8*)&sA[s][(wave * 16 + lr) * 64 + ((ks * 4 + quad) ^ rsw) * 8];
#pragma unroll
            for (int nt = 0; nt < 4; nt++) {
                bf16x8 bf = *(const bf16x8*)&sB[s][(nt * 16 + lr) * 64 + ((ks * 4 + quad) ^ rsw) * 8];
                acc[nt] = __builtin_amdgcn_mfma_f32_16x16x32_bf16(af, bf, acc[nt], 0, 0, 0);
            }
        }
        asm volatile("" ::: "memory");
        if (t + 2 < ntk) STAGE64(t + 2, (t + 2) & 3);
    }
#undef STAGE64
#pragma unroll
    for (int nt = 0; nt < 4; nt++) {
        int col = n0 + nt * 16 + lr;
        float bvv = bias ? bias[col] : 0.f;
#pragma unroll
        for (int r = 0; r < 4; r++) {
            int row = m0 + wave * 16 + quad * 4 + r;
            float v = acc[nt][r] + bvv;
            if (ACT) v = fmaxf(v, 0.f);
            if (OUT_BF16) ((u16*)Cout)[(size_t)row * N + col] = f2bf(v);
            else          ((float*)Cout)[(size_t)row * N + col] = v;
        }
    }
}

// ---------------- dtdecay: dtraw = x @ W_dt, fused softplus + decay ----------------
// r22: the wave's 2 rows are processed TOGETHER in one k-pass so the 32
// weight bf2f converts per k-step are shared. 256 blocks x 16 rows.
__global__ __launch_bounds__(512) void dtdecay(const u16* __restrict__ xb,
                                               const u16* __restrict__ WdtT,
                                               const float* __restrict__ dt_bias,
                                               const float* __restrict__ A_log,
                                               float* __restrict__ dtv,
                                               float* __restrict__ decayv) {
    __shared__ __align__(16) u16 sw[NHEAD * D_IN];   // 64 KB, [h][k]
    const int tid = threadIdx.x;
#pragma unroll
    for (int i = 0; i < 8; ++i) {
        int idx = (tid + i * 512) * 8;
        *(uint4*)&sw[idx] = *(const uint4*)(WdtT + idx);
    }
    __syncthreads();
    const int wave = tid >> 6, lane = tid & 63;
    const int q = lane >> 4, lr = lane & 15;
    const int row0 = blockIdx.x * 16 + wave * 2;
    const u16* xp0 = xb + (size_t)row0 * D_IN;
    const u16* xp1 = xb + (size_t)(row0 + 1) * D_IN;
    float acc0[4] = {0.f, 0.f, 0.f, 0.f};
    float acc1[4] = {0.f, 0.f, 0.f, 0.f};
#pragma unroll 4
    for (int k0 = 0; k0 < 16; ++k0) {
        const int kk = k0 * 128 + lr * 8;
        uint4 xv0 = *(const uint4*)(xp0 + kk);
        uint4 xv1 = *(const uint4*)(xp1 + kk);
        const u16* xu0 = (const u16*)&xv0;
        const u16* xu1 = (const u16*)&xv1;
        float xf0[8], xf1[8];
#pragma unroll
        for (int j = 0; j < 8; ++j) { xf0[j] = bf2f(xu0[j]); xf1[j] = bf2f(xu1[j]); }
#pragma unroll
        for (int j = 0; j < 4; ++j) {
            uint4 wv = *(const uint4*)&sw[(q * 4 + j) * D_IN + kk];
            const u16* wu = (const u16*)&wv;
#pragma unroll
            for (int jj = 0; jj < 8; ++jj) {
                float wf = bf2f(wu[jj]);
                acc0[j] = fmaf(xf0[jj], wf, acc0[j]);
                acc1[j] = fmaf(xf1[jj], wf, acc1[j]);
            }
        }
    }
    // reduce across the 16 lanes of each quad (masks 1,2,4,8 stay in-quad)
#pragma unroll
    for (int m = 1; m <= 8; m <<= 1)
#pragma unroll
        for (int j = 0; j < 4; ++j) {
            acc0[j] += __shfl_xor(acc0[j], m);
            acc1[j] += __shfl_xor(acc1[j], m);
        }
    if (lr == 0) {
#pragma unroll
        for (int j = 0; j < 4; ++j) {
            int h = q * 4 + j;
            float ae = expf(A_log[h]);
            float z0 = acc0[j] + dt_bias[h];
            float sp0 = (z0 > 20.f) ? z0 : log1pf(expf(z0));
            float z1 = acc1[j] + dt_bias[h];
            float sp1 = (z1 > 20.f) ? z1 : log1pf(expf(z1));
            dtv[row0 * NHEAD + h] = sp0;
            decayv[row0 * NHEAD + h] = expf(-ae * sp0);
            dtv[(row0 + 1) * NHEAD + h] = sp1;
            decayv[(row0 + 1) * NHEAD + h] = expf(-ae * sp1);
        }
    }
}

// ---------------- seg_state: segment-final states as weighted outer-product sum ----------------
__global__ __launch_bounds__(256) void seg_state(const u16* __restrict__ xw,
                                                 const u16* __restrict__ BCm,
                                                 const float* __restrict__ dtv,
                                                 const float* __restrict__ decayv,
                                                 float* __restrict__ Hbuf) {
    const int blk = blockIdx.x;
    const int seg = blk >> 7;
    const int b   = (blk >> 4) & 7;
    const int h   = blk & 15;
    const int tid = threadIdx.x;
    const int pgrp = tid >> 3;
    const int oct  = tid & 7;

    __shared__ __align__(16) u16 sx[SEGT][PDIM];
    __shared__ __align__(16) u16 sbm[SEGT][NSTATE];
    __shared__ float sw[SEGT];
    __shared__ float sdt[SEGT];
    __shared__ float sdec[SEGT];
    __shared__ float sP[32];

    const int t0 = seg * SEGT;

#pragma unroll
    for (int k = 0; k < 8; ++k) {
        int idx = tid + k * 256;
        int t = idx >> 4, c = (idx & 15) * 8;
        int r = (t0 + t) * B_SZ + b;
        *(uint4*)&sx[t][c] = *(const uint4*)(xw + (size_t)r * D_IN + h * PDIM + c);
    }
#pragma unroll
    for (int k = 0; k < 4; ++k) {
        int idx = tid + k * 256;
        int t = idx >> 3, c = (idx & 7) * 8;
        int r = (t0 + t) * B_SZ + b;
        *(uint4*)&sbm[t][c] = *(const uint4*)(BCm + (size_t)r * BCSTR + h * NSTATE + c);
    }
    if (tid < SEGT)            sdt[tid] = dtv[((t0 + tid) * B_SZ + b) * NHEAD + h];
    else if (tid < 2 * SEGT)   sdec[tid - SEGT] = decayv[((t0 + tid - SEGT) * B_SZ + b) * NHEAD + h];
    __syncthreads();

    if (tid < 32) {
        float p = 1.f;
        for (int i = 3; i >= 0; --i) {
            int t = tid * 4 + i;
            sw[t] = sdt[t] * p;
            p *= sdec[t];
        }
        sP[tid] = p;
    }
    __syncthreads();
    if (tid == 0) {
        float suf = 1.f;
        for (int q = 31; q >= 0; --q) { float tmp = sP[q]; sP[q] = suf; suf *= tmp; }
    }
    __syncthreads();
    if (tid < 32) {
        float m = sP[tid];
        for (int i = 0; i < 4; ++i) sw[tid * 4 + i] *= m;
    }
    __syncthreads();

    float acc[4][8];
#pragma unroll
    for (int i = 0; i < 4; i++)
#pragma unroll
        for (int j = 0; j < 8; j++) acc[i][j] = 0.f;

    for (int t = 0; t < SEGT; ++t) {
        float w = sw[t];
        const u16* xp = &sx[t][pgrp * 4];
        const u16* bp = &sbm[t][oct * 8];
        float xv[4], bv[8];
#pragma unroll
        for (int i = 0; i < 4; i++) xv[i] = w * bf2f(xp[i]);
#pragma unroll
        for (int j = 0; j < 8; j++) bv[j] = bf2f(bp[j]);
#pragma unroll
        for (int i = 0; i < 4; i++)
#pragma unroll
            for (int j = 0; j < 8; j++)
                acc[i][j] = fmaf(xv[i], bv[j], acc[i][j]);
    }

    float* base = Hbuf + (size_t)seg * SLOT +
                  (((size_t)b * NHEAD + h) * PDIM + pgrp * 4) * NSTATE + oct * 8;
#pragma unroll
    for (int i = 0; i < 4; i++) {
        *(float4*)(base + (size_t)i * NSTATE)     = make_float4(acc[i][0], acc[i][1], acc[i][2], acc[i][3]);
        *(float4*)(base + (size_t)i * NSTATE + 4) = make_float4(acc[i][4], acc[i][5], acc[i][6], acc[i][7]);
    }
}

// ---------------- prefix combine -> bf16 prefix states Hbf ----------------
__global__ __launch_bounds__(256) void seg_prefix(const float* __restrict__ Hbuf,
                                                  const float* __restrict__ decayv,
                                                  u16* __restrict__ Hbf) {
    const int blk = blockIdx.x;
    const int b  = blk >> 6;
    const int h  = (blk >> 2) & 15;
    const int ec = blk & 3;
    const int tid = threadIdx.x;

    __shared__ float sA[NSEG];

    if (tid < 64 * (NSEG - 2)) {
        int s = 1 + (tid >> 6);
        int i = tid & 63;
        int t = s * SEGT + i * 2;
        float p = decayv[(t * B_SZ + b) * NHEAD + h] *
                  decayv[((t + 1) * B_SZ + b) * NHEAD + h];
        p *= __shfl_xor(p, 1);
        p *= __shfl_xor(p, 2);
        p *= __shfl_xor(p, 4);
        p *= __shfl_xor(p, 8);
        p *= __shfl_xor(p, 16);
        p *= __shfl_xor(p, 32);
        if (i == 0) sA[s] = p;
    }
    __syncthreads();

    const size_t base = (((size_t)b * NHEAD + h) * PDIM * NSTATE) + (size_t)ec * 2048 + tid * 8;
    float4 P0 = *(const float4*)(Hbuf + base);
    float4 P1 = *(const float4*)(Hbuf + base + 4);
    u16 pk[8];
    pk[0] = f2bf(P0.x); pk[1] = f2bf(P0.y); pk[2] = f2bf(P0.z); pk[3] = f2bf(P0.w);
    pk[4] = f2bf(P1.x); pk[5] = f2bf(P1.y); pk[6] = f2bf(P1.z); pk[7] = f2bf(P1.w);
    *(uint4*)(Hbf + base) = *(const uint4*)pk;
#pragma unroll
    for (int s = 1; s <= NSEG - 2; ++s) {
        float a = sA[s];
        const float* slot = Hbuf + (size_t)s * SLOT + base;
        float4 h0 = *(const float4*)(slot);
        float4 h1 = *(const float4*)(slot + 4);
        P0.x = fmaf(a, P0.x, h0.x); P0.y = fmaf(a, P0.y, h0.y);
        P0.z = fmaf(a, P0.z, h0.z); P0.w = fmaf(a, P0.w, h0.w);
        P1.x = fmaf(a, P1.x, h1.x); P1.y = fmaf(a, P1.y, h1.y);
        P1.z = fmaf(a, P1.z, h1.z); P1.w = fmaf(a, P1.w, h1.w);
        pk[0] = f2bf(P0.x); pk[1] = f2bf(P0.y); pk[2] = f2bf(P0.z); pk[3] = f2bf(P0.w);
        pk[4] = f2bf(P1.x); pk[5] = f2bf(P1.y); pk[6] = f2bf(P1.z); pk[7] = f2bf(P1.w);
        *(uint4*)(Hbf + (size_t)s * SLOT + base) = *(const uint4*)pk;
    }
}

// ---------------- chunk_scan: fused S' build + Y = exp(L).C@Hp^T + S'@X^T ----------------
__global__ __launch_bounds__(256) void chunk_scan(const u16* __restrict__ BCm,
                                                  const float* __restrict__ dtv,
                                                  const float* __restrict__ decayv,
                                                  const u16* __restrict__ Hbf,
                                                  u16* __restrict__ xb) {
    __shared__ __align__(16) u16 sB_[128][68];   // B [t'][n]
    __shared__ __align__(16) u16 sC_[128][68];   // C [t][n]
    __shared__ __align__(16) u16 sS[128][132];   // S' [t][t']
    __shared__ __align__(16) u16 sXT[128][36];   // X^T [p][k-tile]
    __shared__ float sdt[SEGT], sL[SEGT], sEL[SEGT], stmp[32];

    const int blk = blockIdx.x;
    const int seg = blk >> 7, b = (blk >> 4) & 7, h = blk & 15;
    const int tid = threadIdx.x;
    const int wave = tid >> 6, lane = tid & 63;
    const int quad = lane >> 4, lr = lane & 15;
    const int wm = wave & 1, wn = wave >> 1;
    const int t0 = seg * SEGT;

#pragma unroll
    for (int it = 0; it < 4; ++it) {
        int idx = tid + it * 256;
        int t = idx >> 3, c = (idx & 7) * 8;
        int r = (t0 + t) * B_SZ + b;
        *(uint4*)&sB_[t][c] = *(const uint4*)(BCm + (size_t)r * BCSTR + h * NSTATE + c);
        *(uint4*)&sC_[t][c] = *(const uint4*)(BCm + (size_t)r * BCSTR + 1024 + h * NSTATE + c);
    }
    if (tid < SEGT) sdt[tid] = dtv[((t0 + tid) * B_SZ + b) * NHEAD + h];
    else if (tid < 2 * SEGT) {
        int t = tid - SEGT;
        sL[t] = __logf(fmaxf(decayv[((t0 + t) * B_SZ + b) * NHEAD + h], 1e-30f));
    }
    __syncthreads();
    if (tid < 32) {
        float s = 0.f, v[4];
#pragma unroll
        for (int i = 0; i < 4; ++i) { s += sL[tid * 4 + i]; v[i] = s; }
        stmp[tid] = s;
#pragma unroll
        for (int i = 0; i < 4; ++i) sL[tid * 4 + i] = v[i];
    }
    __syncthreads();
    if (tid == 0) {
        float run = 0.f;
        for (int q = 0; q < 32; ++q) { float c2 = stmp[q]; stmp[q] = run; run += c2; }
    }
    __syncthreads();
    if (tid < 32) {
        float off = stmp[tid];
#pragma unroll
        for (int i = 0; i < 4; ++i) sL[tid * 4 + i] += off;
    }
    __syncthreads();
    if (tid < SEGT) sEL[tid] = __expf(sL[tid]);

    floatx4 accS[4][4];
#pragma unroll
    for (int i = 0; i < 4; i++)
#pragma unroll
        for (int j = 0; j < 4; j++)
#pragma unroll
            for (int r = 0; r < 4; r++) accS[i][j][r] = 0.f;
#pragma unroll
    for (int k0 = 0; k0 < 64; k0 += 32) {
        bf16x8 af[4], bfr[4];
#pragma unroll
        for (int i = 0; i < 4; i++)
            af[i] = *(const bf16x8*)&sB_[wm * 64 + i * 16 + lr][k0 + quad * 8];
#pragma unroll
        for (int j = 0; j < 4; j++)
            bfr[j] = *(const bf16x8*)&sC_[wn * 64 + j * 16 + lr][k0 + quad * 8];
#pragma unroll
        for (int i = 0; i < 4; i++)
#pragma unroll
            for (int j = 0; j < 4; j++)
                accS[i][j] = __builtin_amdgcn_mfma_f32_16x16x32_bf16(af[i], bfr[j], accS[i][j], 0, 0, 0);
    }
#pragma unroll
    for (int j = 0; j < 4; j++) {
        int tt = wn * 64 + j * 16 + lr;
        float Lt = sL[tt];
#pragma unroll
        for (int i = 0; i < 4; i++) {
#pragma unroll
            for (int r = 0; r < 4; r++) {
                int tp = wm * 64 + i * 16 + quad * 4 + r;
                float v = 0.f;
                if (tp <= tt) v = accS[i][j][r] * sdt[tp] * __expf(Lt - sL[tp]);
                sS[tt][tp] = f2bf(v);
            }
        }
    }

    floatx4 acc[4][4];
#pragma unroll
    for (int i = 0; i < 4; i++)
#pragma unroll
        for (int j = 0; j < 4; j++)
#pragma unroll
            for (int r = 0; r < 4; r++) acc[i][j][r] = 0.f;
    __syncthreads();
    if (seg > 0) {
        const u16* hbase = Hbf + (size_t)(seg - 1) * SLOT + (((size_t)b * NHEAD + h) * PDIM) * NSTATE;
#pragma unroll
        for (int k0 = 0; k0 < 64; k0 += 32) {
            bf16x8 af[4], bfr[4];
#pragma unroll
            for (int i = 0; i < 4; i++)
                af[i] = *(const bf16x8*)&sC_[wm * 64 + i * 16 + lr][k0 + quad * 8];
#pragma unroll
            for (int j = 0; j < 4; j++)
                bfr[j] = *(const bf16x8*)(hbase + (size_t)(wn * 64 + j * 16 + lr) * NSTATE + k0 + quad * 8);
#pragma unroll
            for (int i = 0; i < 4; i++)
#pragma unroll
                for (int j = 0; j < 4; j++)
                    acc[i][j] = __builtin_amdgcn_mfma_f32_16x16x32_bf16(af[i], bfr[j], acc[i][j], 0, 0, 0);
        }
#pragma unroll
        for (int i = 0; i < 4; i++) {
#pragma unroll
            for (int r = 0; r < 4; r++) {
                float el = sEL[wm * 64 + i * 16 + quad * 4 + r];
#pragma unroll
                for (int j = 0; j < 4; j++) acc[i][j][r] *= el;
            }
        }
    }

    const int px = tid & 127, koh = (tid >> 7) * 16;
    for (int kc = 0; kc < 128; kc += 32) {
        u16 xv[16];
#pragma unroll
        for (int j2 = 0; j2 < 16; ++j2) {
            int tp = kc + koh + j2;
            xv[j2] = xb[(size_t)((t0 + tp) * B_SZ + b) * D_IN + h * PDIM + px];
        }
        __syncthreads();
        *(uint4*)&sXT[px][koh]     = *(const uint4*)&xv[0];
        *(uint4*)&sXT[px][koh + 8] = *(const uint4*)&xv[8];
        __syncthreads();
        bf16x8 af[4], bfr[4];
#pragma unroll
        for (int i = 0; i < 4; i++)
            af[i] = *(const bf16x8*)&sS[wm * 64 + i * 16 + lr][kc + quad * 8];
#pragma unroll
        for (int j = 0; j < 4; j++)
            bfr[j] = *(const bf16x8*)&sXT[wn * 64 + j * 16 + lr][quad * 8];
#pragma unroll
        for (int i = 0; i < 4; i++)
#pragma unroll
            for (int j = 0; j < 4; j++)
                acc[i][j] = __builtin_amdgcn_mfma_f32_16x16x32_bf16(af[i], bfr[j], acc[i][j], 0, 0, 0);
    }

#pragma unroll
    for (int j = 0; j < 4; j++) {
        int p = wn * 64 + j * 16 + lr;
#pragma unroll
        for (int i = 0; i < 4; i++) {
#pragma unroll
            for (int r = 0; r < 4; r++) {
                int t = wm * 64 + i * 16 + quad * 4 + r;
                xb[(size_t)((t0 + t) * B_SZ + b) * D_IN + h * PDIM + p] = f2bf(acc[i][j][r]);
            }
        }
    }
}

// ---------------- launch ----------------
extern "C" void kernel_launch(void* const* d_in, const int* in_sizes, int n_in,
                              void* d_out, int out_size, void* d_ws, size_t ws_size,
                              hipStream_t stream) {
    const float* obs     = (const float*)d_in[0];
    const float* W_in    = (const float*)d_in[1];
    const float* b_in    = (const float*)d_in[2];
    const float* A_log   = (const float*)d_in[3];
    const float* dt_bias = (const float*)d_in[4];
    const float* W_dt    = (const float*)d_in[5];
    const float* W_B     = (const float*)d_in[6];
    const float* W_C     = (const float*)d_in[7];
    const float* W_yo    = (const float*)d_in[8];
    const float* b_yo    = (const float*)d_in[9];
    const float* W_head  = (const float*)d_in[10];
    const float* b_head  = (const float*)d_in[11];

    char* ws = (char*)d_ws;
    size_t o = 0;
    u16*   xb     = (u16*)(ws + o);   o += (size_t)ROWS * D_IN * 2;            // 16 MB (x, then y in-place)
    u16*   BCm    = (u16*)(ws + o);   o += (size_t)ROWS * BCSTR * 2;           // 17.8 MB (B | C | pad)
    float* dtv    = (float*)(ws + o); o += (size_t)ROWS * NHEAD * 4;
    float* decayv = (float*)(ws + o); o += (size_t)ROWS * NHEAD * 4;
    u16*   zb     = (u16*)(ws + o);   o += (size_t)ROWS * NUNITS * 2;          // 2 MB
    float* Hseg   = (float*)(ws + o); o += (size_t)(NSEG - 1) * SLOT * 4;      // 12 MB
    u16*   Hbf    = (u16*)(ws + o);   o += (size_t)(NSEG - 1) * SLOT * 2;      // 6 MB
    u16*   obsb   = (u16*)(ws + o);   o += (size_t)ROWS * OBS_D * 2;           // 2 MB
    u16*   WinT   = (u16*)(ws + o);   o += (size_t)D_IN * OBS_D * 2;           // 1 MB
    u16*   WBCT   = (u16*)(ws + o);   o += (size_t)BCN * D_IN * 2;             // 8 MB
    u16*   WdtT   = (u16*)(ws + o);   o += (size_t)NHEAD * D_IN * 2;           // 64 KB
    u16*   WyoT   = (u16*)(ws + o);   o += (size_t)NUNITS * D_IN * 2;          // 1 MB
    u16*   WheadT = (u16*)(ws + o);   o += (size_t)NACT * NUNITS * 2;

    // zero-work launch of the harness-required symbol (kept referenced)
    ActorAgent_27625229647898_kernel<<<dim3(1), 256, 0, stream>>>((float*)d_out, 0, 0.f);

    // ---- all weight prep in one launch ----
    prep<<<dim3(160 + 5136), 256, 0, stream>>>(obs, W_dt, W_in, W_B, W_C, W_yo, W_head,
                                               obsb, WinT, WBCT, WdtT, WyoT, WheadT);

    // ---- x = relu(obs @ W_in + b_in) -> bf16 ----
    gemm_bt128<1, 1, 1><<<dim3(32, 16), 256, 0, stream>>>(obsb, WinT, b_in, xb, ROWS, D_IN, OBS_D, D_IN);
    // ---- dt = softplus(x @ W_dt + dt_bias); decay = exp(-exp(A_log)*dt) ----
    dtdecay<<<dim3(256), 512, 0, stream>>>(xb, WdtT, dt_bias, A_log, dtv, decayv);
    // ---- B|C projection: N=2048 (16 tiles -> 512 blocks = 2/CU), ldc=2176 (non-pow2 stride) ----
    gemm_bt128<0, 1, 0><<<dim3(32, 16), 256, 0, stream>>>(xb, WBCT, (const float*)nullptr, BCm, ROWS, BCN, D_IN, BCSTR);
    // ---- scan: A) segment-local final states ----
    seg_state<<<dim3((NSEG - 1) * 128), 256, 0, stream>>>(xb, BCm, dtv, decayv, Hseg);
    //          B) prefix combine -> bf16 ----
    seg_prefix<<<dim3(512), 256, 0, stream>>>(Hseg, decayv, Hbf);
    //          C) fused S' + Y, in-place over xb ----
    chunk_scan<<<dim3(NSEG * 128), 256, 0, stream>>>(BCm, dtv, decayv, Hbf, xb);
    // ---- z = relu(y @ W_yo + b_yo) -> bf16 ----
    gemm_bt64<1, 1><<<dim3(64, 4), 256, 0, stream>>>(xb, WyoT, b_yo, zb, ROWS, NUNITS, D_IN);
    // ---- logits = z @ W_head + b_head -> d_out (fp32) ----
    gemm_bt64<0, 0><<<dim3(64, 1), 256, 0, stream>>>(zb, WheadT, b_head, (float*)d_out, ROWS, NACT, NUNITS);
}